// Round 8
// baseline (2445.388 us; speedup 1.0000x reference)
//
#include <hip/hip_runtime.h>
#include <hip/hip_bf16.h>
#include <math.h>

#define H 256
#define N0 50000
#define N1 10000
#define N2 4000
#define N3 1024
#define FAN 16

typedef __hip_bfloat16 bf16;
typedef __attribute__((ext_vector_type(8))) short short8;
typedef __attribute__((ext_vector_type(4))) short short4v;
typedef __attribute__((ext_vector_type(2))) short short2v;
typedef __attribute__((ext_vector_type(4))) float floatx4;

typedef const __attribute__((address_space(1))) void* gas_ptr;
typedef __attribute__((address_space(3))) void* las_ptr;

__device__ __forceinline__ void load_lds16(const void* g, void* l) {
    __builtin_amdgcn_global_load_lds((gas_ptr)g, (las_ptr)l, 16, 0, 0);
}

__device__ __forceinline__ float2 cvt_bf2(unsigned u) {
    union { unsigned q; float f; } lo, hi;
    lo.q = u << 16; hi.q = u & 0xffff0000u;
    return make_float2(lo.f, hi.f);
}

// ---------------- L1 gather-fused GEMM: 64x512 tile, 512 thr (8 waves) ----------------
// (round-6/7 verified: ~170us, FETCH 107MB = features read ~once; gather pass deleted.
//  Occupancy note: 64 VGPR + 64 AGPR acc = 128 regs/wave -> 2 blocks/CU; B-ring is
//  48 VGPR of that — the register wall for this family, accepted.)
__global__ __launch_bounds__(512, 4) void gemm_l1_fused(
    const float* __restrict__ F, const int* __restrict__ n_ids,
    const bf16* __restrict__ BtKV, const bf16* __restrict__ BtQS,
    const float* __restrict__ bk, const float* __restrict__ bv,
    const float* __restrict__ bq, const float* __restrict__ bs,
    bf16* __restrict__ Ckv, size_t CkvStr,
    float* __restrict__ Cqs, size_t CqsStr,
    int nbKV)
{
    constexpr int K = 256, Nh = 256, N = 512, KC = K / 32;
    __shared__ bf16 A_s[64 * K];

    const int z = blockIdx.z;
    const bool isKV = (int)blockIdx.x < nbKV;
    const int bx = isKV ? blockIdx.x : blockIdx.x - nbKV;
    const int M = isKV ? N0 : N1;
    const bf16* Bt = (isKV ? BtKV : BtQS) + (size_t)z * N * K;
    const float* b1 = (isKV ? bk : bq) + (size_t)z * Nh;
    const float* b2 = (isKV ? bv : bs) + (size_t)z * Nh;

    const int lane = threadIdx.x & 63;
    const int w = threadIdx.x >> 6;             // 0..7 (col group)
    const int lm = lane & 15;
    const int q = lane >> 4;
    const int mbase = bx * 64;

    // ---- gather-stage A (64 x 256): LDS chunk c of row r holds global chunk c^(r&7) ----
    {
        const int* idz = n_ids + (size_t)z * N0;
        #pragma unroll 4
        for (int j = 0; j < 8; j++) {
            int row = w * 8 + j;
            int grow = mbase + row; grow = grow < M ? grow : M - 1;
            int gidx = idz[grow];               // wave-uniform -> scalar load
            float4 v = *(const float4*)(F + (size_t)gidx * H + lane * 4);
            bf16 t4[4] = {(bf16)v.x, (bf16)v.y, (bf16)v.z, (bf16)v.w};
            int c16 = (lane >> 1) ^ (row & 7);  // 16B bf16 chunk, XOR swizzle
            *(short4v*)(A_s + (size_t)row * K + c16 * 8 + (lane & 1) * 4) =
                *(const short4v*)t4;
        }
    }

    const bf16* bp[4];
    #pragma unroll
    for (int ni = 0; ni < 4; ni++)
        bp[ni] = Bt + (size_t)(w * 64 + ni * 16 + lm) * K + q * 8;

    floatx4 acc[4][4];
    #pragma unroll
    for (int i = 0; i < 4; i++)
        #pragma unroll
        for (int j = 0; j < 4; j++)
            acc[i][j] = (floatx4){0.f, 0.f, 0.f, 0.f};

    // 3-deep B ring preload (L2-resident weights), issued before the barrier
    short8 br0[4], br1[4], br2[4];
    #pragma unroll
    for (int ni = 0; ni < 4; ni++) br0[ni] = *(const short8*)(bp[ni]);
    #pragma unroll
    for (int ni = 0; ni < 4; ni++) br1[ni] = *(const short8*)(bp[ni] + 32);
    #pragma unroll
    for (int ni = 0; ni < 4; ni++) br2[ni] = *(const short8*)(bp[ni] + 64);

    __syncthreads();

    #pragma unroll
    for (int kc = 0; kc < KC; kc++) {
        short8 bc[4];
        #pragma unroll
        for (int ni = 0; ni < 4; ni++) {
            bc[ni] = br0[ni]; br0[ni] = br1[ni]; br1[ni] = br2[ni];
        }
        if (kc + 3 < KC) {
            #pragma unroll
            for (int ni = 0; ni < 4; ni++)
                br2[ni] = *(const short8*)(bp[ni] + (kc + 3) * 32);
        }
        short8 af[4];
        #pragma unroll
        for (int mi = 0; mi < 4; mi++) {
            int row = mi * 16 + lm;
            af[mi] = *(const short8*)(A_s + row * K + (((kc * 4 + q) ^ (lm & 7)) * 8));
        }
        #pragma unroll
        for (int mi = 0; mi < 4; mi++)
            #pragma unroll
            for (int ni = 0; ni < 4; ni++)
                acc[mi][ni] = __builtin_amdgcn_mfma_f32_16x16x32_bf16(
                    af[mi], bc[ni], acc[mi][ni], 0, 0, 0);
    }

    // C/D layout: col = lane&15, row = (lane>>4)*4 + reg  [m89]
    if (isKV) {
        bf16* C = Ckv + (size_t)z * CkvStr;
        __syncthreads();                        // A_s dead; reuse as transpose stage
        bf16* stg = A_s + (size_t)w * (16 * 72);    // 8 waves x 2304B = 18KB < 32KB
        #pragma unroll
        for (int p = 0; p < 4; p++) {           // p == mi
            #pragma unroll
            for (int ni = 0; ni < 4; ni++) {
                int colg = w * 64 + ni * 16 + lm;
                float bias = (colg < Nh) ? b1[colg] : b2[colg - Nh];
                #pragma unroll
                for (int rg = 0; rg < 4; rg++)
                    stg[(q * 4 + rg) * 72 + ni * 16 + lm] = (bf16)(acc[p][ni][rg] + bias);
            }
            #pragma unroll
            for (int it = 0; it < 2; it++) {
                int rl = it * 8 + (lane >> 3);
                int grow = mbase + p * 16 + rl;
                short8 vv = *(const short8*)(stg + rl * 72 + (lane & 7) * 8);
                if (grow < M)
                    *(short8*)(C + (size_t)grow * N + w * 64 + (lane & 7) * 8) = vv;
            }
        }
    } else {
        float* C = Cqs + (size_t)z * CqsStr;
        #pragma unroll
        for (int ni = 0; ni < 4; ni++) {
            int colg = w * 64 + ni * 16 + lm;
            float bias = (colg < Nh) ? b1[colg] : b2[colg - Nh];
            #pragma unroll
            for (int mi = 0; mi < 4; mi++) {
                int rb = mbase + mi * 16 + q * 4;
                #pragma unroll
                for (int rg = 0; rg < 4; rg++) {
                    int rr = rb + rg;
                    if (rr < M) C[(size_t)rr * N + colg] = acc[mi][ni][rg] + bias;
                }
            }
        }
    }
}

// ---------------- dual-output LDS-A MFMA GEMM (L2/L3) ----------------
// NORM mode (L2): (x-mu)*istd -> ELU applied during A-staging (reg-staged bf16,
// same XOR-swizzled LDS layout; K-loop/epilogue untouched).
template<int K, bool NORM>
__global__ __launch_bounds__(256, 4) void gemm_dual(
    const bf16* __restrict__ A, size_t Astr,
    const float* __restrict__ muv, const float* __restrict__ istdv,
    const bf16* __restrict__ BtKV, const bf16* __restrict__ BtQS,
    const float* __restrict__ bk, const float* __restrict__ bv,
    const float* __restrict__ bq, const float* __restrict__ bs, int Nh,
    bf16* __restrict__ Ckv, size_t CkvStr, int Mkv,
    float* __restrict__ Cqs, size_t CqsStr, int Mqs,
    int nbKV)
{
    constexpr int KC = K / 32;
    constexpr int CPR = K / 8;                  // 16B chunks per row
    constexpr int LOG_CPR = (K == 256) ? 5 : 4;
    constexpr int RPI = 64 / CPR;               // rows per staging issue
    constexpr int ISSUES = 16 / RPI;            // per wave (16 rows/wave)
    const int N = 2 * Nh;
    __shared__ bf16 A_s[64 * K];

    const int z = blockIdx.z;
    const bool isKV = (int)blockIdx.x < nbKV;
    const int bx = isKV ? blockIdx.x : blockIdx.x - nbKV;
    const int M = isKV ? Mkv : Mqs;
    const bf16* Bt = (isKV ? BtKV : BtQS) + (size_t)z * N * K;
    const float* b1 = (isKV ? bk : bq) + (size_t)z * Nh;
    const float* b2 = (isKV ? bv : bs) + (size_t)z * Nh;
    A += (size_t)z * Astr;

    const int lane = threadIdx.x & 63;
    const int w = threadIdx.x >> 6;             // 0..3 (col group)
    const int lm = lane & 15;
    const int q = lane >> 4;
    const int mbase = bx * 64;
    const int n0 = blockIdx.y * 256;

    // ---- stage A tile (64 x K): LDS chunk c of row r holds global chunk c^(r&7) ----
    {
        const int ch = lane & (CPR - 1);
        const int rsub = lane >> LOG_CPR;
        if constexpr (NORM) {
            const float* muz = muv + (size_t)z * K;
            const float* isz = istdv + (size_t)z * K;
            #pragma unroll
            for (int i = 0; i < ISSUES; i++) {
                int row = w * 16 + i * RPI + rsub;
                int grow = mbase + row; grow = grow < M ? grow : M - 1;
                int gch = ch ^ (row & 7);
                short8 raw = *(const short8*)(A + (size_t)grow * K + gch * 8);
                float4 m0 = *(const float4*)(muz + gch * 8);
                float4 m1 = *(const float4*)(muz + gch * 8 + 4);
                float4 i0 = *(const float4*)(isz + gch * 8);
                float4 i1 = *(const float4*)(isz + gch * 8 + 4);
                float mm[8] = {m0.x, m0.y, m0.z, m0.w, m1.x, m1.y, m1.z, m1.w};
                float ii[8] = {i0.x, i0.y, i0.z, i0.w, i1.x, i1.y, i1.z, i1.w};
                bf16 outb[8];
                #pragma unroll
                for (int j = 0; j < 8; j++) {
                    union { unsigned u; float f; } cv;
                    cv.u = ((unsigned)(unsigned short)raw[j]) << 16;
                    float t = (cv.f - mm[j]) * ii[j];
                    t = t > 0.f ? t : __expf(t) - 1.0f;
                    outb[j] = (bf16)t;
                }
                *(short8*)(A_s + (size_t)row * K + ch * 8) = *(const short8*)outb;
            }
        } else {
            #pragma unroll
            for (int i = 0; i < ISSUES; i++) {
                int row = w * 16 + i * RPI + rsub;
                int grow = mbase + row; grow = grow < M ? grow : M - 1;
                int gch = ch ^ (row & 7);
                load_lds16(A + (size_t)grow * K + gch * 8,
                           A_s + (size_t)(w * 16 + i * RPI) * K);
            }
        }
    }

    const bf16* bp[4];
    #pragma unroll
    for (int ni = 0; ni < 4; ni++)
        bp[ni] = Bt + (size_t)(n0 + w * 64 + ni * 16 + lm) * K + q * 8;

    floatx4 acc[4][4];
    #pragma unroll
    for (int i = 0; i < 4; i++)
        #pragma unroll
        for (int j = 0; j < 4; j++)
            acc[i][j] = (floatx4){0.f, 0.f, 0.f, 0.f};

    // 3-deep B ring preload, issued before the barrier (overlaps staging drain)
    short8 br0[4], br1[4], br2[4];
    #pragma unroll
    for (int ni = 0; ni < 4; ni++) br0[ni] = *(const short8*)(bp[ni]);
    #pragma unroll
    for (int ni = 0; ni < 4; ni++) br1[ni] = *(const short8*)(bp[ni] + 32);
    #pragma unroll
    for (int ni = 0; ni < 4; ni++) br2[ni] = *(const short8*)(bp[ni] + 64);

    __syncthreads();

    #pragma unroll
    for (int kc = 0; kc < KC; kc++) {
        short8 bc[4];
        #pragma unroll
        for (int ni = 0; ni < 4; ni++) {
            bc[ni] = br0[ni]; br0[ni] = br1[ni]; br1[ni] = br2[ni];
        }
        if (kc + 3 < KC) {
            #pragma unroll
            for (int ni = 0; ni < 4; ni++)
                br2[ni] = *(const short8*)(bp[ni] + (kc + 3) * 32);
        }
        short8 af[4];
        #pragma unroll
        for (int mi = 0; mi < 4; mi++) {
            int row = mi * 16 + lm;
            af[mi] = *(const short8*)(A_s + row * K + (((kc * 4 + q) ^ (lm & 7)) * 8));
        }
        #pragma unroll
        for (int mi = 0; mi < 4; mi++)
            #pragma unroll
            for (int ni = 0; ni < 4; ni++)
                acc[mi][ni] = __builtin_amdgcn_mfma_f32_16x16x32_bf16(
                    af[mi], bc[ni], acc[mi][ni], 0, 0, 0);
    }

    // C/D layout: col = lane&15, row = (lane>>4)*4 + reg  [m89]
    if (isKV) {
        bf16* C = Ckv + (size_t)z * CkvStr;
        __syncthreads();                        // A_s dead; reuse as transpose stage
        bf16* stg = A_s + (size_t)w * (16 * 72);
        #pragma unroll
        for (int p = 0; p < 4; p++) {           // p == mi
            #pragma unroll
            for (int ni = 0; ni < 4; ni++) {
                int colg = n0 + w * 64 + ni * 16 + lm;
                float bias = (colg < Nh) ? b1[colg] : b2[colg - Nh];
                #pragma unroll
                for (int rg = 0; rg < 4; rg++)
                    stg[(q * 4 + rg) * 72 + ni * 16 + lm] = (bf16)(acc[p][ni][rg] + bias);
            }
            #pragma unroll
            for (int it = 0; it < 2; it++) {
                int rl = it * 8 + (lane >> 3);
                int grow = mbase + p * 16 + rl;
                short8 vv = *(const short8*)(stg + rl * 72 + (lane & 7) * 8);
                if (grow < M)
                    *(short8*)(C + (size_t)grow * N + n0 + w * 64 + (lane & 7) * 8) = vv;
            }
        }
    } else {
        float* C = Cqs + (size_t)z * CqsStr;
        #pragma unroll
        for (int ni = 0; ni < 4; ni++) {
            int colg = n0 + w * 64 + ni * 16 + lm;
            float bias = (colg < Nh) ? b1[colg] : b2[colg - Nh];
            #pragma unroll
            for (int mi = 0; mi < 4; mi++) {
                int rb = mbase + mi * 16 + q * 4;
                #pragma unroll
                for (int rg = 0; rg < 4; rg++) {
                    int rr = rb + rg;
                    if (rr < M) C[(size_t)rr * N + colg] = acc[mi][ni][rg] + bias;
                }
            }
        }
    }
}

// ---------------- all weight packs in ONE dispatch (job via blockIdx.z) ----------
__global__ __launch_bounds__(256) void pack_all(
    const float* __restrict__ l1_Wk, const float* __restrict__ l1_Wv,
    const float* __restrict__ l1_Wq, const float* __restrict__ l1_Ws,
    const float* __restrict__ l2_Wk, const float* __restrict__ l2_Wv,
    const float* __restrict__ l2_Wq, const float* __restrict__ l2_Ws,
    const float* __restrict__ l3_Wk, const float* __restrict__ l3_Wv,
    const float* __restrict__ l3_Wq, const float* __restrict__ l3_Ws,
    bf16* __restrict__ Wkv1, bf16* __restrict__ Wqs1,
    bf16* __restrict__ Wkv2, bf16* __restrict__ Wqs2,
    bf16* __restrict__ Wkv3, bf16* __restrict__ Wqs3)
{
    int job = blockIdx.z, r = blockIdx.y, nn = blockIdx.x, k = threadIdx.x;
    const float *W1, *W2; bf16* Wt; int K, Nh;
    switch (job) {
        case 0: W1 = l1_Wk; W2 = l1_Wv; Wt = Wkv1; K = 256; Nh = 256; break;
        case 1: W1 = l1_Wq; W2 = l1_Ws; Wt = Wqs1; K = 256; Nh = 256; break;
        case 2: W1 = l2_Wk; W2 = l2_Wv; Wt = Wkv2; K = 256; Nh = 128; break;
        case 3: W1 = l2_Wq; W2 = l2_Ws; Wt = Wqs2; K = 256; Nh = 128; break;
        case 4: W1 = l3_Wk; W2 = l3_Wv; Wt = Wkv3; K = 128; Nh = 256; break;
        default: W1 = l3_Wq; W2 = l3_Ws; Wt = Wqs3; K = 128; Nh = 256; break;
    }
    if (nn >= 2 * Nh || k >= K) return;
    size_t wstride = (size_t)K * Nh;
    float v = (nn < Nh) ? W1[(size_t)r * wstride + (size_t)k * Nh + nn]
                        : W2[(size_t)r * wstride + (size_t)k * Nh + (nn - Nh)];
    Wt[(size_t)r * 2 * wstride + (size_t)nn * K + k] = (bf16)v;
}

// ---------------- fused attention + gated skip ----------------
// v-prefetch: both random-access rounds issued back-to-back (in-order vmcnt
// keeps k-consumes unaffected; v latency hides under softmax math).
// STATS (L1): per-column (y, y^2) accumulated via f32 atomicAdd into 3xH
// accumulators -> the separate colstat_partial pass (15.4MB re-read + launch
// gap) is deleted. Stats use the bf16-rounded y (bit-identical to reading x1b).
template<int CPL, int HEADS, bool STATS>   // hc = CPL*64
__global__ __launch_bounds__(256) void attn_gate(
    const float* __restrict__ qs, size_t qsStr,
    const bf16* __restrict__ kv, size_t kvStr,
    const int* __restrict__ src,
    const float* __restrict__ Wb,
    float* __restrict__ yf, size_t yfStr,
    bf16* __restrict__ yb, size_t ybStr,
    float* __restrict__ ps, float* __restrict__ pss,
    int ndst, float scale)
{
    constexpr int hc = CPL * 64;
    constexpr int LPH = 64 / HEADS;
    const int z = blockIdx.y;
    int lane = threadIdx.x & 63;
    int d = blockIdx.x * 4 + (threadIdx.x >> 6);
    if (d >= ndst) return;
    qs += (size_t)z * qsStr;
    kv += (size_t)z * kvStr;
    src += (size_t)z * ndst * FAN;
    Wb += (size_t)z * 3 * hc;

    const float* qp = qs + (size_t)d * (2 * hc) + lane * CPL;
    float qv[CPL], xv[CPL];
    if constexpr (CPL == 2) {
        float2 a = *(const float2*)qp;
        float2 b = *(const float2*)(qp + hc);
        qv[0] = a.x; qv[1] = a.y; xv[0] = b.x; xv[1] = b.y;
    } else {
        float4 a = *(const float4*)qp;
        float4 b = *(const float4*)(qp + hc);
        qv[0] = a.x; qv[1] = a.y; qv[2] = a.z; qv[3] = a.w;
        xv[0] = b.x; xv[1] = b.y; xv[2] = b.z; xv[3] = b.w;
    }
    const int* sp = src + (size_t)d * FAN;
    int sidx[FAN];
    #pragma unroll
    for (int e = 0; e < FAN; e++) sidx[e] = sp[e];

    // partial dots (all k loads issued before the shuffle phase)
    float part[FAN];
    #pragma unroll
    for (int e = 0; e < FAN; e++) {
        const bf16* kp = kv + (size_t)sidx[e] * (2 * hc) + lane * CPL;
        if constexpr (CPL == 2) {
            float2 kf = cvt_bf2(*(const unsigned*)kp);
            part[e] = qv[0] * kf.x + qv[1] * kf.y;
        } else {
            uint2 u = *(const uint2*)kp;
            float2 k0 = cvt_bf2(u.x), k1 = cvt_bf2(u.y);
            part[e] = qv[0] * k0.x + qv[1] * k0.y + qv[2] * k1.x + qv[3] * k1.y;
        }
    }

    // prefetch v rows into regs (overlaps softmax below)
    uint2 vreg[FAN];
    #pragma unroll
    for (int e = 0; e < FAN; e++) {
        const bf16* vp = kv + (size_t)sidx[e] * (2 * hc) + hc + lane * CPL;
        if constexpr (CPL == 2) vreg[e].x = *(const unsigned*)vp;
        else                    vreg[e]   = *(const uint2*)vp;
    }

    float logit[FAN], mx = -1e30f;
    #pragma unroll
    for (int e = 0; e < FAN; e++) {
        float dt = part[e];
        #pragma unroll
        for (int off = LPH / 2; off > 0; off >>= 1) dt += __shfl_xor(dt, off, 64);
        dt *= scale;
        logit[e] = dt;
        mx = fmaxf(mx, dt);
    }
    float zsum = 0.f, p[FAN];
    #pragma unroll
    for (int e = 0; e < FAN; e++) { p[e] = __expf(logit[e] - mx); zsum += p[e]; }
    float inv = 1.f / zsum;

    float ov[CPL];
    #pragma unroll
    for (int j = 0; j < CPL; j++) ov[j] = 0.f;
    #pragma unroll
    for (int e = 0; e < FAN; e++) {
        if constexpr (CPL == 2) {
            float2 vf = cvt_bf2(vreg[e].x);
            ov[0] += p[e] * vf.x; ov[1] += p[e] * vf.y;
        } else {
            float2 v0 = cvt_bf2(vreg[e].x), v1 = cvt_bf2(vreg[e].y);
            ov[0] += p[e] * v0.x; ov[1] += p[e] * v0.y;
            ov[2] += p[e] * v1.x; ov[3] += p[e] * v1.y;
        }
    }
    #pragma unroll
    for (int j = 0; j < CPL; j++) ov[j] *= inv;

    // gated skip
    float s = 0.f;
    #pragma unroll
    for (int j = 0; j < CPL; j++) {
        int c = lane * CPL + j;
        s += ov[j] * Wb[c] + xv[j] * Wb[hc + c] + (ov[j] - xv[j]) * Wb[2 * hc + c];
    }
    #pragma unroll
    for (int off = 32; off > 0; off >>= 1) s += __shfl_xor(s, off, 64);
    float g = 1.f / (1.f + __expf(-s));

    float yv[CPL];
    #pragma unroll
    for (int j = 0; j < CPL; j++) yv[j] = g * xv[j] + (1.f - g) * ov[j];

    if (yf) {
        float* op = yf + (size_t)z * yfStr + (size_t)d * hc + lane * CPL;
        if constexpr (CPL == 2) *(float2*)op = make_float2(yv[0], yv[1]);
        else *(float4*)op = make_float4(yv[0], yv[1], yv[2], yv[3]);
    }
    if (yb) {
        bf16* op = yb + (size_t)z * ybStr + (size_t)d * hc + lane * CPL;
        bf16 tmp[CPL];
        #pragma unroll
        for (int j = 0; j < CPL; j++) tmp[j] = (bf16)yv[j];
        if constexpr (CPL == 2) *(short2v*)op = *(const short2v*)tmp;
        else *(short4v*)op = *(const short4v*)tmp;
        if constexpr (STATS) {
            float* psz  = ps  + (size_t)z * hc;
            float* pssz = pss + (size_t)z * hc;
            #pragma unroll
            for (int j = 0; j < CPL; j++) {
                float tb = (float)tmp[j];       // stats on bf16-rounded y
                int c = lane * CPL + j;
                atomicAdd(&psz[c], tb);
                atomicAdd(&pssz[c], tb * tb);
            }
        }
    }
}

// tiny: ps/pss (3 x H, atomically accumulated) -> per-column mu, istd
__global__ __launch_bounds__(256) void colstats_final(
    const float* __restrict__ ps, const float* __restrict__ pss, int M,
    float* __restrict__ muv, float* __restrict__ istdv)
{
    int z = blockIdx.x;
    int c = threadIdx.x;
    float s = ps[(size_t)z * H + c];
    float ss = pss[(size_t)z * H + c];
    float mu = s / M;
    muv[(size_t)z * H + c] = mu;
    istdv[(size_t)z * H + c] = rsqrtf(ss / M - mu * mu + 1e-5f);
}

// ---------------- semantic attention across the 3 relations ----------------
// shuffle-based score reduction: 7 barriers/block (was 27 with the LDS tree)
__global__ __launch_bounds__(256) void semantic_kernel(
    const float* __restrict__ emb,   // (3, N3, H)
    const float* __restrict__ Wo, const float* __restrict__ bo,
    const float* __restrict__ uo, const float* __restrict__ rl,
    float* __restrict__ outp)
{
    __shared__ float m_s[3][H];
    __shared__ float wsum[4];
    __shared__ float score_s[3];
    int n = blockIdx.x, c = threadIdx.x;
    for (int r = 0; r < 3; r++)
        m_s[r][c] = emb[((size_t)r * N3 + n) * H + c] * rl[r];
    __syncthreads();
    for (int r = 0; r < 3; r++) {
        float t = bo[c];
        for (int k2 = 0; k2 < H; k2++) t += m_s[r][k2] * Wo[k2 * H + c];
        float v = tanhf(t) * uo[c];
        #pragma unroll
        for (int off = 32; off > 0; off >>= 1) v += __shfl_xor(v, off, 64);
        if ((c & 63) == 0) wsum[c >> 6] = v;
        __syncthreads();
        if (c == 0) score_s[r] = wsum[0] + wsum[1] + wsum[2] + wsum[3];
        __syncthreads();
    }
    float s0 = score_s[0], s1 = score_s[1], s2 = score_s[2];
    float mx = fmaxf(s0, fmaxf(s1, s2));
    float e0 = __expf(s0 - mx), e1 = __expf(s1 - mx), e2 = __expf(s2 - mx);
    float zi = 1.0f / (e0 + e1 + e2);
    outp[(size_t)n * H + c] = (m_s[0][c] * e0 + m_s[1][c] * e1 + m_s[2][c] * e2) * zi;
}

extern "C" void kernel_launch(void* const* d_in, const int* in_sizes, int n_in,
                              void* d_out, int out_size, void* d_ws, size_t ws_size,
                              hipStream_t stream) {
    const float* features = (const float*)d_in[0];
    const int*   n_ids    = (const int*)d_in[1];
    const int*   src1     = (const int*)d_in[2];
    const int*   src2     = (const int*)d_in[4];
    const int*   src3     = (const int*)d_in[6];
    const float* l1_Wq = (const float*)d_in[8];
    const float* l1_Wk = (const float*)d_in[9];
    const float* l1_Wv = (const float*)d_in[10];
    const float* l1_Ws = (const float*)d_in[11];
    const float* l1_bq = (const float*)d_in[12];
    const float* l1_bk = (const float*)d_in[13];
    const float* l1_bv = (const float*)d_in[14];
    const float* l1_bs = (const float*)d_in[15];
    const float* l1_Wb = (const float*)d_in[16];
    const float* l2_Wq = (const float*)d_in[17];
    const float* l2_Wk = (const float*)d_in[18];
    const float* l2_Wv = (const float*)d_in[19];
    const float* l2_Ws = (const float*)d_in[20];
    const float* l2_bq = (const float*)d_in[21];
    const float* l2_bk = (const float*)d_in[22];
    const float* l2_bv = (const float*)d_in[23];
    const float* l2_bs = (const float*)d_in[24];
    const float* l2_Wb = (const float*)d_in[25];
    const float* l3_Wq = (const float*)d_in[26];
    const float* l3_Wk = (const float*)d_in[27];
    const float* l3_Wv = (const float*)d_in[28];
    const float* l3_Ws = (const float*)d_in[29];
    const float* l3_bq = (const float*)d_in[30];
    const float* l3_bk = (const float*)d_in[31];
    const float* l3_bv = (const float*)d_in[32];
    const float* l3_bs = (const float*)d_in[33];
    const float* l3_Wb = (const float*)d_in[34];
    const float* w_omega = (const float*)d_in[35];
    const float* b_omega = (const float*)d_in[36];
    const float* u_omega = (const float*)d_in[37];
    const float* rl      = (const float*)d_in[38];

    // ---- workspace layout: per-relation buffers ----
    float* ws = (float*)d_ws;
    size_t o = 0;
    float* emb = ws + o; o += (size_t)3 * N3 * H;
    float* qs1 = ws + o; o += (size_t)3 * N1 * 512;
    float* qs2 = ws + o; o += (size_t)3 * N2 * 256;
    float* qs3 = ws + o; o += (size_t)3 * N3 * 512;
    float* ps  = ws + o; o += (size_t)3 * H;
    float* pss = ws + o; o += (size_t)3 * H;
    float* muv   = ws + o; o += (size_t)3 * H;
    float* istdv = ws + o; o += (size_t)3 * H;

    bf16* bws = (bf16*)(ws + o);
    size_t b = 0;
    bf16* kv1 = bws + b; b += (size_t)3 * N0 * 512;
    bf16* x1b = bws + b; b += (size_t)3 * N1 * 256;
    bf16* kv2 = bws + b; b += (size_t)3 * N1 * 256;
    bf16* x2b = bws + b; b += (size_t)3 * N2 * 128;
    bf16* kv3 = bws + b; b += (size_t)3 * N2 * 512;
    bf16* Wkv1 = bws + b; b += (size_t)3 * 512 * H;
    bf16* Wqs1 = bws + b; b += (size_t)3 * 512 * H;
    bf16* Wkv2 = bws + b; b += (size_t)3 * 256 * H;
    bf16* Wqs2 = bws + b; b += (size_t)3 * 256 * H;
    bf16* Wkv3 = bws + b; b += (size_t)3 * 512 * 128;
    bf16* Wqs3 = bws + b; b += (size_t)3 * 512 * 128;

    const float sc128 = 0.088388347648318447f;  // 1/sqrt(128)
    const float sc256 = 0.0625f;                // 1/sqrt(256)

    // zero the atomic stats accumulators (ps, pss are contiguous)
    hipMemsetAsync(ps, 0, (size_t)2 * 3 * H * sizeof(float), stream);

    // ---- all weight packs, one dispatch ----
    pack_all<<<dim3(512, 3, 6), 256, 0, stream>>>(
        l1_Wk, l1_Wv, l1_Wq, l1_Ws, l2_Wk, l2_Wv, l2_Wq, l2_Ws,
        l3_Wk, l3_Wv, l3_Wq, l3_Ws, Wkv1, Wqs1, Wkv2, Wqs2, Wkv3, Wqs3);

    // ---- L1 (gather-fused, single-pass): 64x512 tile, 512 thr ----
    {
        int nbKV = (N0 + 63) / 64, nbQS = (N1 + 63) / 64;
        gemm_l1_fused<<<dim3(nbKV + nbQS, 1, 3), 512, 0, stream>>>(
            features, n_ids, Wkv1, Wqs1, l1_bk, l1_bv, l1_bq, l1_bs,
            kv1, (size_t)N0 * 512, qs1, (size_t)N1 * 512, nbKV);
    }
    attn_gate<4, 2, true><<<dim3((N1 + 3) / 4, 3), 256, 0, stream>>>(
        qs1, (size_t)N1 * 512, kv1, (size_t)N0 * 512, src1, l1_Wb,
        (float*)nullptr, 0, x1b, (size_t)N1 * 256, ps, pss, N1, sc128);
    colstats_final<<<dim3(3), 256, 0, stream>>>(ps, pss, N1, muv, istdv);

    // ---- L2 (norm+ELU folded into A-staging): din=256, hc=128, N=256, K=256 ----
    {
        int nbKV = (N1 + 63) / 64, nbQS = (N2 + 63) / 64;
        gemm_dual<256, true><<<dim3(nbKV + nbQS, 1, 3), 256, 0, stream>>>(
            x1b, (size_t)N1 * 256, muv, istdv,
            Wkv2, Wqs2, l2_bk, l2_bv, l2_bq, l2_bs, 128,
            kv2, (size_t)N1 * 256, N1, qs2, (size_t)N2 * 256, N2, nbKV);
    }
    attn_gate<2, 1, false><<<dim3((N2 + 3) / 4, 3), 256, 0, stream>>>(
        qs2, (size_t)N2 * 256, kv2, (size_t)N1 * 256, src2, l2_Wb,
        (float*)nullptr, 0, x2b, (size_t)N2 * 128,
        (float*)nullptr, (float*)nullptr, N2, sc128);

    // ---- L3: din=128, heads=1, ch=256, hc=256, N=512, K=128 ----
    {
        int nbKV = (N2 + 63) / 64, nbQS = (N3 + 63) / 64;
        gemm_dual<128, false><<<dim3(nbKV + nbQS, 2, 3), 256, 0, stream>>>(
            x2b, (size_t)N2 * 128, (const float*)nullptr, (const float*)nullptr,
            Wkv3, Wqs3, l3_bk, l3_bv, l3_bq, l3_bs, 256,
            kv3, (size_t)N2 * 512, N2, qs3, (size_t)N3 * 512, N3, nbKV);
    }
    attn_gate<4, 1, false><<<dim3((N3 + 3) / 4, 3), 256, 0, stream>>>(
        qs3, (size_t)N3 * 512, kv3, (size_t)N2 * 512, src3, l3_Wb,
        emb, (size_t)N3 * H, (bf16*)nullptr, 0,
        (float*)nullptr, (float*)nullptr, N3, sc256);

    semantic_kernel<<<N3, 256, 0, stream>>>(emb, w_omega, b_omega, u_omega, rl, (float*)d_out);
}

// Round 9
// 582.460 us; speedup vs baseline: 4.1984x; 4.1984x over previous
//
#include <hip/hip_runtime.h>
#include <hip/hip_bf16.h>
#include <math.h>

#define H 256
#define N0 50000
#define N1 10000
#define N2 4000
#define N3 1024
#define FAN 16

typedef __hip_bfloat16 bf16;
typedef __attribute__((ext_vector_type(8))) short short8;
typedef __attribute__((ext_vector_type(4))) short short4v;
typedef __attribute__((ext_vector_type(2))) short short2v;
typedef __attribute__((ext_vector_type(4))) float floatx4;

typedef const __attribute__((address_space(1))) void* gas_ptr;
typedef __attribute__((address_space(3))) void* las_ptr;

__device__ __forceinline__ void load_lds16(const void* g, void* l) {
    __builtin_amdgcn_global_load_lds((gas_ptr)g, (las_ptr)l, 16, 0, 0);
}

__device__ __forceinline__ float2 cvt_bf2(unsigned u) {
    union { unsigned q; float f; } lo, hi;
    lo.q = u << 16; hi.q = u & 0xffff0000u;
    return make_float2(lo.f, hi.f);
}

// ---------------- L1 gather-fused GEMM: 64x512 tile, 512 thr (8 waves) ----------------
// (round-6/7 verified: ~170us, FETCH 107MB = features read ~once; gather pass deleted.)
// RULE (round-8 lesson): never convert a column-reduction into same-address
// global atomics when rows >> 1000 — 10k serialized atomics/address = 1.9ms.
__global__ __launch_bounds__(512, 4) void gemm_l1_fused(
    const float* __restrict__ F, const int* __restrict__ n_ids,
    const bf16* __restrict__ BtKV, const bf16* __restrict__ BtQS,
    const float* __restrict__ bk, const float* __restrict__ bv,
    const float* __restrict__ bq, const float* __restrict__ bs,
    bf16* __restrict__ Ckv, size_t CkvStr,
    float* __restrict__ Cqs, size_t CqsStr,
    int nbKV)
{
    constexpr int K = 256, Nh = 256, N = 512, KC = K / 32;
    __shared__ bf16 A_s[64 * K];

    const int z = blockIdx.z;
    const bool isKV = (int)blockIdx.x < nbKV;
    const int bx = isKV ? blockIdx.x : blockIdx.x - nbKV;
    const int M = isKV ? N0 : N1;
    const bf16* Bt = (isKV ? BtKV : BtQS) + (size_t)z * N * K;
    const float* b1 = (isKV ? bk : bq) + (size_t)z * Nh;
    const float* b2 = (isKV ? bv : bs) + (size_t)z * Nh;

    const int lane = threadIdx.x & 63;
    const int w = threadIdx.x >> 6;             // 0..7 (col group)
    const int lm = lane & 15;
    const int q = lane >> 4;
    const int mbase = bx * 64;

    // ---- gather-stage A (64 x 256): LDS chunk c of row r holds global chunk c^(r&7) ----
    {
        const int* idz = n_ids + (size_t)z * N0;
        #pragma unroll 4
        for (int j = 0; j < 8; j++) {
            int row = w * 8 + j;
            int grow = mbase + row; grow = grow < M ? grow : M - 1;
            int gidx = idz[grow];               // wave-uniform -> scalar load
            float4 v = *(const float4*)(F + (size_t)gidx * H + lane * 4);
            bf16 t4[4] = {(bf16)v.x, (bf16)v.y, (bf16)v.z, (bf16)v.w};
            int c16 = (lane >> 1) ^ (row & 7);  // 16B bf16 chunk, XOR swizzle
            *(short4v*)(A_s + (size_t)row * K + c16 * 8 + (lane & 1) * 4) =
                *(const short4v*)t4;
        }
    }

    const bf16* bp[4];
    #pragma unroll
    for (int ni = 0; ni < 4; ni++)
        bp[ni] = Bt + (size_t)(w * 64 + ni * 16 + lm) * K + q * 8;

    floatx4 acc[4][4];
    #pragma unroll
    for (int i = 0; i < 4; i++)
        #pragma unroll
        for (int j = 0; j < 4; j++)
            acc[i][j] = (floatx4){0.f, 0.f, 0.f, 0.f};

    // 3-deep B ring preload (L2-resident weights), issued before the barrier
    short8 br0[4], br1[4], br2[4];
    #pragma unroll
    for (int ni = 0; ni < 4; ni++) br0[ni] = *(const short8*)(bp[ni]);
    #pragma unroll
    for (int ni = 0; ni < 4; ni++) br1[ni] = *(const short8*)(bp[ni] + 32);
    #pragma unroll
    for (int ni = 0; ni < 4; ni++) br2[ni] = *(const short8*)(bp[ni] + 64);

    __syncthreads();

    #pragma unroll
    for (int kc = 0; kc < KC; kc++) {
        short8 bc[4];
        #pragma unroll
        for (int ni = 0; ni < 4; ni++) {
            bc[ni] = br0[ni]; br0[ni] = br1[ni]; br1[ni] = br2[ni];
        }
        if (kc + 3 < KC) {
            #pragma unroll
            for (int ni = 0; ni < 4; ni++)
                br2[ni] = *(const short8*)(bp[ni] + (kc + 3) * 32);
        }
        short8 af[4];
        #pragma unroll
        for (int mi = 0; mi < 4; mi++) {
            int row = mi * 16 + lm;
            af[mi] = *(const short8*)(A_s + row * K + (((kc * 4 + q) ^ (lm & 7)) * 8));
        }
        #pragma unroll
        for (int mi = 0; mi < 4; mi++)
            #pragma unroll
            for (int ni = 0; ni < 4; ni++)
                acc[mi][ni] = __builtin_amdgcn_mfma_f32_16x16x32_bf16(
                    af[mi], bc[ni], acc[mi][ni], 0, 0, 0);
    }

    // C/D layout: col = lane&15, row = (lane>>4)*4 + reg  [m89]
    if (isKV) {
        bf16* C = Ckv + (size_t)z * CkvStr;
        __syncthreads();                        // A_s dead; reuse as transpose stage
        bf16* stg = A_s + (size_t)w * (16 * 72);    // 8 waves x 2304B = 18KB < 32KB
        #pragma unroll
        for (int p = 0; p < 4; p++) {           // p == mi
            #pragma unroll
            for (int ni = 0; ni < 4; ni++) {
                int colg = w * 64 + ni * 16 + lm;
                float bias = (colg < Nh) ? b1[colg] : b2[colg - Nh];
                #pragma unroll
                for (int rg = 0; rg < 4; rg++)
                    stg[(q * 4 + rg) * 72 + ni * 16 + lm] = (bf16)(acc[p][ni][rg] + bias);
            }
            #pragma unroll
            for (int it = 0; it < 2; it++) {
                int rl = it * 8 + (lane >> 3);
                int grow = mbase + p * 16 + rl;
                short8 vv = *(const short8*)(stg + rl * 72 + (lane & 7) * 8);
                if (grow < M)
                    *(short8*)(C + (size_t)grow * N + w * 64 + (lane & 7) * 8) = vv;
            }
        }
    } else {
        float* C = Cqs + (size_t)z * CqsStr;
        #pragma unroll
        for (int ni = 0; ni < 4; ni++) {
            int colg = w * 64 + ni * 16 + lm;
            float bias = (colg < Nh) ? b1[colg] : b2[colg - Nh];
            #pragma unroll
            for (int mi = 0; mi < 4; mi++) {
                int rb = mbase + mi * 16 + q * 4;
                #pragma unroll
                for (int rg = 0; rg < 4; rg++) {
                    int rr = rb + rg;
                    if (rr < M) C[(size_t)rr * N + colg] = acc[mi][ni][rg] + bias;
                }
            }
        }
    }
}

// ---------------- dual-output LDS-A MFMA GEMM (L2/L3) ----------------
// NORM mode (L2): (x-mu)*istd -> ELU applied during A-staging (reg-staged bf16,
// same XOR-swizzled LDS layout; K-loop/epilogue untouched).
template<int K, bool NORM>
__global__ __launch_bounds__(256, 4) void gemm_dual(
    const bf16* __restrict__ A, size_t Astr,
    const float* __restrict__ muv, const float* __restrict__ istdv,
    const bf16* __restrict__ BtKV, const bf16* __restrict__ BtQS,
    const float* __restrict__ bk, const float* __restrict__ bv,
    const float* __restrict__ bq, const float* __restrict__ bs, int Nh,
    bf16* __restrict__ Ckv, size_t CkvStr, int Mkv,
    float* __restrict__ Cqs, size_t CqsStr, int Mqs,
    int nbKV)
{
    constexpr int KC = K / 32;
    constexpr int CPR = K / 8;                  // 16B chunks per row
    constexpr int LOG_CPR = (K == 256) ? 5 : 4;
    constexpr int RPI = 64 / CPR;               // rows per staging issue
    constexpr int ISSUES = 16 / RPI;            // per wave (16 rows/wave)
    const int N = 2 * Nh;
    __shared__ bf16 A_s[64 * K];

    const int z = blockIdx.z;
    const bool isKV = (int)blockIdx.x < nbKV;
    const int bx = isKV ? blockIdx.x : blockIdx.x - nbKV;
    const int M = isKV ? Mkv : Mqs;
    const bf16* Bt = (isKV ? BtKV : BtQS) + (size_t)z * N * K;
    const float* b1 = (isKV ? bk : bq) + (size_t)z * Nh;
    const float* b2 = (isKV ? bv : bs) + (size_t)z * Nh;
    A += (size_t)z * Astr;

    const int lane = threadIdx.x & 63;
    const int w = threadIdx.x >> 6;             // 0..3 (col group)
    const int lm = lane & 15;
    const int q = lane >> 4;
    const int mbase = bx * 64;
    const int n0 = blockIdx.y * 256;

    // ---- stage A tile (64 x K): LDS chunk c of row r holds global chunk c^(r&7) ----
    {
        const int ch = lane & (CPR - 1);
        const int rsub = lane >> LOG_CPR;
        if constexpr (NORM) {
            const float* muz = muv + (size_t)z * K;
            const float* isz = istdv + (size_t)z * K;
            #pragma unroll
            for (int i = 0; i < ISSUES; i++) {
                int row = w * 16 + i * RPI + rsub;
                int grow = mbase + row; grow = grow < M ? grow : M - 1;
                int gch = ch ^ (row & 7);
                short8 raw = *(const short8*)(A + (size_t)grow * K + gch * 8);
                float4 m0 = *(const float4*)(muz + gch * 8);
                float4 m1 = *(const float4*)(muz + gch * 8 + 4);
                float4 i0 = *(const float4*)(isz + gch * 8);
                float4 i1 = *(const float4*)(isz + gch * 8 + 4);
                float mm[8] = {m0.x, m0.y, m0.z, m0.w, m1.x, m1.y, m1.z, m1.w};
                float ii[8] = {i0.x, i0.y, i0.z, i0.w, i1.x, i1.y, i1.z, i1.w};
                bf16 outb[8];
                #pragma unroll
                for (int j = 0; j < 8; j++) {
                    union { unsigned u; float f; } cv;
                    cv.u = ((unsigned)(unsigned short)raw[j]) << 16;
                    float t = (cv.f - mm[j]) * ii[j];
                    t = t > 0.f ? t : __expf(t) - 1.0f;
                    outb[j] = (bf16)t;
                }
                *(short8*)(A_s + (size_t)row * K + ch * 8) = *(const short8*)outb;
            }
        } else {
            #pragma unroll
            for (int i = 0; i < ISSUES; i++) {
                int row = w * 16 + i * RPI + rsub;
                int grow = mbase + row; grow = grow < M ? grow : M - 1;
                int gch = ch ^ (row & 7);
                load_lds16(A + (size_t)grow * K + gch * 8,
                           A_s + (size_t)(w * 16 + i * RPI) * K);
            }
        }
    }

    const bf16* bp[4];
    #pragma unroll
    for (int ni = 0; ni < 4; ni++)
        bp[ni] = Bt + (size_t)(n0 + w * 64 + ni * 16 + lm) * K + q * 8;

    floatx4 acc[4][4];
    #pragma unroll
    for (int i = 0; i < 4; i++)
        #pragma unroll
        for (int j = 0; j < 4; j++)
            acc[i][j] = (floatx4){0.f, 0.f, 0.f, 0.f};

    // 3-deep B ring preload, issued before the barrier (overlaps staging drain)
    short8 br0[4], br1[4], br2[4];
    #pragma unroll
    for (int ni = 0; ni < 4; ni++) br0[ni] = *(const short8*)(bp[ni]);
    #pragma unroll
    for (int ni = 0; ni < 4; ni++) br1[ni] = *(const short8*)(bp[ni] + 32);
    #pragma unroll
    for (int ni = 0; ni < 4; ni++) br2[ni] = *(const short8*)(bp[ni] + 64);

    __syncthreads();

    #pragma unroll
    for (int kc = 0; kc < KC; kc++) {
        short8 bc[4];
        #pragma unroll
        for (int ni = 0; ni < 4; ni++) {
            bc[ni] = br0[ni]; br0[ni] = br1[ni]; br1[ni] = br2[ni];
        }
        if (kc + 3 < KC) {
            #pragma unroll
            for (int ni = 0; ni < 4; ni++)
                br2[ni] = *(const short8*)(bp[ni] + (kc + 3) * 32);
        }
        short8 af[4];
        #pragma unroll
        for (int mi = 0; mi < 4; mi++) {
            int row = mi * 16 + lm;
            af[mi] = *(const short8*)(A_s + row * K + (((kc * 4 + q) ^ (lm & 7)) * 8));
        }
        #pragma unroll
        for (int mi = 0; mi < 4; mi++)
            #pragma unroll
            for (int ni = 0; ni < 4; ni++)
                acc[mi][ni] = __builtin_amdgcn_mfma_f32_16x16x32_bf16(
                    af[mi], bc[ni], acc[mi][ni], 0, 0, 0);
    }

    // C/D layout: col = lane&15, row = (lane>>4)*4 + reg  [m89]
    if (isKV) {
        bf16* C = Ckv + (size_t)z * CkvStr;
        __syncthreads();                        // A_s dead; reuse as transpose stage
        bf16* stg = A_s + (size_t)w * (16 * 72);
        #pragma unroll
        for (int p = 0; p < 4; p++) {           // p == mi
            #pragma unroll
            for (int ni = 0; ni < 4; ni++) {
                int colg = n0 + w * 64 + ni * 16 + lm;
                float bias = (colg < Nh) ? b1[colg] : b2[colg - Nh];
                #pragma unroll
                for (int rg = 0; rg < 4; rg++)
                    stg[(q * 4 + rg) * 72 + ni * 16 + lm] = (bf16)(acc[p][ni][rg] + bias);
            }
            #pragma unroll
            for (int it = 0; it < 2; it++) {
                int rl = it * 8 + (lane >> 3);
                int grow = mbase + p * 16 + rl;
                short8 vv = *(const short8*)(stg + rl * 72 + (lane & 7) * 8);
                if (grow < M)
                    *(short8*)(C + (size_t)grow * N + n0 + w * 64 + (lane & 7) * 8) = vv;
            }
        }
    } else {
        float* C = Cqs + (size_t)z * CqsStr;
        #pragma unroll
        for (int ni = 0; ni < 4; ni++) {
            int colg = n0 + w * 64 + ni * 16 + lm;
            float bias = (colg < Nh) ? b1[colg] : b2[colg - Nh];
            #pragma unroll
            for (int mi = 0; mi < 4; mi++) {
                int rb = mbase + mi * 16 + q * 4;
                #pragma unroll
                for (int rg = 0; rg < 4; rg++) {
                    int rr = rb + rg;
                    if (rr < M) C[(size_t)rr * N + colg] = acc[mi][ni][rg] + bias;
                }
            }
        }
    }
}

// ---------------- all weight packs in ONE dispatch (job via blockIdx.z) ----------
__global__ __launch_bounds__(256) void pack_all(
    const float* __restrict__ l1_Wk, const float* __restrict__ l1_Wv,
    const float* __restrict__ l1_Wq, const float* __restrict__ l1_Ws,
    const float* __restrict__ l2_Wk, const float* __restrict__ l2_Wv,
    const float* __restrict__ l2_Wq, const float* __restrict__ l2_Ws,
    const float* __restrict__ l3_Wk, const float* __restrict__ l3_Wv,
    const float* __restrict__ l3_Wq, const float* __restrict__ l3_Ws,
    bf16* __restrict__ Wkv1, bf16* __restrict__ Wqs1,
    bf16* __restrict__ Wkv2, bf16* __restrict__ Wqs2,
    bf16* __restrict__ Wkv3, bf16* __restrict__ Wqs3)
{
    int job = blockIdx.z, r = blockIdx.y, nn = blockIdx.x, k = threadIdx.x;
    const float *W1, *W2; bf16* Wt; int K, Nh;
    switch (job) {
        case 0: W1 = l1_Wk; W2 = l1_Wv; Wt = Wkv1; K = 256; Nh = 256; break;
        case 1: W1 = l1_Wq; W2 = l1_Ws; Wt = Wqs1; K = 256; Nh = 256; break;
        case 2: W1 = l2_Wk; W2 = l2_Wv; Wt = Wkv2; K = 256; Nh = 128; break;
        case 3: W1 = l2_Wq; W2 = l2_Ws; Wt = Wqs2; K = 256; Nh = 128; break;
        case 4: W1 = l3_Wk; W2 = l3_Wv; Wt = Wkv3; K = 128; Nh = 256; break;
        default: W1 = l3_Wq; W2 = l3_Ws; Wt = Wqs3; K = 128; Nh = 256; break;
    }
    if (nn >= 2 * Nh || k >= K) return;
    size_t wstride = (size_t)K * Nh;
    float v = (nn < Nh) ? W1[(size_t)r * wstride + (size_t)k * Nh + nn]
                        : W2[(size_t)r * wstride + (size_t)k * Nh + (nn - Nh)];
    Wt[(size_t)r * 2 * wstride + (size_t)nn * K + k] = (bf16)v;
}

// ---------------- fused attention + gated skip ----------------
// v-prefetch: both random-access rounds issued back-to-back (in-order vmcnt
// keeps k-consumes unaffected; v latency hides under softmax math).
template<int CPL, int HEADS>   // hc = CPL*64
__global__ __launch_bounds__(256) void attn_gate(
    const float* __restrict__ qs, size_t qsStr,
    const bf16* __restrict__ kv, size_t kvStr,
    const int* __restrict__ src,
    const float* __restrict__ Wb,
    float* __restrict__ yf, size_t yfStr,
    bf16* __restrict__ yb, size_t ybStr,
    int ndst, float scale)
{
    constexpr int hc = CPL * 64;
    constexpr int LPH = 64 / HEADS;
    const int z = blockIdx.y;
    int lane = threadIdx.x & 63;
    int d = blockIdx.x * 4 + (threadIdx.x >> 6);
    if (d >= ndst) return;
    qs += (size_t)z * qsStr;
    kv += (size_t)z * kvStr;
    src += (size_t)z * ndst * FAN;
    Wb += (size_t)z * 3 * hc;

    const float* qp = qs + (size_t)d * (2 * hc) + lane * CPL;
    float qv[CPL], xv[CPL];
    if constexpr (CPL == 2) {
        float2 a = *(const float2*)qp;
        float2 b = *(const float2*)(qp + hc);
        qv[0] = a.x; qv[1] = a.y; xv[0] = b.x; xv[1] = b.y;
    } else {
        float4 a = *(const float4*)qp;
        float4 b = *(const float4*)(qp + hc);
        qv[0] = a.x; qv[1] = a.y; qv[2] = a.z; qv[3] = a.w;
        xv[0] = b.x; xv[1] = b.y; xv[2] = b.z; xv[3] = b.w;
    }
    const int* sp = src + (size_t)d * FAN;
    int sidx[FAN];
    #pragma unroll
    for (int e = 0; e < FAN; e++) sidx[e] = sp[e];

    // partial dots (all k loads issued before the shuffle phase)
    float part[FAN];
    #pragma unroll
    for (int e = 0; e < FAN; e++) {
        const bf16* kp = kv + (size_t)sidx[e] * (2 * hc) + lane * CPL;
        if constexpr (CPL == 2) {
            float2 kf = cvt_bf2(*(const unsigned*)kp);
            part[e] = qv[0] * kf.x + qv[1] * kf.y;
        } else {
            uint2 u = *(const uint2*)kp;
            float2 k0 = cvt_bf2(u.x), k1 = cvt_bf2(u.y);
            part[e] = qv[0] * k0.x + qv[1] * k0.y + qv[2] * k1.x + qv[3] * k1.y;
        }
    }

    // prefetch v rows into regs (overlaps softmax below)
    uint2 vreg[FAN];
    #pragma unroll
    for (int e = 0; e < FAN; e++) {
        const bf16* vp = kv + (size_t)sidx[e] * (2 * hc) + hc + lane * CPL;
        if constexpr (CPL == 2) vreg[e].x = *(const unsigned*)vp;
        else                    vreg[e]   = *(const uint2*)vp;
    }

    float logit[FAN], mx = -1e30f;
    #pragma unroll
    for (int e = 0; e < FAN; e++) {
        float dt = part[e];
        #pragma unroll
        for (int off = LPH / 2; off > 0; off >>= 1) dt += __shfl_xor(dt, off, 64);
        dt *= scale;
        logit[e] = dt;
        mx = fmaxf(mx, dt);
    }
    float zsum = 0.f, p[FAN];
    #pragma unroll
    for (int e = 0; e < FAN; e++) { p[e] = __expf(logit[e] - mx); zsum += p[e]; }
    float inv = 1.f / zsum;

    float ov[CPL];
    #pragma unroll
    for (int j = 0; j < CPL; j++) ov[j] = 0.f;
    #pragma unroll
    for (int e = 0; e < FAN; e++) {
        if constexpr (CPL == 2) {
            float2 vf = cvt_bf2(vreg[e].x);
            ov[0] += p[e] * vf.x; ov[1] += p[e] * vf.y;
        } else {
            float2 v0 = cvt_bf2(vreg[e].x), v1 = cvt_bf2(vreg[e].y);
            ov[0] += p[e] * v0.x; ov[1] += p[e] * v0.y;
            ov[2] += p[e] * v1.x; ov[3] += p[e] * v1.y;
        }
    }
    #pragma unroll
    for (int j = 0; j < CPL; j++) ov[j] *= inv;

    // gated skip
    float s = 0.f;
    #pragma unroll
    for (int j = 0; j < CPL; j++) {
        int c = lane * CPL + j;
        s += ov[j] * Wb[c] + xv[j] * Wb[hc + c] + (ov[j] - xv[j]) * Wb[2 * hc + c];
    }
    #pragma unroll
    for (int off = 32; off > 0; off >>= 1) s += __shfl_xor(s, off, 64);
    float g = 1.f / (1.f + __expf(-s));

    float yv[CPL];
    #pragma unroll
    for (int j = 0; j < CPL; j++) yv[j] = g * xv[j] + (1.f - g) * ov[j];

    if (yf) {
        float* op = yf + (size_t)z * yfStr + (size_t)d * hc + lane * CPL;
        if constexpr (CPL == 2) *(float2*)op = make_float2(yv[0], yv[1]);
        else *(float4*)op = make_float4(yv[0], yv[1], yv[2], yv[3]);
    }
    if (yb) {
        bf16* op = yb + (size_t)z * ybStr + (size_t)d * hc + lane * CPL;
        bf16 tmp[CPL];
        #pragma unroll
        for (int j = 0; j < CPL; j++) tmp[j] = (bf16)yv[j];
        if constexpr (CPL == 2) *(short2v*)op = *(const short2v*)tmp;
        else *(short4v*)op = *(const short4v*)tmp;
    }
}

// ---------------- column stats (bf16 input), relation via blockIdx.y ----------------
__global__ __launch_bounds__(256) void colstat_partial(
    const bf16* __restrict__ x, size_t xStr, int M,
    float* __restrict__ ps, float* __restrict__ pss)
{
    int z = blockIdx.y;
    const bf16* xp = x + (size_t)z * xStr;
    int f = threadIdx.x;
    int b = blockIdx.x;   // 64
    float s = 0.f, ss = 0.f;
    for (int r = b; r < M; r += 64) {
        float v = (float)xp[(size_t)r * H + f];
        s += v; ss += v * v;
    }
    ps[((size_t)z * 64 + b) * H + f] = s;
    pss[((size_t)z * 64 + b) * H + f] = ss;
}

// tiny: reduce ps/pss (64 partials) -> per-column mu, istd (3 x H each)
__global__ __launch_bounds__(256) void colstats_final(
    const float* __restrict__ ps, const float* __restrict__ pss, int M,
    float* __restrict__ muv, float* __restrict__ istdv)
{
    int z = blockIdx.y;
    int c = threadIdx.x;
    float s = 0.f, ss = 0.f;
    #pragma unroll 8
    for (int b = 0; b < 64; b++) {
        s += ps[((size_t)z * 64 + b) * H + c];
        ss += pss[((size_t)z * 64 + b) * H + c];
    }
    float mu = s / M;
    muv[(size_t)z * H + c] = mu;
    istdv[(size_t)z * H + c] = rsqrtf(ss / M - mu * mu + 1e-5f);
}

// ---------------- semantic attention across the 3 relations ----------------
// shuffle-based score reduction: 7 barriers/block (was 27 with the LDS tree)
__global__ __launch_bounds__(256) void semantic_kernel(
    const float* __restrict__ emb,   // (3, N3, H)
    const float* __restrict__ Wo, const float* __restrict__ bo,
    const float* __restrict__ uo, const float* __restrict__ rl,
    float* __restrict__ outp)
{
    __shared__ float m_s[3][H];
    __shared__ float wsum[4];
    __shared__ float score_s[3];
    int n = blockIdx.x, c = threadIdx.x;
    for (int r = 0; r < 3; r++)
        m_s[r][c] = emb[((size_t)r * N3 + n) * H + c] * rl[r];
    __syncthreads();
    for (int r = 0; r < 3; r++) {
        float t = bo[c];
        for (int k2 = 0; k2 < H; k2++) t += m_s[r][k2] * Wo[k2 * H + c];
        float v = tanhf(t) * uo[c];
        #pragma unroll
        for (int off = 32; off > 0; off >>= 1) v += __shfl_xor(v, off, 64);
        if ((c & 63) == 0) wsum[c >> 6] = v;
        __syncthreads();
        if (c == 0) score_s[r] = wsum[0] + wsum[1] + wsum[2] + wsum[3];
        __syncthreads();
    }
    float s0 = score_s[0], s1 = score_s[1], s2 = score_s[2];
    float mx = fmaxf(s0, fmaxf(s1, s2));
    float e0 = __expf(s0 - mx), e1 = __expf(s1 - mx), e2 = __expf(s2 - mx);
    float zi = 1.0f / (e0 + e1 + e2);
    outp[(size_t)n * H + c] = (m_s[0][c] * e0 + m_s[1][c] * e1 + m_s[2][c] * e2) * zi;
}

extern "C" void kernel_launch(void* const* d_in, const int* in_sizes, int n_in,
                              void* d_out, int out_size, void* d_ws, size_t ws_size,
                              hipStream_t stream) {
    const float* features = (const float*)d_in[0];
    const int*   n_ids    = (const int*)d_in[1];
    const int*   src1     = (const int*)d_in[2];
    const int*   src2     = (const int*)d_in[4];
    const int*   src3     = (const int*)d_in[6];
    const float* l1_Wq = (const float*)d_in[8];
    const float* l1_Wk = (const float*)d_in[9];
    const float* l1_Wv = (const float*)d_in[10];
    const float* l1_Ws = (const float*)d_in[11];
    const float* l1_bq = (const float*)d_in[12];
    const float* l1_bk = (const float*)d_in[13];
    const float* l1_bv = (const float*)d_in[14];
    const float* l1_bs = (const float*)d_in[15];
    const float* l1_Wb = (const float*)d_in[16];
    const float* l2_Wq = (const float*)d_in[17];
    const float* l2_Wk = (const float*)d_in[18];
    const float* l2_Wv = (const float*)d_in[19];
    const float* l2_Ws = (const float*)d_in[20];
    const float* l2_bq = (const float*)d_in[21];
    const float* l2_bk = (const float*)d_in[22];
    const float* l2_bv = (const float*)d_in[23];
    const float* l2_bs = (const float*)d_in[24];
    const float* l2_Wb = (const float*)d_in[25];
    const float* l3_Wq = (const float*)d_in[26];
    const float* l3_Wk = (const float*)d_in[27];
    const float* l3_Wv = (const float*)d_in[28];
    const float* l3_Ws = (const float*)d_in[29];
    const float* l3_bq = (const float*)d_in[30];
    const float* l3_bk = (const float*)d_in[31];
    const float* l3_bv = (const float*)d_in[32];
    const float* l3_bs = (const float*)d_in[33];
    const float* l3_Wb = (const float*)d_in[34];
    const float* w_omega = (const float*)d_in[35];
    const float* b_omega = (const float*)d_in[36];
    const float* u_omega = (const float*)d_in[37];
    const float* rl      = (const float*)d_in[38];

    // ---- workspace layout: per-relation buffers ----
    float* ws = (float*)d_ws;
    size_t o = 0;
    float* emb = ws + o; o += (size_t)3 * N3 * H;
    float* qs1 = ws + o; o += (size_t)3 * N1 * 512;
    float* qs2 = ws + o; o += (size_t)3 * N2 * 256;
    float* qs3 = ws + o; o += (size_t)3 * N3 * 512;
    float* ps  = ws + o; o += (size_t)3 * 64 * H;
    float* pss = ws + o; o += (size_t)3 * 64 * H;
    float* muv   = ws + o; o += (size_t)3 * H;
    float* istdv = ws + o; o += (size_t)3 * H;

    bf16* bws = (bf16*)(ws + o);
    size_t b = 0;
    bf16* kv1 = bws + b; b += (size_t)3 * N0 * 512;
    bf16* x1b = bws + b; b += (size_t)3 * N1 * 256;
    bf16* kv2 = bws + b; b += (size_t)3 * N1 * 256;
    bf16* x2b = bws + b; b += (size_t)3 * N2 * 128;
    bf16* kv3 = bws + b; b += (size_t)3 * N2 * 512;
    bf16* Wkv1 = bws + b; b += (size_t)3 * 512 * H;
    bf16* Wqs1 = bws + b; b += (size_t)3 * 512 * H;
    bf16* Wkv2 = bws + b; b += (size_t)3 * 256 * H;
    bf16* Wqs2 = bws + b; b += (size_t)3 * 256 * H;
    bf16* Wkv3 = bws + b; b += (size_t)3 * 512 * 128;
    bf16* Wqs3 = bws + b; b += (size_t)3 * 512 * 128;

    const float sc128 = 0.088388347648318447f;  // 1/sqrt(128)
    const float sc256 = 0.0625f;                // 1/sqrt(256)

    // ---- all weight packs, one dispatch ----
    pack_all<<<dim3(512, 3, 6), 256, 0, stream>>>(
        l1_Wk, l1_Wv, l1_Wq, l1_Ws, l2_Wk, l2_Wv, l2_Wq, l2_Ws,
        l3_Wk, l3_Wv, l3_Wq, l3_Ws, Wkv1, Wqs1, Wkv2, Wqs2, Wkv3, Wqs3);

    // ---- L1 (gather-fused, single-pass): 64x512 tile, 512 thr ----
    {
        int nbKV = (N0 + 63) / 64, nbQS = (N1 + 63) / 64;
        gemm_l1_fused<<<dim3(nbKV + nbQS, 1, 3), 512, 0, stream>>>(
            features, n_ids, Wkv1, Wqs1, l1_bk, l1_bv, l1_bq, l1_bs,
            kv1, (size_t)N0 * 512, qs1, (size_t)N1 * 512, nbKV);
    }
    attn_gate<4, 2><<<dim3((N1 + 3) / 4, 3), 256, 0, stream>>>(
        qs1, (size_t)N1 * 512, kv1, (size_t)N0 * 512, src1, l1_Wb,
        (float*)nullptr, 0, x1b, (size_t)N1 * 256, N1, sc128);
    colstat_partial<<<dim3(64, 3), 256, 0, stream>>>(x1b, (size_t)N1 * 256, N1, ps, pss);
    colstats_final<<<dim3(1, 3), 256, 0, stream>>>(ps, pss, N1, muv, istdv);

    // ---- L2 (norm+ELU folded into A-staging): din=256, hc=128, N=256, K=256 ----
    {
        int nbKV = (N1 + 63) / 64, nbQS = (N2 + 63) / 64;
        gemm_dual<256, true><<<dim3(nbKV + nbQS, 1, 3), 256, 0, stream>>>(
            x1b, (size_t)N1 * 256, muv, istdv,
            Wkv2, Wqs2, l2_bk, l2_bv, l2_bq, l2_bs, 128,
            kv2, (size_t)N1 * 256, N1, qs2, (size_t)N2 * 256, N2, nbKV);
    }
    attn_gate<2, 1><<<dim3((N2 + 3) / 4, 3), 256, 0, stream>>>(
        qs2, (size_t)N2 * 256, kv2, (size_t)N1 * 256, src2, l2_Wb,
        (float*)nullptr, 0, x2b, (size_t)N2 * 128, N2, sc128);

    // ---- L3: din=128, heads=1, ch=256, hc=256, N=512, K=128 ----
    {
        int nbKV = (N2 + 63) / 64, nbQS = (N3 + 63) / 64;
        gemm_dual<128, false><<<dim3(nbKV + nbQS, 2, 3), 256, 0, stream>>>(
            x2b, (size_t)N2 * 128, (const float*)nullptr, (const float*)nullptr,
            Wkv3, Wqs3, l3_bk, l3_bv, l3_bq, l3_bs, 256,
            kv3, (size_t)N2 * 512, N2, qs3, (size_t)N3 * 512, N3, nbKV);
    }
    attn_gate<4, 1><<<dim3((N3 + 3) / 4, 3), 256, 0, stream>>>(
        qs3, (size_t)N3 * 512, kv3, (size_t)N2 * 512, src3, l3_Wb,
        emb, (size_t)N3 * H, (bf16*)nullptr, 0, N3, sc256);

    semantic_kernel<<<N3, 256, 0, stream>>>(emb, w_omega, b_omega, u_omega, rl, (float*)d_out);
}

// Round 10
// 556.361 us; speedup vs baseline: 4.3953x; 1.0469x over previous
//
#include <hip/hip_runtime.h>
#include <hip/hip_bf16.h>
#include <math.h>

#define H 256
#define N0 50000
#define N1 10000
#define N2 4000
#define N3 1024
#define FAN 16

typedef __hip_bfloat16 bf16;
typedef __attribute__((ext_vector_type(8))) short short8;
typedef __attribute__((ext_vector_type(4))) short short4v;
typedef __attribute__((ext_vector_type(2))) short short2v;
typedef __attribute__((ext_vector_type(4))) float floatx4;

typedef const __attribute__((address_space(1))) void* gas_ptr;
typedef __attribute__((address_space(3))) void* las_ptr;

__device__ __forceinline__ void load_lds16(const void* g, void* l) {
    __builtin_amdgcn_global_load_lds((gas_ptr)g, (las_ptr)l, 16, 0, 0);
}

__device__ __forceinline__ float2 cvt_bf2(unsigned u) {
    union { unsigned q; float f; } lo, hi;
    lo.q = u << 16; hi.q = u & 0xffff0000u;
    return make_float2(lo.f, hi.f);
}

// ---------------- L1 gather-fused GEMM: 64x512 tile, 512 thr (8 waves) ----------------
// (round-6..9 verified: ~170us, FETCH 107MB = features read ~once; gather pass deleted.)
// RULE (round-8 lesson): never convert a column-reduction into same-address
// global atomics when rows >> 1000 — 10k serialized atomics/address = 1.9ms.
// Round-10: qs epilogue LDS-coalesced — scalar f32 scatter (64B per 16-lane
// group, 4 rows/wave) caused ~29MB measured write amplification (244 vs 215
// logical); wave-local 16x64 f32 stage -> float4 stores = 256B contiguous/row.
__global__ __launch_bounds__(512, 4) void gemm_l1_fused(
    const float* __restrict__ F, const int* __restrict__ n_ids,
    const bf16* __restrict__ BtKV, const bf16* __restrict__ BtQS,
    const float* __restrict__ bk, const float* __restrict__ bv,
    const float* __restrict__ bq, const float* __restrict__ bs,
    bf16* __restrict__ Ckv, size_t CkvStr,
    float* __restrict__ Cqs, size_t CqsStr,
    int nbKV)
{
    constexpr int K = 256, Nh = 256, N = 512, KC = K / 32;
    __shared__ bf16 A_s[64 * K];

    const int z = blockIdx.z;
    const bool isKV = (int)blockIdx.x < nbKV;
    const int bx = isKV ? blockIdx.x : blockIdx.x - nbKV;
    const int M = isKV ? N0 : N1;
    const bf16* Bt = (isKV ? BtKV : BtQS) + (size_t)z * N * K;
    const float* b1 = (isKV ? bk : bq) + (size_t)z * Nh;
    const float* b2 = (isKV ? bv : bs) + (size_t)z * Nh;

    const int lane = threadIdx.x & 63;
    const int w = threadIdx.x >> 6;             // 0..7 (col group)
    const int lm = lane & 15;
    const int q = lane >> 4;
    const int mbase = bx * 64;

    // ---- gather-stage A (64 x 256): LDS chunk c of row r holds global chunk c^(r&7) ----
    {
        const int* idz = n_ids + (size_t)z * N0;
        #pragma unroll 4
        for (int j = 0; j < 8; j++) {
            int row = w * 8 + j;
            int grow = mbase + row; grow = grow < M ? grow : M - 1;
            int gidx = idz[grow];               // wave-uniform -> scalar load
            float4 v = *(const float4*)(F + (size_t)gidx * H + lane * 4);
            bf16 t4[4] = {(bf16)v.x, (bf16)v.y, (bf16)v.z, (bf16)v.w};
            int c16 = (lane >> 1) ^ (row & 7);  // 16B bf16 chunk, XOR swizzle
            *(short4v*)(A_s + (size_t)row * K + c16 * 8 + (lane & 1) * 4) =
                *(const short4v*)t4;
        }
    }

    const bf16* bp[4];
    #pragma unroll
    for (int ni = 0; ni < 4; ni++)
        bp[ni] = Bt + (size_t)(w * 64 + ni * 16 + lm) * K + q * 8;

    floatx4 acc[4][4];
    #pragma unroll
    for (int i = 0; i < 4; i++)
        #pragma unroll
        for (int j = 0; j < 4; j++)
            acc[i][j] = (floatx4){0.f, 0.f, 0.f, 0.f};

    // 3-deep B ring preload (L2-resident weights), issued before the barrier
    short8 br0[4], br1[4], br2[4];
    #pragma unroll
    for (int ni = 0; ni < 4; ni++) br0[ni] = *(const short8*)(bp[ni]);
    #pragma unroll
    for (int ni = 0; ni < 4; ni++) br1[ni] = *(const short8*)(bp[ni] + 32);
    #pragma unroll
    for (int ni = 0; ni < 4; ni++) br2[ni] = *(const short8*)(bp[ni] + 64);

    __syncthreads();

    #pragma unroll
    for (int kc = 0; kc < KC; kc++) {
        short8 bc[4];
        #pragma unroll
        for (int ni = 0; ni < 4; ni++) {
            bc[ni] = br0[ni]; br0[ni] = br1[ni]; br1[ni] = br2[ni];
        }
        if (kc + 3 < KC) {
            #pragma unroll
            for (int ni = 0; ni < 4; ni++)
                br2[ni] = *(const short8*)(bp[ni] + (kc + 3) * 32);
        }
        short8 af[4];
        #pragma unroll
        for (int mi = 0; mi < 4; mi++) {
            int row = mi * 16 + lm;
            af[mi] = *(const short8*)(A_s + row * K + (((kc * 4 + q) ^ (lm & 7)) * 8));
        }
        #pragma unroll
        for (int mi = 0; mi < 4; mi++)
            #pragma unroll
            for (int ni = 0; ni < 4; ni++)
                acc[mi][ni] = __builtin_amdgcn_mfma_f32_16x16x32_bf16(
                    af[mi], bc[ni], acc[mi][ni], 0, 0, 0);
    }

    // C/D layout: col = lane&15, row = (lane>>4)*4 + reg  [m89]
    if (isKV) {
        bf16* C = Ckv + (size_t)z * CkvStr;
        __syncthreads();                        // A_s dead; reuse as transpose stage
        bf16* stg = A_s + (size_t)w * (16 * 72);    // 8 waves x 2304B = 18KB < 32KB
        #pragma unroll
        for (int p = 0; p < 4; p++) {           // p == mi
            #pragma unroll
            for (int ni = 0; ni < 4; ni++) {
                int colg = w * 64 + ni * 16 + lm;
                float bias = (colg < Nh) ? b1[colg] : b2[colg - Nh];
                #pragma unroll
                for (int rg = 0; rg < 4; rg++)
                    stg[(q * 4 + rg) * 72 + ni * 16 + lm] = (bf16)(acc[p][ni][rg] + bias);
            }
            #pragma unroll
            for (int it = 0; it < 2; it++) {
                int rl = it * 8 + (lane >> 3);
                int grow = mbase + p * 16 + rl;
                short8 vv = *(const short8*)(stg + rl * 72 + (lane & 7) * 8);
                if (grow < M)
                    *(short8*)(C + (size_t)grow * N + w * 64 + (lane & 7) * 8) = vv;
            }
        }
    } else {
        float* C = Cqs + (size_t)z * CqsStr;
        __syncthreads();                        // A_s dead; reuse as f32 store stage
        float* stgf = (float*)A_s + (size_t)w * (16 * 64);  // 8 waves x 4KB = 32KB exact
        #pragma unroll
        for (int p = 0; p < 4; p++) {           // p == mi
            #pragma unroll
            for (int ni = 0; ni < 4; ni++) {
                int colg = w * 64 + ni * 16 + lm;
                float bias = (colg < Nh) ? b1[colg] : b2[colg - Nh];
                #pragma unroll
                for (int rg = 0; rg < 4; rg++)
                    stgf[(q * 4 + rg) * 64 + ni * 16 + lm] = acc[p][ni][rg] + bias;
            }
            #pragma unroll
            for (int it = 0; it < 4; it++) {
                int rl = it * 4 + q;
                int rr = mbase + p * 16 + rl;
                float4 vv = *(const float4*)(stgf + rl * 64 + lm * 4);
                if (rr < M)
                    *(float4*)(C + (size_t)rr * N + w * 64 + lm * 4) = vv;
            }
        }
    }
}

// ---------------- dual-output LDS-A MFMA GEMM (L2/L3) ----------------
// NORM mode (L2): (x-mu)*istd -> ELU applied during A-staging (reg-staged bf16,
// same XOR-swizzled LDS layout; K-loop/epilogue untouched).
// qs epilogue LDS-coalesced (round-10, same mechanism as gemm_l1_fused).
template<int K, bool NORM>
__global__ __launch_bounds__(256, 4) void gemm_dual(
    const bf16* __restrict__ A, size_t Astr,
    const float* __restrict__ muv, const float* __restrict__ istdv,
    const bf16* __restrict__ BtKV, const bf16* __restrict__ BtQS,
    const float* __restrict__ bk, const float* __restrict__ bv,
    const float* __restrict__ bq, const float* __restrict__ bs, int Nh,
    bf16* __restrict__ Ckv, size_t CkvStr, int Mkv,
    float* __restrict__ Cqs, size_t CqsStr, int Mqs,
    int nbKV)
{
    constexpr int KC = K / 32;
    constexpr int CPR = K / 8;                  // 16B chunks per row
    constexpr int LOG_CPR = (K == 256) ? 5 : 4;
    constexpr int RPI = 64 / CPR;               // rows per staging issue
    constexpr int ISSUES = 16 / RPI;            // per wave (16 rows/wave)
    const int N = 2 * Nh;
    __shared__ bf16 A_s[64 * K];

    const int z = blockIdx.z;
    const bool isKV = (int)blockIdx.x < nbKV;
    const int bx = isKV ? blockIdx.x : blockIdx.x - nbKV;
    const int M = isKV ? Mkv : Mqs;
    const bf16* Bt = (isKV ? BtKV : BtQS) + (size_t)z * N * K;
    const float* b1 = (isKV ? bk : bq) + (size_t)z * Nh;
    const float* b2 = (isKV ? bv : bs) + (size_t)z * Nh;
    A += (size_t)z * Astr;

    const int lane = threadIdx.x & 63;
    const int w = threadIdx.x >> 6;             // 0..3 (col group)
    const int lm = lane & 15;
    const int q = lane >> 4;
    const int mbase = bx * 64;
    const int n0 = blockIdx.y * 256;

    // ---- stage A tile (64 x K): LDS chunk c of row r holds global chunk c^(r&7) ----
    {
        const int ch = lane & (CPR - 1);
        const int rsub = lane >> LOG_CPR;
        if constexpr (NORM) {
            const float* muz = muv + (size_t)z * K;
            const float* isz = istdv + (size_t)z * K;
            #pragma unroll
            for (int i = 0; i < ISSUES; i++) {
                int row = w * 16 + i * RPI + rsub;
                int grow = mbase + row; grow = grow < M ? grow : M - 1;
                int gch = ch ^ (row & 7);
                short8 raw = *(const short8*)(A + (size_t)grow * K + gch * 8);
                float4 m0 = *(const float4*)(muz + gch * 8);
                float4 m1 = *(const float4*)(muz + gch * 8 + 4);
                float4 i0 = *(const float4*)(isz + gch * 8);
                float4 i1 = *(const float4*)(isz + gch * 8 + 4);
                float mm[8] = {m0.x, m0.y, m0.z, m0.w, m1.x, m1.y, m1.z, m1.w};
                float ii[8] = {i0.x, i0.y, i0.z, i0.w, i1.x, i1.y, i1.z, i1.w};
                bf16 outb[8];
                #pragma unroll
                for (int j = 0; j < 8; j++) {
                    union { unsigned u; float f; } cv;
                    cv.u = ((unsigned)(unsigned short)raw[j]) << 16;
                    float t = (cv.f - mm[j]) * ii[j];
                    t = t > 0.f ? t : __expf(t) - 1.0f;
                    outb[j] = (bf16)t;
                }
                *(short8*)(A_s + (size_t)row * K + ch * 8) = *(const short8*)outb;
            }
        } else {
            #pragma unroll
            for (int i = 0; i < ISSUES; i++) {
                int row = w * 16 + i * RPI + rsub;
                int grow = mbase + row; grow = grow < M ? grow : M - 1;
                int gch = ch ^ (row & 7);
                load_lds16(A + (size_t)grow * K + gch * 8,
                           A_s + (size_t)(w * 16 + i * RPI) * K);
            }
        }
    }

    const bf16* bp[4];
    #pragma unroll
    for (int ni = 0; ni < 4; ni++)
        bp[ni] = Bt + (size_t)(n0 + w * 64 + ni * 16 + lm) * K + q * 8;

    floatx4 acc[4][4];
    #pragma unroll
    for (int i = 0; i < 4; i++)
        #pragma unroll
        for (int j = 0; j < 4; j++)
            acc[i][j] = (floatx4){0.f, 0.f, 0.f, 0.f};

    // 3-deep B ring preload, issued before the barrier (overlaps staging drain)
    short8 br0[4], br1[4], br2[4];
    #pragma unroll
    for (int ni = 0; ni < 4; ni++) br0[ni] = *(const short8*)(bp[ni]);
    #pragma unroll
    for (int ni = 0; ni < 4; ni++) br1[ni] = *(const short8*)(bp[ni] + 32);
    #pragma unroll
    for (int ni = 0; ni < 4; ni++) br2[ni] = *(const short8*)(bp[ni] + 64);

    __syncthreads();

    #pragma unroll
    for (int kc = 0; kc < KC; kc++) {
        short8 bc[4];
        #pragma unroll
        for (int ni = 0; ni < 4; ni++) {
            bc[ni] = br0[ni]; br0[ni] = br1[ni]; br1[ni] = br2[ni];
        }
        if (kc + 3 < KC) {
            #pragma unroll
            for (int ni = 0; ni < 4; ni++)
                br2[ni] = *(const short8*)(bp[ni] + (kc + 3) * 32);
        }
        short8 af[4];
        #pragma unroll
        for (int mi = 0; mi < 4; mi++) {
            int row = mi * 16 + lm;
            af[mi] = *(const short8*)(A_s + row * K + (((kc * 4 + q) ^ (lm & 7)) * 8));
        }
        #pragma unroll
        for (int mi = 0; mi < 4; mi++)
            #pragma unroll
            for (int ni = 0; ni < 4; ni++)
                acc[mi][ni] = __builtin_amdgcn_mfma_f32_16x16x32_bf16(
                    af[mi], bc[ni], acc[mi][ni], 0, 0, 0);
    }

    // C/D layout: col = lane&15, row = (lane>>4)*4 + reg  [m89]
    if (isKV) {
        bf16* C = Ckv + (size_t)z * CkvStr;
        __syncthreads();                        // A_s dead; reuse as transpose stage
        bf16* stg = A_s + (size_t)w * (16 * 72);
        #pragma unroll
        for (int p = 0; p < 4; p++) {           // p == mi
            #pragma unroll
            for (int ni = 0; ni < 4; ni++) {
                int colg = n0 + w * 64 + ni * 16 + lm;
                float bias = (colg < Nh) ? b1[colg] : b2[colg - Nh];
                #pragma unroll
                for (int rg = 0; rg < 4; rg++)
                    stg[(q * 4 + rg) * 72 + ni * 16 + lm] = (bf16)(acc[p][ni][rg] + bias);
            }
            #pragma unroll
            for (int it = 0; it < 2; it++) {
                int rl = it * 8 + (lane >> 3);
                int grow = mbase + p * 16 + rl;
                short8 vv = *(const short8*)(stg + rl * 72 + (lane & 7) * 8);
                if (grow < M)
                    *(short8*)(C + (size_t)grow * N + n0 + w * 64 + (lane & 7) * 8) = vv;
            }
        }
    } else {
        float* C = Cqs + (size_t)z * CqsStr;
        __syncthreads();                        // A_s dead; reuse as f32 store stage
        float* stgf = (float*)A_s + (size_t)w * (16 * 64);  // 4 waves x 4KB <= 16KB
        #pragma unroll
        for (int p = 0; p < 4; p++) {           // p == mi
            #pragma unroll
            for (int ni = 0; ni < 4; ni++) {
                int colg = n0 + w * 64 + ni * 16 + lm;
                float bias = (colg < Nh) ? b1[colg] : b2[colg - Nh];
                #pragma unroll
                for (int rg = 0; rg < 4; rg++)
                    stgf[(q * 4 + rg) * 64 + ni * 16 + lm] = acc[p][ni][rg] + bias;
            }
            #pragma unroll
            for (int it = 0; it < 4; it++) {
                int rl = it * 4 + q;
                int rr = mbase + p * 16 + rl;
                float4 vv = *(const float4*)(stgf + rl * 64 + lm * 4);
                if (rr < M)
                    *(float4*)(C + (size_t)rr * N + n0 + w * 64 + lm * 4) = vv;
            }
        }
    }
}

// ---------------- all weight packs in ONE dispatch (job via blockIdx.z) ----------
__global__ __launch_bounds__(256) void pack_all(
    const float* __restrict__ l1_Wk, const float* __restrict__ l1_Wv,
    const float* __restrict__ l1_Wq, const float* __restrict__ l1_Ws,
    const float* __restrict__ l2_Wk, const float* __restrict__ l2_Wv,
    const float* __restrict__ l2_Wq, const float* __restrict__ l2_Ws,
    const float* __restrict__ l3_Wk, const float* __restrict__ l3_Wv,
    const float* __restrict__ l3_Wq, const float* __restrict__ l3_Ws,
    bf16* __restrict__ Wkv1, bf16* __restrict__ Wqs1,
    bf16* __restrict__ Wkv2, bf16* __restrict__ Wqs2,
    bf16* __restrict__ Wkv3, bf16* __restrict__ Wqs3)
{
    int job = blockIdx.z, r = blockIdx.y, nn = blockIdx.x, k = threadIdx.x;
    const float *W1, *W2; bf16* Wt; int K, Nh;
    switch (job) {
        case 0: W1 = l1_Wk; W2 = l1_Wv; Wt = Wkv1; K = 256; Nh = 256; break;
        case 1: W1 = l1_Wq; W2 = l1_Ws; Wt = Wqs1; K = 256; Nh = 256; break;
        case 2: W1 = l2_Wk; W2 = l2_Wv; Wt = Wkv2; K = 256; Nh = 128; break;
        case 3: W1 = l2_Wq; W2 = l2_Ws; Wt = Wqs2; K = 256; Nh = 128; break;
        case 4: W1 = l3_Wk; W2 = l3_Wv; Wt = Wkv3; K = 128; Nh = 256; break;
        default: W1 = l3_Wq; W2 = l3_Ws; Wt = Wqs3; K = 128; Nh = 256; break;
    }
    if (nn >= 2 * Nh || k >= K) return;
    size_t wstride = (size_t)K * Nh;
    float v = (nn < Nh) ? W1[(size_t)r * wstride + (size_t)k * Nh + nn]
                        : W2[(size_t)r * wstride + (size_t)k * Nh + (nn - Nh)];
    Wt[(size_t)r * 2 * wstride + (size_t)nn * K + k] = (bf16)v;
}

// ---------------- fused attention + gated skip ----------------
// v-prefetch: both random-access rounds issued back-to-back (in-order vmcnt
// keeps k-consumes unaffected; v latency hides under softmax math).
template<int CPL, int HEADS>   // hc = CPL*64
__global__ __launch_bounds__(256) void attn_gate(
    const float* __restrict__ qs, size_t qsStr,
    const bf16* __restrict__ kv, size_t kvStr,
    const int* __restrict__ src,
    const float* __restrict__ Wb,
    float* __restrict__ yf, size_t yfStr,
    bf16* __restrict__ yb, size_t ybStr,
    int ndst, float scale)
{
    constexpr int hc = CPL * 64;
    constexpr int LPH = 64 / HEADS;
    const int z = blockIdx.y;
    int lane = threadIdx.x & 63;
    int d = blockIdx.x * 4 + (threadIdx.x >> 6);
    if (d >= ndst) return;
    qs += (size_t)z * qsStr;
    kv += (size_t)z * kvStr;
    src += (size_t)z * ndst * FAN;
    Wb += (size_t)z * 3 * hc;

    const float* qp = qs + (size_t)d * (2 * hc) + lane * CPL;
    float qv[CPL], xv[CPL];
    if constexpr (CPL == 2) {
        float2 a = *(const float2*)qp;
        float2 b = *(const float2*)(qp + hc);
        qv[0] = a.x; qv[1] = a.y; xv[0] = b.x; xv[1] = b.y;
    } else {
        float4 a = *(const float4*)qp;
        float4 b = *(const float4*)(qp + hc);
        qv[0] = a.x; qv[1] = a.y; qv[2] = a.z; qv[3] = a.w;
        xv[0] = b.x; xv[1] = b.y; xv[2] = b.z; xv[3] = b.w;
    }
    const int* sp = src + (size_t)d * FAN;
    int sidx[FAN];
    #pragma unroll
    for (int e = 0; e < FAN; e++) sidx[e] = sp[e];

    // partial dots (all k loads issued before the shuffle phase)
    float part[FAN];
    #pragma unroll
    for (int e = 0; e < FAN; e++) {
        const bf16* kp = kv + (size_t)sidx[e] * (2 * hc) + lane * CPL;
        if constexpr (CPL == 2) {
            float2 kf = cvt_bf2(*(const unsigned*)kp);
            part[e] = qv[0] * kf.x + qv[1] * kf.y;
        } else {
            uint2 u = *(const uint2*)kp;
            float2 k0 = cvt_bf2(u.x), k1 = cvt_bf2(u.y);
            part[e] = qv[0] * k0.x + qv[1] * k0.y + qv[2] * k1.x + qv[3] * k1.y;
        }
    }

    // prefetch v rows into regs (overlaps softmax below)
    uint2 vreg[FAN];
    #pragma unroll
    for (int e = 0; e < FAN; e++) {
        const bf16* vp = kv + (size_t)sidx[e] * (2 * hc) + hc + lane * CPL;
        if constexpr (CPL == 2) vreg[e].x = *(const unsigned*)vp;
        else                    vreg[e]   = *(const uint2*)vp;
    }

    float logit[FAN], mx = -1e30f;
    #pragma unroll
    for (int e = 0; e < FAN; e++) {
        float dt = part[e];
        #pragma unroll
        for (int off = LPH / 2; off > 0; off >>= 1) dt += __shfl_xor(dt, off, 64);
        dt *= scale;
        logit[e] = dt;
        mx = fmaxf(mx, dt);
    }
    float zsum = 0.f, p[FAN];
    #pragma unroll
    for (int e = 0; e < FAN; e++) { p[e] = __expf(logit[e] - mx); zsum += p[e]; }
    float inv = 1.f / zsum;

    float ov[CPL];
    #pragma unroll
    for (int j = 0; j < CPL; j++) ov[j] = 0.f;
    #pragma unroll
    for (int e = 0; e < FAN; e++) {
        if constexpr (CPL == 2) {
            float2 vf = cvt_bf2(vreg[e].x);
            ov[0] += p[e] * vf.x; ov[1] += p[e] * vf.y;
        } else {
            float2 v0 = cvt_bf2(vreg[e].x), v1 = cvt_bf2(vreg[e].y);
            ov[0] += p[e] * v0.x; ov[1] += p[e] * v0.y;
            ov[2] += p[e] * v1.x; ov[3] += p[e] * v1.y;
        }
    }
    #pragma unroll
    for (int j = 0; j < CPL; j++) ov[j] *= inv;

    // gated skip
    float s = 0.f;
    #pragma unroll
    for (int j = 0; j < CPL; j++) {
        int c = lane * CPL + j;
        s += ov[j] * Wb[c] + xv[j] * Wb[hc + c] + (ov[j] - xv[j]) * Wb[2 * hc + c];
    }
    #pragma unroll
    for (int off = 32; off > 0; off >>= 1) s += __shfl_xor(s, off, 64);
    float g = 1.f / (1.f + __expf(-s));

    float yv[CPL];
    #pragma unroll
    for (int j = 0; j < CPL; j++) yv[j] = g * xv[j] + (1.f - g) * ov[j];

    if (yf) {
        float* op = yf + (size_t)z * yfStr + (size_t)d * hc + lane * CPL;
        if constexpr (CPL == 2) *(float2*)op = make_float2(yv[0], yv[1]);
        else *(float4*)op = make_float4(yv[0], yv[1], yv[2], yv[3]);
    }
    if (yb) {
        bf16* op = yb + (size_t)z * ybStr + (size_t)d * hc + lane * CPL;
        bf16 tmp[CPL];
        #pragma unroll
        for (int j = 0; j < CPL; j++) tmp[j] = (bf16)yv[j];
        if constexpr (CPL == 2) *(short2v*)op = *(const short2v*)tmp;
        else *(short4v*)op = *(const short4v*)tmp;
    }
}

// ---------------- column stats (bf16 input), relation via blockIdx.y ----------------
__global__ __launch_bounds__(256) void colstat_partial(
    const bf16* __restrict__ x, size_t xStr, int M,
    float* __restrict__ ps, float* __restrict__ pss)
{
    int z = blockIdx.y;
    const bf16* xp = x + (size_t)z * xStr;
    int f = threadIdx.x;
    int b = blockIdx.x;   // 64
    float s = 0.f, ss = 0.f;
    for (int r = b; r < M; r += 64) {
        float v = (float)xp[(size_t)r * H + f];
        s += v; ss += v * v;
    }
    ps[((size_t)z * 64 + b) * H + f] = s;
    pss[((size_t)z * 64 + b) * H + f] = ss;
}

// tiny: reduce ps/pss (64 partials) -> per-column mu, istd (3 x H each)
__global__ __launch_bounds__(256) void colstats_final(
    const float* __restrict__ ps, const float* __restrict__ pss, int M,
    float* __restrict__ muv, float* __restrict__ istdv)
{
    int z = blockIdx.y;
    int c = threadIdx.x;
    float s = 0.f, ss = 0.f;
    #pragma unroll 8
    for (int b = 0; b < 64; b++) {
        s += ps[((size_t)z * 64 + b) * H + c];
        ss += pss[((size_t)z * 64 + b) * H + c];
    }
    float mu = s / M;
    muv[(size_t)z * H + c] = mu;
    istdv[(size_t)z * H + c] = rsqrtf(ss / M - mu * mu + 1e-5f);
}

// ---------------- semantic attention across the 3 relations ----------------
// shuffle-based score reduction: 7 barriers/block (was 27 with the LDS tree)
__global__ __launch_bounds__(256) void semantic_kernel(
    const float* __restrict__ emb,   // (3, N3, H)
    const float* __restrict__ Wo, const float* __restrict__ bo,
    const float* __restrict__ uo, const float* __restrict__ rl,
    float* __restrict__ outp)
{
    __shared__ float m_s[3][H];
    __shared__ float wsum[4];
    __shared__ float score_s[3];
    int n = blockIdx.x, c = threadIdx.x;
    for (int r = 0; r < 3; r++)
        m_s[r][c] = emb[((size_t)r * N3 + n) * H + c] * rl[r];
    __syncthreads();
    for (int r = 0; r < 3; r++) {
        float t = bo[c];
        for (int k2 = 0; k2 < H; k2++) t += m_s[r][k2] * Wo[k2 * H + c];
        float v = tanhf(t) * uo[c];
        #pragma unroll
        for (int off = 32; off > 0; off >>= 1) v += __shfl_xor(v, off, 64);
        if ((c & 63) == 0) wsum[c >> 6] = v;
        __syncthreads();
        if (c == 0) score_s[r] = wsum[0] + wsum[1] + wsum[2] + wsum[3];
        __syncthreads();
    }
    float s0 = score_s[0], s1 = score_s[1], s2 = score_s[2];
    float mx = fmaxf(s0, fmaxf(s1, s2));
    float e0 = __expf(s0 - mx), e1 = __expf(s1 - mx), e2 = __expf(s2 - mx);
    float zi = 1.0f / (e0 + e1 + e2);
    outp[(size_t)n * H + c] = (m_s[0][c] * e0 + m_s[1][c] * e1 + m_s[2][c] * e2) * zi;
}

extern "C" void kernel_launch(void* const* d_in, const int* in_sizes, int n_in,
                              void* d_out, int out_size, void* d_ws, size_t ws_size,
                              hipStream_t stream) {
    const float* features = (const float*)d_in[0];
    const int*   n_ids    = (const int*)d_in[1];
    const int*   src1     = (const int*)d_in[2];
    const int*   src2     = (const int*)d_in[4];
    const int*   src3     = (const int*)d_in[6];
    const float* l1_Wq = (const float*)d_in[8];
    const float* l1_Wk = (const float*)d_in[9];
    const float* l1_Wv = (const float*)d_in[10];
    const float* l1_Ws = (const float*)d_in[11];
    const float* l1_bq = (const float*)d_in[12];
    const float* l1_bk = (const float*)d_in[13];
    const float* l1_bv = (const float*)d_in[14];
    const float* l1_bs = (const float*)d_in[15];
    const float* l1_Wb = (const float*)d_in[16];
    const float* l2_Wq = (const float*)d_in[17];
    const float* l2_Wk = (const float*)d_in[18];
    const float* l2_Wv = (const float*)d_in[19];
    const float* l2_Ws = (const float*)d_in[20];
    const float* l2_bq = (const float*)d_in[21];
    const float* l2_bk = (const float*)d_in[22];
    const float* l2_bv = (const float*)d_in[23];
    const float* l2_bs = (const float*)d_in[24];
    const float* l2_Wb = (const float*)d_in[25];
    const float* l3_Wq = (const float*)d_in[26];
    const float* l3_Wk = (const float*)d_in[27];
    const float* l3_Wv = (const float*)d_in[28];
    const float* l3_Ws = (const float*)d_in[29];
    const float* l3_bq = (const float*)d_in[30];
    const float* l3_bk = (const float*)d_in[31];
    const float* l3_bv = (const float*)d_in[32];
    const float* l3_bs = (const float*)d_in[33];
    const float* l3_Wb = (const float*)d_in[34];
    const float* w_omega = (const float*)d_in[35];
    const float* b_omega = (const float*)d_in[36];
    const float* u_omega = (const float*)d_in[37];
    const float* rl      = (const float*)d_in[38];

    // ---- workspace layout: per-relation buffers ----
    float* ws = (float*)d_ws;
    size_t o = 0;
    float* emb = ws + o; o += (size_t)3 * N3 * H;
    float* qs1 = ws + o; o += (size_t)3 * N1 * 512;
    float* qs2 = ws + o; o += (size_t)3 * N2 * 256;
    float* qs3 = ws + o; o += (size_t)3 * N3 * 512;
    float* ps  = ws + o; o += (size_t)3 * 64 * H;
    float* pss = ws + o; o += (size_t)3 * 64 * H;
    float* muv   = ws + o; o += (size_t)3 * H;
    float* istdv = ws + o; o += (size_t)3 * H;

    bf16* bws = (bf16*)(ws + o);
    size_t b = 0;
    bf16* kv1 = bws + b; b += (size_t)3 * N0 * 512;
    bf16* x1b = bws + b; b += (size_t)3 * N1 * 256;
    bf16* kv2 = bws + b; b += (size_t)3 * N1 * 256;
    bf16* x2b = bws + b; b += (size_t)3 * N2 * 128;
    bf16* kv3 = bws + b; b += (size_t)3 * N2 * 512;
    bf16* Wkv1 = bws + b; b += (size_t)3 * 512 * H;
    bf16* Wqs1 = bws + b; b += (size_t)3 * 512 * H;
    bf16* Wkv2 = bws + b; b += (size_t)3 * 256 * H;
    bf16* Wqs2 = bws + b; b += (size_t)3 * 256 * H;
    bf16* Wkv3 = bws + b; b += (size_t)3 * 512 * 128;
    bf16* Wqs3 = bws + b; b += (size_t)3 * 512 * 128;

    const float sc128 = 0.088388347648318447f;  // 1/sqrt(128)
    const float sc256 = 0.0625f;                // 1/sqrt(256)

    // ---- all weight packs, one dispatch ----
    pack_all<<<dim3(512, 3, 6), 256, 0, stream>>>(
        l1_Wk, l1_Wv, l1_Wq, l1_Ws, l2_Wk, l2_Wv, l2_Wq, l2_Ws,
        l3_Wk, l3_Wv, l3_Wq, l3_Ws, Wkv1, Wqs1, Wkv2, Wqs2, Wkv3, Wqs3);

    // ---- L1 (gather-fused, single-pass): 64x512 tile, 512 thr ----
    {
        int nbKV = (N0 + 63) / 64, nbQS = (N1 + 63) / 64;
        gemm_l1_fused<<<dim3(nbKV + nbQS, 1, 3), 512, 0, stream>>>(
            features, n_ids, Wkv1, Wqs1, l1_bk, l1_bv, l1_bq, l1_bs,
            kv1, (size_t)N0 * 512, qs1, (size_t)N1 * 512, nbKV);
    }
    attn_gate<4, 2><<<dim3((N1 + 3) / 4, 3), 256, 0, stream>>>(
        qs1, (size_t)N1 * 512, kv1, (size_t)N0 * 512, src1, l1_Wb,
        (float*)nullptr, 0, x1b, (size_t)N1 * 256, N1, sc128);
    colstat_partial<<<dim3(64, 3), 256, 0, stream>>>(x1b, (size_t)N1 * 256, N1, ps, pss);
    colstats_final<<<dim3(1, 3), 256, 0, stream>>>(ps, pss, N1, muv, istdv);

    // ---- L2 (norm+ELU folded into A-staging): din=256, hc=128, N=256, K=256 ----
    {
        int nbKV = (N1 + 63) / 64, nbQS = (N2 + 63) / 64;
        gemm_dual<256, true><<<dim3(nbKV + nbQS, 1, 3), 256, 0, stream>>>(
            x1b, (size_t)N1 * 256, muv, istdv,
            Wkv2, Wqs2, l2_bk, l2_bv, l2_bq, l2_bs, 128,
            kv2, (size_t)N1 * 256, N1, qs2, (size_t)N2 * 256, N2, nbKV);
    }
    attn_gate<2, 1><<<dim3((N2 + 3) / 4, 3), 256, 0, stream>>>(
        qs2, (size_t)N2 * 256, kv2, (size_t)N1 * 256, src2, l2_Wb,
        (float*)nullptr, 0, x2b, (size_t)N2 * 128, N2, sc128);

    // ---- L3: din=128, heads=1, ch=256, hc=256, N=512, K=128 ----
    {
        int nbKV = (N2 + 63) / 64, nbQS = (N3 + 63) / 64;
        gemm_dual<128, false><<<dim3(nbKV + nbQS, 2, 3), 256, 0, stream>>>(
            x2b, (size_t)N2 * 128, (const float*)nullptr, (const float*)nullptr,
            Wkv3, Wqs3, l3_bk, l3_bv, l3_bq, l3_bs, 256,
            kv3, (size_t)N2 * 512, N2, qs3, (size_t)N3 * 512, N3, nbKV);
    }
    attn_gate<4, 1><<<dim3((N3 + 3) / 4, 3), 256, 0, stream>>>(
        qs3, (size_t)N3 * 512, kv3, (size_t)N2 * 512, src3, l3_Wb,
        emb, (size_t)N3 * H, (bf16*)nullptr, 0, N3, sc256);

    semantic_kernel<<<N3, 256, 0, stream>>>(emb, w_omega, b_omega, u_omega, rl, (float*)d_out);
}

// Round 11
// 551.218 us; speedup vs baseline: 4.4363x; 1.0093x over previous
//
#include <hip/hip_runtime.h>
#include <hip/hip_bf16.h>
#include <math.h>

#define H 256
#define N0 50000
#define N1 10000
#define N2 4000
#define N3 1024
#define FAN 16

typedef __hip_bfloat16 bf16;
typedef __attribute__((ext_vector_type(8))) short short8;
typedef __attribute__((ext_vector_type(4))) short short4v;
typedef __attribute__((ext_vector_type(2))) short short2v;
typedef __attribute__((ext_vector_type(4))) float floatx4;

typedef const __attribute__((address_space(1))) void* gas_ptr;
typedef __attribute__((address_space(3))) void* las_ptr;

__device__ __forceinline__ void load_lds16(const void* g, void* l) {
    __builtin_amdgcn_global_load_lds((gas_ptr)g, (las_ptr)l, 16, 0, 0);
}

__device__ __forceinline__ float2 cvt_bf2(unsigned u) {
    union { unsigned q; float f; } lo, hi;
    lo.q = u << 16; hi.q = u & 0xffff0000u;
    return make_float2(lo.f, hi.f);
}

// ---------------- L1 gather-fused GEMM: 64x512 tile, 512 thr (8 waves) ----------------
// (round-6..10 verified: FETCH ~features-once; qs epilogue LDS-coalesced ->
//  full-line stores restored the 2.4 TB/s family rate (round-10: byte-rate,
//  not byte-count, was the lever). Round-11: kv-tile i / qs-tile i adjacent in
//  grid.x — qs tiles re-gather the same n_ids[0..N1] rows as kv tiles 0..156;
//  adjacency makes the re-read an L3 hit (they were 782 slots apart; 317MB
//  working set > 256MB L3 evicted in between).
// RULE (round-8): never convert a column-reduction into same-address global
// atomics when rows >> 1000 — 10k serialized atomics/address = 1.9ms.
__global__ __launch_bounds__(512, 4) void gemm_l1_fused(
    const float* __restrict__ F, const int* __restrict__ n_ids,
    const bf16* __restrict__ BtKV, const bf16* __restrict__ BtQS,
    const float* __restrict__ bk, const float* __restrict__ bv,
    const float* __restrict__ bq, const float* __restrict__ bs,
    bf16* __restrict__ Ckv, size_t CkvStr,
    float* __restrict__ Cqs, size_t CqsStr)
{
    constexpr int K = 256, Nh = 256, N = 512, KC = K / 32;
    constexpr int NBKV = (N0 + 63) / 64, NBQS = (N1 + 63) / 64;
    __shared__ bf16 A_s[64 * K];

    const int z = blockIdx.z;
    // interleave: x=2i -> kv tile i, x=2i+1 -> qs tile i (i<NBQS); rest kv
    int x = blockIdx.x, bxl;
    if (x < 2 * NBQS) bxl = (x & 1) ? (NBKV + (x >> 1)) : (x >> 1);
    else              bxl = x - NBQS;
    const bool isKV = bxl < NBKV;
    const int bx = isKV ? bxl : bxl - NBKV;
    const int M = isKV ? N0 : N1;
    const bf16* Bt = (isKV ? BtKV : BtQS) + (size_t)z * N * K;
    const float* b1 = (isKV ? bk : bq) + (size_t)z * Nh;
    const float* b2 = (isKV ? bv : bs) + (size_t)z * Nh;

    const int lane = threadIdx.x & 63;
    const int w = threadIdx.x >> 6;             // 0..7 (col group)
    const int lm = lane & 15;
    const int q = lane >> 4;
    const int mbase = bx * 64;

    // ---- gather-stage A (64 x 256): LDS chunk c of row r holds global chunk c^(r&7) ----
    {
        const int* idz = n_ids + (size_t)z * N0;
        #pragma unroll 4
        for (int j = 0; j < 8; j++) {
            int row = w * 8 + j;
            int grow = mbase + row; grow = grow < M ? grow : M - 1;
            int gidx = idz[grow];               // wave-uniform -> scalar load
            float4 v = *(const float4*)(F + (size_t)gidx * H + lane * 4);
            bf16 t4[4] = {(bf16)v.x, (bf16)v.y, (bf16)v.z, (bf16)v.w};
            int c16 = (lane >> 1) ^ (row & 7);  // 16B bf16 chunk, XOR swizzle
            *(short4v*)(A_s + (size_t)row * K + c16 * 8 + (lane & 1) * 4) =
                *(const short4v*)t4;
        }
    }

    const bf16* bp[4];
    #pragma unroll
    for (int ni = 0; ni < 4; ni++)
        bp[ni] = Bt + (size_t)(w * 64 + ni * 16 + lm) * K + q * 8;

    floatx4 acc[4][4];
    #pragma unroll
    for (int i = 0; i < 4; i++)
        #pragma unroll
        for (int j = 0; j < 4; j++)
            acc[i][j] = (floatx4){0.f, 0.f, 0.f, 0.f};

    // 3-deep B ring preload (L2-resident weights), issued before the barrier
    short8 br0[4], br1[4], br2[4];
    #pragma unroll
    for (int ni = 0; ni < 4; ni++) br0[ni] = *(const short8*)(bp[ni]);
    #pragma unroll
    for (int ni = 0; ni < 4; ni++) br1[ni] = *(const short8*)(bp[ni] + 32);
    #pragma unroll
    for (int ni = 0; ni < 4; ni++) br2[ni] = *(const short8*)(bp[ni] + 64);

    __syncthreads();

    #pragma unroll
    for (int kc = 0; kc < KC; kc++) {
        short8 bc[4];
        #pragma unroll
        for (int ni = 0; ni < 4; ni++) {
            bc[ni] = br0[ni]; br0[ni] = br1[ni]; br1[ni] = br2[ni];
        }
        if (kc + 3 < KC) {
            #pragma unroll
            for (int ni = 0; ni < 4; ni++)
                br2[ni] = *(const short8*)(bp[ni] + (kc + 3) * 32);
        }
        short8 af[4];
        #pragma unroll
        for (int mi = 0; mi < 4; mi++) {
            int row = mi * 16 + lm;
            af[mi] = *(const short8*)(A_s + row * K + (((kc * 4 + q) ^ (lm & 7)) * 8));
        }
        #pragma unroll
        for (int mi = 0; mi < 4; mi++)
            #pragma unroll
            for (int ni = 0; ni < 4; ni++)
                acc[mi][ni] = __builtin_amdgcn_mfma_f32_16x16x32_bf16(
                    af[mi], bc[ni], acc[mi][ni], 0, 0, 0);
    }

    // C/D layout: col = lane&15, row = (lane>>4)*4 + reg  [m89]
    if (isKV) {
        bf16* C = Ckv + (size_t)z * CkvStr;
        __syncthreads();                        // A_s dead; reuse as transpose stage
        bf16* stg = A_s + (size_t)w * (16 * 72);    // 8 waves x 2304B = 18KB < 32KB
        #pragma unroll
        for (int p = 0; p < 4; p++) {           // p == mi
            #pragma unroll
            for (int ni = 0; ni < 4; ni++) {
                int colg = w * 64 + ni * 16 + lm;
                float bias = (colg < Nh) ? b1[colg] : b2[colg - Nh];
                #pragma unroll
                for (int rg = 0; rg < 4; rg++)
                    stg[(q * 4 + rg) * 72 + ni * 16 + lm] = (bf16)(acc[p][ni][rg] + bias);
            }
            #pragma unroll
            for (int it = 0; it < 2; it++) {
                int rl = it * 8 + (lane >> 3);
                int grow = mbase + p * 16 + rl;
                short8 vv = *(const short8*)(stg + rl * 72 + (lane & 7) * 8);
                if (grow < M)
                    *(short8*)(C + (size_t)grow * N + w * 64 + (lane & 7) * 8) = vv;
            }
        }
    } else {
        float* C = Cqs + (size_t)z * CqsStr;
        __syncthreads();                        // A_s dead; reuse as f32 store stage
        float* stgf = (float*)A_s + (size_t)w * (16 * 64);  // 8 waves x 4KB = 32KB exact
        #pragma unroll
        for (int p = 0; p < 4; p++) {           // p == mi
            #pragma unroll
            for (int ni = 0; ni < 4; ni++) {
                int colg = w * 64 + ni * 16 + lm;
                float bias = (colg < Nh) ? b1[colg] : b2[colg - Nh];
                #pragma unroll
                for (int rg = 0; rg < 4; rg++)
                    stgf[(q * 4 + rg) * 64 + ni * 16 + lm] = acc[p][ni][rg] + bias;
            }
            #pragma unroll
            for (int it = 0; it < 4; it++) {
                int rl = it * 4 + q;
                int rr = mbase + p * 16 + rl;
                float4 vv = *(const float4*)(stgf + rl * 64 + lm * 4);
                if (rr < M)
                    *(float4*)(C + (size_t)rr * N + w * 64 + lm * 4) = vv;
            }
        }
    }
}

// ---------------- dual-output LDS-A MFMA GEMM (L2/L3) ----------------
// NORM mode (L2): (x-mu)*istd -> ELU applied during A-staging (reg-staged bf16,
// same XOR-swizzled LDS layout; K-loop/epilogue untouched).
// qs epilogue LDS-coalesced (round-10 full-line store rate fix).
template<int K, bool NORM>
__global__ __launch_bounds__(256, 4) void gemm_dual(
    const bf16* __restrict__ A, size_t Astr,
    const float* __restrict__ muv, const float* __restrict__ istdv,
    const bf16* __restrict__ BtKV, const bf16* __restrict__ BtQS,
    const float* __restrict__ bk, const float* __restrict__ bv,
    const float* __restrict__ bq, const float* __restrict__ bs, int Nh,
    bf16* __restrict__ Ckv, size_t CkvStr, int Mkv,
    float* __restrict__ Cqs, size_t CqsStr, int Mqs,
    int nbKV)
{
    constexpr int KC = K / 32;
    constexpr int CPR = K / 8;                  // 16B chunks per row
    constexpr int LOG_CPR = (K == 256) ? 5 : 4;
    constexpr int RPI = 64 / CPR;               // rows per staging issue
    constexpr int ISSUES = 16 / RPI;            // per wave (16 rows/wave)
    const int N = 2 * Nh;
    __shared__ bf16 A_s[64 * K];

    const int z = blockIdx.z;
    const bool isKV = (int)blockIdx.x < nbKV;
    const int bx = isKV ? blockIdx.x : blockIdx.x - nbKV;
    const int M = isKV ? Mkv : Mqs;
    const bf16* Bt = (isKV ? BtKV : BtQS) + (size_t)z * N * K;
    const float* b1 = (isKV ? bk : bq) + (size_t)z * Nh;
    const float* b2 = (isKV ? bv : bs) + (size_t)z * Nh;
    A += (size_t)z * Astr;

    const int lane = threadIdx.x & 63;
    const int w = threadIdx.x >> 6;             // 0..3 (col group)
    const int lm = lane & 15;
    const int q = lane >> 4;
    const int mbase = bx * 64;
    const int n0 = blockIdx.y * 256;

    // ---- stage A tile (64 x K): LDS chunk c of row r holds global chunk c^(r&7) ----
    {
        const int ch = lane & (CPR - 1);
        const int rsub = lane >> LOG_CPR;
        if constexpr (NORM) {
            const float* muz = muv + (size_t)z * K;
            const float* isz = istdv + (size_t)z * K;
            #pragma unroll
            for (int i = 0; i < ISSUES; i++) {
                int row = w * 16 + i * RPI + rsub;
                int grow = mbase + row; grow = grow < M ? grow : M - 1;
                int gch = ch ^ (row & 7);
                short8 raw = *(const short8*)(A + (size_t)grow * K + gch * 8);
                float4 m0 = *(const float4*)(muz + gch * 8);
                float4 m1 = *(const float4*)(muz + gch * 8 + 4);
                float4 i0 = *(const float4*)(isz + gch * 8);
                float4 i1 = *(const float4*)(isz + gch * 8 + 4);
                float mm[8] = {m0.x, m0.y, m0.z, m0.w, m1.x, m1.y, m1.z, m1.w};
                float ii[8] = {i0.x, i0.y, i0.z, i0.w, i1.x, i1.y, i1.z, i1.w};
                bf16 outb[8];
                #pragma unroll
                for (int j = 0; j < 8; j++) {
                    union { unsigned u; float f; } cv;
                    cv.u = ((unsigned)(unsigned short)raw[j]) << 16;
                    float t = (cv.f - mm[j]) * ii[j];
                    t = t > 0.f ? t : __expf(t) - 1.0f;
                    outb[j] = (bf16)t;
                }
                *(short8*)(A_s + (size_t)row * K + ch * 8) = *(const short8*)outb;
            }
        } else {
            #pragma unroll
            for (int i = 0; i < ISSUES; i++) {
                int row = w * 16 + i * RPI + rsub;
                int grow = mbase + row; grow = grow < M ? grow : M - 1;
                int gch = ch ^ (row & 7);
                load_lds16(A + (size_t)grow * K + gch * 8,
                           A_s + (size_t)(w * 16 + i * RPI) * K);
            }
        }
    }

    const bf16* bp[4];
    #pragma unroll
    for (int ni = 0; ni < 4; ni++)
        bp[ni] = Bt + (size_t)(n0 + w * 64 + ni * 16 + lm) * K + q * 8;

    floatx4 acc[4][4];
    #pragma unroll
    for (int i = 0; i < 4; i++)
        #pragma unroll
        for (int j = 0; j < 4; j++)
            acc[i][j] = (floatx4){0.f, 0.f, 0.f, 0.f};

    // 3-deep B ring preload, issued before the barrier (overlaps staging drain)
    short8 br0[4], br1[4], br2[4];
    #pragma unroll
    for (int ni = 0; ni < 4; ni++) br0[ni] = *(const short8*)(bp[ni]);
    #pragma unroll
    for (int ni = 0; ni < 4; ni++) br1[ni] = *(const short8*)(bp[ni] + 32);
    #pragma unroll
    for (int ni = 0; ni < 4; ni++) br2[ni] = *(const short8*)(bp[ni] + 64);

    __syncthreads();

    #pragma unroll
    for (int kc = 0; kc < KC; kc++) {
        short8 bc[4];
        #pragma unroll
        for (int ni = 0; ni < 4; ni++) {
            bc[ni] = br0[ni]; br0[ni] = br1[ni]; br1[ni] = br2[ni];
        }
        if (kc + 3 < KC) {
            #pragma unroll
            for (int ni = 0; ni < 4; ni++)
                br2[ni] = *(const short8*)(bp[ni] + (kc + 3) * 32);
        }
        short8 af[4];
        #pragma unroll
        for (int mi = 0; mi < 4; mi++) {
            int row = mi * 16 + lm;
            af[mi] = *(const short8*)(A_s + row * K + (((kc * 4 + q) ^ (lm & 7)) * 8));
        }
        #pragma unroll
        for (int mi = 0; mi < 4; mi++)
            #pragma unroll
            for (int ni = 0; ni < 4; ni++)
                acc[mi][ni] = __builtin_amdgcn_mfma_f32_16x16x32_bf16(
                    af[mi], bc[ni], acc[mi][ni], 0, 0, 0);
    }

    // C/D layout: col = lane&15, row = (lane>>4)*4 + reg  [m89]
    if (isKV) {
        bf16* C = Ckv + (size_t)z * CkvStr;
        __syncthreads();                        // A_s dead; reuse as transpose stage
        bf16* stg = A_s + (size_t)w * (16 * 72);
        #pragma unroll
        for (int p = 0; p < 4; p++) {           // p == mi
            #pragma unroll
            for (int ni = 0; ni < 4; ni++) {
                int colg = n0 + w * 64 + ni * 16 + lm;
                float bias = (colg < Nh) ? b1[colg] : b2[colg - Nh];
                #pragma unroll
                for (int rg = 0; rg < 4; rg++)
                    stg[(q * 4 + rg) * 72 + ni * 16 + lm] = (bf16)(acc[p][ni][rg] + bias);
            }
            #pragma unroll
            for (int it = 0; it < 2; it++) {
                int rl = it * 8 + (lane >> 3);
                int grow = mbase + p * 16 + rl;
                short8 vv = *(const short8*)(stg + rl * 72 + (lane & 7) * 8);
                if (grow < M)
                    *(short8*)(C + (size_t)grow * N + n0 + w * 64 + (lane & 7) * 8) = vv;
            }
        }
    } else {
        float* C = Cqs + (size_t)z * CqsStr;
        __syncthreads();                        // A_s dead; reuse as f32 store stage
        float* stgf = (float*)A_s + (size_t)w * (16 * 64);  // 4 waves x 4KB <= 16KB
        #pragma unroll
        for (int p = 0; p < 4; p++) {           // p == mi
            #pragma unroll
            for (int ni = 0; ni < 4; ni++) {
                int colg = n0 + w * 64 + ni * 16 + lm;
                float bias = (colg < Nh) ? b1[colg] : b2[colg - Nh];
                #pragma unroll
                for (int rg = 0; rg < 4; rg++)
                    stgf[(q * 4 + rg) * 64 + ni * 16 + lm] = acc[p][ni][rg] + bias;
            }
            #pragma unroll
            for (int it = 0; it < 4; it++) {
                int rl = it * 4 + q;
                int rr = mbase + p * 16 + rl;
                float4 vv = *(const float4*)(stgf + rl * 64 + lm * 4);
                if (rr < M)
                    *(float4*)(C + (size_t)rr * N + n0 + w * 64 + lm * 4) = vv;
            }
        }
    }
}

// ---------------- weight packs: LDS-tiled TRANSPOSE (round-11) ----------------
// Old version read W[k*Nh+nn] with thread=k: consecutive lanes 512-1024B apart
// -> ~6.9M uncoalesced scalar 4B loads (4B used per 128B line), a hidden
// multi-10us tail item. Now: block owns a 64-wide nn chunk, reads coalesced
// along nn (256B/wave), transposes via padded LDS tile, writes bf16 coalesced
// along k (128B/wave). Same values, same destination layout.
__global__ __launch_bounds__(256) void pack_all(
    const float* __restrict__ l1_Wk, const float* __restrict__ l1_Wv,
    const float* __restrict__ l1_Wq, const float* __restrict__ l1_Ws,
    const float* __restrict__ l2_Wk, const float* __restrict__ l2_Wv,
    const float* __restrict__ l2_Wq, const float* __restrict__ l2_Ws,
    const float* __restrict__ l3_Wk, const float* __restrict__ l3_Wv,
    const float* __restrict__ l3_Wq, const float* __restrict__ l3_Ws,
    bf16* __restrict__ Wkv1, bf16* __restrict__ Wqs1,
    bf16* __restrict__ Wkv2, bf16* __restrict__ Wqs2,
    bf16* __restrict__ Wkv3, bf16* __restrict__ Wqs3)
{
    int job = blockIdx.z, r = blockIdx.y;
    const float *W1, *W2; bf16* Wt; int K, Nh;
    switch (job) {
        case 0: W1 = l1_Wk; W2 = l1_Wv; Wt = Wkv1; K = 256; Nh = 256; break;
        case 1: W1 = l1_Wq; W2 = l1_Ws; Wt = Wqs1; K = 256; Nh = 256; break;
        case 2: W1 = l2_Wk; W2 = l2_Wv; Wt = Wkv2; K = 256; Nh = 128; break;
        case 3: W1 = l2_Wq; W2 = l2_Ws; Wt = Wqs2; K = 256; Nh = 128; break;
        case 4: W1 = l3_Wk; W2 = l3_Wv; Wt = Wkv3; K = 128; Nh = 256; break;
        default: W1 = l3_Wq; W2 = l3_Ws; Wt = Wqs3; K = 128; Nh = 256; break;
    }
    int nn0 = blockIdx.x * 64;
    if (nn0 >= 2 * Nh) return;                  // whole-block uniform exit

    __shared__ float tile[64][65];              // +1 pad: conflict-free transpose
    size_t wstride = (size_t)K * Nh;
    const float* Wsrc = ((nn0 < Nh) ? W1 : W2) + (size_t)r * wstride;
    int col0 = (nn0 < Nh) ? nn0 : nn0 - Nh;
    bf16* Wdst = Wt + (size_t)r * 2 * wstride;

    int tq = threadIdx.x >> 6;                  // 0..3
    int tl = threadIdx.x & 63;

    for (int k0 = 0; k0 < K; k0 += 64) {
        #pragma unroll
        for (int j = 0; j < 16; j++) {
            int kl = tq * 16 + j;
            tile[kl][tl] = Wsrc[(size_t)(k0 + kl) * Nh + col0 + tl];
        }
        __syncthreads();
        #pragma unroll
        for (int j = 0; j < 16; j++) {
            int nl = tq * 16 + j;
            Wdst[(size_t)(nn0 + nl) * K + k0 + tl] = (bf16)tile[tl][nl];
        }
        __syncthreads();
    }
}

// ---------------- fused attention + gated skip ----------------
// v-prefetch: both random-access rounds issued back-to-back (in-order vmcnt
// keeps k-consumes unaffected; v latency hides under softmax math).
template<int CPL, int HEADS>   // hc = CPL*64
__global__ __launch_bounds__(256) void attn_gate(
    const float* __restrict__ qs, size_t qsStr,
    const bf16* __restrict__ kv, size_t kvStr,
    const int* __restrict__ src,
    const float* __restrict__ Wb,
    float* __restrict__ yf, size_t yfStr,
    bf16* __restrict__ yb, size_t ybStr,
    int ndst, float scale)
{
    constexpr int hc = CPL * 64;
    constexpr int LPH = 64 / HEADS;
    const int z = blockIdx.y;
    int lane = threadIdx.x & 63;
    int d = blockIdx.x * 4 + (threadIdx.x >> 6);
    if (d >= ndst) return;
    qs += (size_t)z * qsStr;
    kv += (size_t)z * kvStr;
    src += (size_t)z * ndst * FAN;
    Wb += (size_t)z * 3 * hc;

    const float* qp = qs + (size_t)d * (2 * hc) + lane * CPL;
    float qv[CPL], xv[CPL];
    if constexpr (CPL == 2) {
        float2 a = *(const float2*)qp;
        float2 b = *(const float2*)(qp + hc);
        qv[0] = a.x; qv[1] = a.y; xv[0] = b.x; xv[1] = b.y;
    } else {
        float4 a = *(const float4*)qp;
        float4 b = *(const float4*)(qp + hc);
        qv[0] = a.x; qv[1] = a.y; qv[2] = a.z; qv[3] = a.w;
        xv[0] = b.x; xv[1] = b.y; xv[2] = b.z; xv[3] = b.w;
    }
    const int* sp = src + (size_t)d * FAN;
    int sidx[FAN];
    #pragma unroll
    for (int e = 0; e < FAN; e++) sidx[e] = sp[e];

    // partial dots (all k loads issued before the shuffle phase)
    float part[FAN];
    #pragma unroll
    for (int e = 0; e < FAN; e++) {
        const bf16* kp = kv + (size_t)sidx[e] * (2 * hc) + lane * CPL;
        if constexpr (CPL == 2) {
            float2 kf = cvt_bf2(*(const unsigned*)kp);
            part[e] = qv[0] * kf.x + qv[1] * kf.y;
        } else {
            uint2 u = *(const uint2*)kp;
            float2 k0 = cvt_bf2(u.x), k1 = cvt_bf2(u.y);
            part[e] = qv[0] * k0.x + qv[1] * k0.y + qv[2] * k1.x + qv[3] * k1.y;
        }
    }

    // prefetch v rows into regs (overlaps softmax below)
    uint2 vreg[FAN];
    #pragma unroll
    for (int e = 0; e < FAN; e++) {
        const bf16* vp = kv + (size_t)sidx[e] * (2 * hc) + hc + lane * CPL;
        if constexpr (CPL == 2) vreg[e].x = *(const unsigned*)vp;
        else                    vreg[e]   = *(const uint2*)vp;
    }

    float logit[FAN], mx = -1e30f;
    #pragma unroll
    for (int e = 0; e < FAN; e++) {
        float dt = part[e];
        #pragma unroll
        for (int off = LPH / 2; off > 0; off >>= 1) dt += __shfl_xor(dt, off, 64);
        dt *= scale;
        logit[e] = dt;
        mx = fmaxf(mx, dt);
    }
    float zsum = 0.f, p[FAN];
    #pragma unroll
    for (int e = 0; e < FAN; e++) { p[e] = __expf(logit[e] - mx); zsum += p[e]; }
    float inv = 1.f / zsum;

    float ov[CPL];
    #pragma unroll
    for (int j = 0; j < CPL; j++) ov[j] = 0.f;
    #pragma unroll
    for (int e = 0; e < FAN; e++) {
        if constexpr (CPL == 2) {
            float2 vf = cvt_bf2(vreg[e].x);
            ov[0] += p[e] * vf.x; ov[1] += p[e] * vf.y;
        } else {
            float2 v0 = cvt_bf2(vreg[e].x), v1 = cvt_bf2(vreg[e].y);
            ov[0] += p[e] * v0.x; ov[1] += p[e] * v0.y;
            ov[2] += p[e] * v1.x; ov[3] += p[e] * v1.y;
        }
    }
    #pragma unroll
    for (int j = 0; j < CPL; j++) ov[j] *= inv;

    // gated skip
    float s = 0.f;
    #pragma unroll
    for (int j = 0; j < CPL; j++) {
        int c = lane * CPL + j;
        s += ov[j] * Wb[c] + xv[j] * Wb[hc + c] + (ov[j] - xv[j]) * Wb[2 * hc + c];
    }
    #pragma unroll
    for (int off = 32; off > 0; off >>= 1) s += __shfl_xor(s, off, 64);
    float g = 1.f / (1.f + __expf(-s));

    float yv[CPL];
    #pragma unroll
    for (int j = 0; j < CPL; j++) yv[j] = g * xv[j] + (1.f - g) * ov[j];

    if (yf) {
        float* op = yf + (size_t)z * yfStr + (size_t)d * hc + lane * CPL;
        if constexpr (CPL == 2) *(float2*)op = make_float2(yv[0], yv[1]);
        else *(float4*)op = make_float4(yv[0], yv[1], yv[2], yv[3]);
    }
    if (yb) {
        bf16* op = yb + (size_t)z * ybStr + (size_t)d * hc + lane * CPL;
        bf16 tmp[CPL];
        #pragma unroll
        for (int j = 0; j < CPL; j++) tmp[j] = (bf16)yv[j];
        if constexpr (CPL == 2) *(short2v*)op = *(const short2v*)tmp;
        else *(short4v*)op = *(const short4v*)tmp;
    }
}

// ---------------- column stats (bf16 input), relation via blockIdx.y ----------------
__global__ __launch_bounds__(256) void colstat_partial(
    const bf16* __restrict__ x, size_t xStr, int M,
    float* __restrict__ ps, float* __restrict__ pss)
{
    int z = blockIdx.y;
    const bf16* xp = x + (size_t)z * xStr;
    int f = threadIdx.x;
    int b = blockIdx.x;   // 64
    float s = 0.f, ss = 0.f;
    for (int r = b; r < M; r += 64) {
        float v = (float)xp[(size_t)r * H + f];
        s += v; ss += v * v;
    }
    ps[((size_t)z * 64 + b) * H + f] = s;
    pss[((size_t)z * 64 + b) * H + f] = ss;
}

// tiny: reduce ps/pss (64 partials) -> per-column mu, istd (3 x H each)
__global__ __launch_bounds__(256) void colstats_final(
    const float* __restrict__ ps, const float* __restrict__ pss, int M,
    float* __restrict__ muv, float* __restrict__ istdv)
{
    int z = blockIdx.y;
    int c = threadIdx.x;
    float s = 0.f, ss = 0.f;
    #pragma unroll 8
    for (int b = 0; b < 64; b++) {
        s += ps[((size_t)z * 64 + b) * H + c];
        ss += pss[((size_t)z * 64 + b) * H + c];
    }
    float mu = s / M;
    muv[(size_t)z * H + c] = mu;
    istdv[(size_t)z * H + c] = rsqrtf(ss / M - mu * mu + 1e-5f);
}

// ---------------- semantic attention across the 3 relations ----------------
// shuffle-based score reduction: 7 barriers/block (was 27 with the LDS tree)
__global__ __launch_bounds__(256) void semantic_kernel(
    const float* __restrict__ emb,   // (3, N3, H)
    const float* __restrict__ Wo, const float* __restrict__ bo,
    const float* __restrict__ uo, const float* __restrict__ rl,
    float* __restrict__ outp)
{
    __shared__ float m_s[3][H];
    __shared__ float wsum[4];
    __shared__ float score_s[3];
    int n = blockIdx.x, c = threadIdx.x;
    for (int r = 0; r < 3; r++)
        m_s[r][c] = emb[((size_t)r * N3 + n) * H + c] * rl[r];
    __syncthreads();
    for (int r = 0; r < 3; r++) {
        float t = bo[c];
        for (int k2 = 0; k2 < H; k2++) t += m_s[r][k2] * Wo[k2 * H + c];
        float v = tanhf(t) * uo[c];
        #pragma unroll
        for (int off = 32; off > 0; off >>= 1) v += __shfl_xor(v, off, 64);
        if ((c & 63) == 0) wsum[c >> 6] = v;
        __syncthreads();
        if (c == 0) score_s[r] = wsum[0] + wsum[1] + wsum[2] + wsum[3];
        __syncthreads();
    }
    float s0 = score_s[0], s1 = score_s[1], s2 = score_s[2];
    float mx = fmaxf(s0, fmaxf(s1, s2));
    float e0 = __expf(s0 - mx), e1 = __expf(s1 - mx), e2 = __expf(s2 - mx);
    float zi = 1.0f / (e0 + e1 + e2);
    outp[(size_t)n * H + c] = (m_s[0][c] * e0 + m_s[1][c] * e1 + m_s[2][c] * e2) * zi;
}

extern "C" void kernel_launch(void* const* d_in, const int* in_sizes, int n_in,
                              void* d_out, int out_size, void* d_ws, size_t ws_size,
                              hipStream_t stream) {
    const float* features = (const float*)d_in[0];
    const int*   n_ids    = (const int*)d_in[1];
    const int*   src1     = (const int*)d_in[2];
    const int*   src2     = (const int*)d_in[4];
    const int*   src3     = (const int*)d_in[6];
    const float* l1_Wq = (const float*)d_in[8];
    const float* l1_Wk = (const float*)d_in[9];
    const float* l1_Wv = (const float*)d_in[10];
    const float* l1_Ws = (const float*)d_in[11];
    const float* l1_bq = (const float*)d_in[12];
    const float* l1_bk = (const float*)d_in[13];
    const float* l1_bv = (const float*)d_in[14];
    const float* l1_bs = (const float*)d_in[15];
    const float* l1_Wb = (const float*)d_in[16];
    const float* l2_Wq = (const float*)d_in[17];
    const float* l2_Wk = (const float*)d_in[18];
    const float* l2_Wv = (const float*)d_in[19];
    const float* l2_Ws = (const float*)d_in[20];
    const float* l2_bq = (const float*)d_in[21];
    const float* l2_bk = (const float*)d_in[22];
    const float* l2_bv = (const float*)d_in[23];
    const float* l2_bs = (const float*)d_in[24];
    const float* l2_Wb = (const float*)d_in[25];
    const float* l3_Wq = (const float*)d_in[26];
    const float* l3_Wk = (const float*)d_in[27];
    const float* l3_Wv = (const float*)d_in[28];
    const float* l3_Ws = (const float*)d_in[29];
    const float* l3_bq = (const float*)d_in[30];
    const float* l3_bk = (const float*)d_in[31];
    const float* l3_bv = (const float*)d_in[32];
    const float* l3_bs = (const float*)d_in[33];
    const float* l3_Wb = (const float*)d_in[34];
    const float* w_omega = (const float*)d_in[35];
    const float* b_omega = (const float*)d_in[36];
    const float* u_omega = (const float*)d_in[37];
    const float* rl      = (const float*)d_in[38];

    // ---- workspace layout: per-relation buffers ----
    float* ws = (float*)d_ws;
    size_t o = 0;
    float* emb = ws + o; o += (size_t)3 * N3 * H;
    float* qs1 = ws + o; o += (size_t)3 * N1 * 512;
    float* qs2 = ws + o; o += (size_t)3 * N2 * 256;
    float* qs3 = ws + o; o += (size_t)3 * N3 * 512;
    float* ps  = ws + o; o += (size_t)3 * 64 * H;
    float* pss = ws + o; o += (size_t)3 * 64 * H;
    float* muv   = ws + o; o += (size_t)3 * H;
    float* istdv = ws + o; o += (size_t)3 * H;

    bf16* bws = (bf16*)(ws + o);
    size_t b = 0;
    bf16* kv1 = bws + b; b += (size_t)3 * N0 * 512;
    bf16* x1b = bws + b; b += (size_t)3 * N1 * 256;
    bf16* kv2 = bws + b; b += (size_t)3 * N1 * 256;
    bf16* x2b = bws + b; b += (size_t)3 * N2 * 128;
    bf16* kv3 = bws + b; b += (size_t)3 * N2 * 512;
    bf16* Wkv1 = bws + b; b += (size_t)3 * 512 * H;
    bf16* Wqs1 = bws + b; b += (size_t)3 * 512 * H;
    bf16* Wkv2 = bws + b; b += (size_t)3 * 256 * H;
    bf16* Wqs2 = bws + b; b += (size_t)3 * 256 * H;
    bf16* Wkv3 = bws + b; b += (size_t)3 * 512 * 128;
    bf16* Wqs3 = bws + b; b += (size_t)3 * 512 * 128;

    const float sc128 = 0.088388347648318447f;  // 1/sqrt(128)
    const float sc256 = 0.0625f;                // 1/sqrt(256)

    // ---- all weight packs, one dispatch (LDS-tiled transpose) ----
    pack_all<<<dim3(8, 3, 6), 256, 0, stream>>>(
        l1_Wk, l1_Wv, l1_Wq, l1_Ws, l2_Wk, l2_Wv, l2_Wq, l2_Ws,
        l3_Wk, l3_Wv, l3_Wq, l3_Ws, Wkv1, Wqs1, Wkv2, Wqs2, Wkv3, Wqs3);

    // ---- L1 (gather-fused, kv/qs interleaved grid): 64x512 tile, 512 thr ----
    {
        int nbKV = (N0 + 63) / 64, nbQS = (N1 + 63) / 64;
        gemm_l1_fused<<<dim3(nbKV + nbQS, 1, 3), 512, 0, stream>>>(
            features, n_ids, Wkv1, Wqs1, l1_bk, l1_bv, l1_bq, l1_bs,
            kv1, (size_t)N0 * 512, qs1, (size_t)N1 * 512);
    }
    attn_gate<4, 2><<<dim3((N1 + 3) / 4, 3), 256, 0, stream>>>(
        qs1, (size_t)N1 * 512, kv1, (size_t)N0 * 512, src1, l1_Wb,
        (float*)nullptr, 0, x1b, (size_t)N1 * 256, N1, sc128);
    colstat_partial<<<dim3(64, 3), 256, 0, stream>>>(x1b, (size_t)N1 * 256, N1, ps, pss);
    colstats_final<<<dim3(1, 3), 256, 0, stream>>>(ps, pss, N1, muv, istdv);

    // ---- L2 (norm+ELU folded into A-staging): din=256, hc=128, N=256, K=256 ----
    {
        int nbKV = (N1 + 63) / 64, nbQS = (N2 + 63) / 64;
        gemm_dual<256, true><<<dim3(nbKV + nbQS, 1, 3), 256, 0, stream>>>(
            x1b, (size_t)N1 * 256, muv, istdv,
            Wkv2, Wqs2, l2_bk, l2_bv, l2_bq, l2_bs, 128,
            kv2, (size_t)N1 * 256, N1, qs2, (size_t)N2 * 256, N2, nbKV);
    }
    attn_gate<2, 1><<<dim3((N2 + 3) / 4, 3), 256, 0, stream>>>(
        qs2, (size_t)N2 * 256, kv2, (size_t)N1 * 256, src2, l2_Wb,
        (float*)nullptr, 0, x2b, (size_t)N2 * 128, N2, sc128);

    // ---- L3: din=128, heads=1, ch=256, hc=256, N=512, K=128 ----
    {
        int nbKV = (N2 + 63) / 64, nbQS = (N3 + 63) / 64;
        gemm_dual<128, false><<<dim3(nbKV + nbQS, 2, 3), 256, 0, stream>>>(
            x2b, (size_t)N2 * 128, (const float*)nullptr, (const float*)nullptr,
            Wkv3, Wqs3, l3_bk, l3_bv, l3_bq, l3_bs, 256,
            kv3, (size_t)N2 * 512, N2, qs3, (size_t)N3 * 512, N3, nbKV);
    }
    attn_gate<4, 1><<<dim3((N3 + 3) / 4, 3), 256, 0, stream>>>(
        qs3, (size_t)N3 * 512, kv3, (size_t)N2 * 512, src3, l3_Wb,
        emb, (size_t)N3 * H, (bf16*)nullptr, 0, N3, sc256);

    semantic_kernel<<<N3, 256, 0, stream>>>(emb, w_omega, b_omega, u_omega, rl, (float*)d_out);
}

// Round 13
// 536.229 us; speedup vs baseline: 4.5603x; 1.0280x over previous
//
#include <hip/hip_runtime.h>
#include <hip/hip_bf16.h>
#include <math.h>

#define H 256
#define N0 50000
#define N1 10000
#define N2 4000
#define N3 1024
#define FAN 16

typedef __hip_bfloat16 bf16;
typedef __attribute__((ext_vector_type(8))) short short8;
typedef __attribute__((ext_vector_type(4))) short short4v;
typedef __attribute__((ext_vector_type(2))) short short2v;
typedef __attribute__((ext_vector_type(4))) float floatx4;

typedef const __attribute__((address_space(1))) void* gas_ptr;
typedef __attribute__((address_space(3))) void* las_ptr;

__device__ __forceinline__ void load_lds16(const void* g, void* l) {
    __builtin_amdgcn_global_load_lds((gas_ptr)g, (las_ptr)l, 16, 0, 0);
}

__device__ __forceinline__ float2 cvt_bf2(unsigned u) {
    union { unsigned q; float f; } lo, hi;
    lo.q = u << 16; hi.q = u & 0xffff0000u;
    return make_float2(lo.f, hi.f);
}

// ---------------- L1 gather-fused GEMM: 64x512 tile, 512 thr (8 waves) ----------------
// STATUS (round-11): at rate-law floor. FETCH 118MB = 3 x 39.35MB unique gathered
// rows per relation, fetched exactly once per z (cross-z reuse impossible: 255MB
// write stream evicts features). 374MB @ 2.45 TB/s = 153us vs 157 measured. DONE.
// RULE (round-8): never convert a column-reduction into same-address global
// atomics when rows >> 1000 — 10k serialized atomics/address = 1.9ms.
__global__ __launch_bounds__(512, 4) void gemm_l1_fused(
    const float* __restrict__ F, const int* __restrict__ n_ids,
    const bf16* __restrict__ BtKV, const bf16* __restrict__ BtQS,
    const float* __restrict__ bk, const float* __restrict__ bv,
    const float* __restrict__ bq, const float* __restrict__ bs,
    bf16* __restrict__ Ckv, size_t CkvStr,
    float* __restrict__ Cqs, size_t CqsStr)
{
    constexpr int K = 256, Nh = 256, N = 512, KC = K / 32;
    constexpr int NBKV = (N0 + 63) / 64, NBQS = (N1 + 63) / 64;
    __shared__ bf16 A_s[64 * K];

    const int z = blockIdx.z;
    int x = blockIdx.x, bxl;
    if (x < 2 * NBQS) bxl = (x & 1) ? (NBKV + (x >> 1)) : (x >> 1);
    else              bxl = x - NBQS;
    const bool isKV = bxl < NBKV;
    const int bx = isKV ? bxl : bxl - NBKV;
    const int M = isKV ? N0 : N1;
    const bf16* Bt = (isKV ? BtKV : BtQS) + (size_t)z * N * K;
    const float* b1 = (isKV ? bk : bq) + (size_t)z * Nh;
    const float* b2 = (isKV ? bv : bs) + (size_t)z * Nh;

    const int lane = threadIdx.x & 63;
    const int w = threadIdx.x >> 6;             // 0..7 (col group)
    const int lm = lane & 15;
    const int q = lane >> 4;
    const int mbase = bx * 64;

    // ---- gather-stage A (64 x 256): LDS chunk c of row r holds global chunk c^(r&7) ----
    {
        const int* idz = n_ids + (size_t)z * N0;
        #pragma unroll 4
        for (int j = 0; j < 8; j++) {
            int row = w * 8 + j;
            int grow = mbase + row; grow = grow < M ? grow : M - 1;
            int gidx = idz[grow];               // wave-uniform -> scalar load
            float4 v = *(const float4*)(F + (size_t)gidx * H + lane * 4);
            bf16 t4[4] = {(bf16)v.x, (bf16)v.y, (bf16)v.z, (bf16)v.w};
            int c16 = (lane >> 1) ^ (row & 7);  // 16B bf16 chunk, XOR swizzle
            *(short4v*)(A_s + (size_t)row * K + c16 * 8 + (lane & 1) * 4) =
                *(const short4v*)t4;
        }
    }

    const bf16* bp[4];
    #pragma unroll
    for (int ni = 0; ni < 4; ni++)
        bp[ni] = Bt + (size_t)(w * 64 + ni * 16 + lm) * K + q * 8;

    floatx4 acc[4][4];
    #pragma unroll
    for (int i = 0; i < 4; i++)
        #pragma unroll
        for (int j = 0; j < 4; j++)
            acc[i][j] = (floatx4){0.f, 0.f, 0.f, 0.f};

    // 3-deep B ring preload (L2-resident weights), issued before the barrier
    short8 br0[4], br1[4], br2[4];
    #pragma unroll
    for (int ni = 0; ni < 4; ni++) br0[ni] = *(const short8*)(bp[ni]);
    #pragma unroll
    for (int ni = 0; ni < 4; ni++) br1[ni] = *(const short8*)(bp[ni] + 32);
    #pragma unroll
    for (int ni = 0; ni < 4; ni++) br2[ni] = *(const short8*)(bp[ni] + 64);

    __syncthreads();

    #pragma unroll
    for (int kc = 0; kc < KC; kc++) {
        short8 bc[4];
        #pragma unroll
        for (int ni = 0; ni < 4; ni++) {
            bc[ni] = br0[ni]; br0[ni] = br1[ni]; br1[ni] = br2[ni];
        }
        if (kc + 3 < KC) {
            #pragma unroll
            for (int ni = 0; ni < 4; ni++)
                br2[ni] = *(const short8*)(bp[ni] + (kc + 3) * 32);
        }
        short8 af[4];
        #pragma unroll
        for (int mi = 0; mi < 4; mi++) {
            int row = mi * 16 + lm;
            af[mi] = *(const short8*)(A_s + row * K + (((kc * 4 + q) ^ (lm & 7)) * 8));
        }
        #pragma unroll
        for (int mi = 0; mi < 4; mi++)
            #pragma unroll
            for (int ni = 0; ni < 4; ni++)
                acc[mi][ni] = __builtin_amdgcn_mfma_f32_16x16x32_bf16(
                    af[mi], bc[ni], acc[mi][ni], 0, 0, 0);
    }

    // C/D layout: col = lane&15, row = (lane>>4)*4 + reg  [m89]
    if (isKV) {
        bf16* C = Ckv + (size_t)z * CkvStr;
        __syncthreads();                        // A_s dead; reuse as transpose stage
        bf16* stg = A_s + (size_t)w * (16 * 72);    // 8 waves x 2304B = 18KB < 32KB
        #pragma unroll
        for (int p = 0; p < 4; p++) {           // p == mi
            #pragma unroll
            for (int ni = 0; ni < 4; ni++) {
                int colg = w * 64 + ni * 16 + lm;
                float bias = (colg < Nh) ? b1[colg] : b2[colg - Nh];
                #pragma unroll
                for (int rg = 0; rg < 4; rg++)
                    stg[(q * 4 + rg) * 72 + ni * 16 + lm] = (bf16)(acc[p][ni][rg] + bias);
            }
            #pragma unroll
            for (int it = 0; it < 2; it++) {
                int rl = it * 8 + (lane >> 3);
                int grow = mbase + p * 16 + rl;
                short8 vv = *(const short8*)(stg + rl * 72 + (lane & 7) * 8);
                if (grow < M)
                    *(short8*)(C + (size_t)grow * N + w * 64 + (lane & 7) * 8) = vv;
            }
        }
    } else {
        float* C = Cqs + (size_t)z * CqsStr;
        __syncthreads();                        // A_s dead; reuse as f32 store stage
        float* stgf = (float*)A_s + (size_t)w * (16 * 64);  // 8 waves x 4KB = 32KB exact
        #pragma unroll
        for (int p = 0; p < 4; p++) {           // p == mi
            #pragma unroll
            for (int ni = 0; ni < 4; ni++) {
                int colg = w * 64 + ni * 16 + lm;
                float bias = (colg < Nh) ? b1[colg] : b2[colg - Nh];
                #pragma unroll
                for (int rg = 0; rg < 4; rg++)
                    stgf[(q * 4 + rg) * 64 + ni * 16 + lm] = acc[p][ni][rg] + bias;
            }
            #pragma unroll
            for (int it = 0; it < 4; it++) {
                int rl = it * 4 + q;
                int rr = mbase + p * 16 + rl;
                float4 vv = *(const float4*)(stgf + rl * 64 + lm * 4);
                if (rr < M)
                    *(float4*)(C + (size_t)rr * N + w * 64 + lm * 4) = vv;
            }
        }
    }
}

// ---------------- dual-output LDS-A MFMA GEMM (L2/L3) ----------------
// NORM mode (L2): (x-mu)*istd -> ELU applied during A-staging (reg-staged bf16,
// same XOR-swizzled LDS layout; K-loop/epilogue untouched).
// qs epilogue LDS-coalesced (round-10 full-line store rate fix).
template<int K, bool NORM>
__global__ __launch_bounds__(256, 4) void gemm_dual(
    const bf16* __restrict__ A, size_t Astr,
    const float* __restrict__ muv, const float* __restrict__ istdv,
    const bf16* __restrict__ BtKV, const bf16* __restrict__ BtQS,
    const float* __restrict__ bk, const float* __restrict__ bv,
    const float* __restrict__ bq, const float* __restrict__ bs, int Nh,
    bf16* __restrict__ Ckv, size_t CkvStr, int Mkv,
    float* __restrict__ Cqs, size_t CqsStr, int Mqs,
    int nbKV)
{
    constexpr int KC = K / 32;
    constexpr int CPR = K / 8;                  // 16B chunks per row
    constexpr int LOG_CPR = (K == 256) ? 5 : 4;
    constexpr int RPI = 64 / CPR;               // rows per staging issue
    constexpr int ISSUES = 16 / RPI;            // per wave (16 rows/wave)
    const int N = 2 * Nh;
    __shared__ bf16 A_s[64 * K];

    const int z = blockIdx.z;
    const bool isKV = (int)blockIdx.x < nbKV;
    const int bx = isKV ? blockIdx.x : blockIdx.x - nbKV;
    const int M = isKV ? Mkv : Mqs;
    const bf16* Bt = (isKV ? BtKV : BtQS) + (size_t)z * N * K;
    const float* b1 = (isKV ? bk : bq) + (size_t)z * Nh;
    const float* b2 = (isKV ? bv : bs) + (size_t)z * Nh;
    A += (size_t)z * Astr;

    const int lane = threadIdx.x & 63;
    const int w = threadIdx.x >> 6;             // 0..3 (col group)
    const int lm = lane & 15;
    const int q = lane >> 4;
    const int mbase = bx * 64;
    const int n0 = blockIdx.y * 256;

    // ---- stage A tile (64 x K): LDS chunk c of row r holds global chunk c^(r&7) ----
    {
        const int ch = lane & (CPR - 1);
        const int rsub = lane >> LOG_CPR;
        if constexpr (NORM) {
            const float* muz = muv + (size_t)z * K;
            const float* isz = istdv + (size_t)z * K;
            #pragma unroll
            for (int i = 0; i < ISSUES; i++) {
                int row = w * 16 + i * RPI + rsub;
                int grow = mbase + row; grow = grow < M ? grow : M - 1;
                int gch = ch ^ (row & 7);
                short8 raw = *(const short8*)(A + (size_t)grow * K + gch * 8);
                float4 m0 = *(const float4*)(muz + gch * 8);
                float4 m1 = *(const float4*)(muz + gch * 8 + 4);
                float4 i0 = *(const float4*)(isz + gch * 8);
                float4 i1 = *(const float4*)(isz + gch * 8 + 4);
                float mm[8] = {m0.x, m0.y, m0.z, m0.w, m1.x, m1.y, m1.z, m1.w};
                float ii[8] = {i0.x, i0.y, i0.z, i0.w, i1.x, i1.y, i1.z, i1.w};
                bf16 outb[8];
                #pragma unroll
                for (int j = 0; j < 8; j++) {
                    union { unsigned u; float f; } cv;
                    cv.u = ((unsigned)(unsigned short)raw[j]) << 16;
                    float t = (cv.f - mm[j]) * ii[j];
                    t = t > 0.f ? t : __expf(t) - 1.0f;
                    outb[j] = (bf16)t;
                }
                *(short8*)(A_s + (size_t)row * K + ch * 8) = *(const short8*)outb;
            }
        } else {
            #pragma unroll
            for (int i = 0; i < ISSUES; i++) {
                int row = w * 16 + i * RPI + rsub;
                int grow = mbase + row; grow = grow < M ? grow : M - 1;
                int gch = ch ^ (row & 7);
                load_lds16(A + (size_t)grow * K + gch * 8,
                           A_s + (size_t)(w * 16 + i * RPI) * K);
            }
        }
    }

    const bf16* bp[4];
    #pragma unroll
    for (int ni = 0; ni < 4; ni++)
        bp[ni] = Bt + (size_t)(n0 + w * 64 + ni * 16 + lm) * K + q * 8;

    floatx4 acc[4][4];
    #pragma unroll
    for (int i = 0; i < 4; i++)
        #pragma unroll
        for (int j = 0; j < 4; j++)
            acc[i][j] = (floatx4){0.f, 0.f, 0.f, 0.f};

    // 3-deep B ring preload, issued before the barrier (overlaps staging drain)
    short8 br0[4], br1[4], br2[4];
    #pragma unroll
    for (int ni = 0; ni < 4; ni++) br0[ni] = *(const short8*)(bp[ni]);
    #pragma unroll
    for (int ni = 0; ni < 4; ni++) br1[ni] = *(const short8*)(bp[ni] + 32);
    #pragma unroll
    for (int ni = 0; ni < 4; ni++) br2[ni] = *(const short8*)(bp[ni] + 64);

    __syncthreads();

    #pragma unroll
    for (int kc = 0; kc < KC; kc++) {
        short8 bc[4];
        #pragma unroll
        for (int ni = 0; ni < 4; ni++) {
            bc[ni] = br0[ni]; br0[ni] = br1[ni]; br1[ni] = br2[ni];
        }
        if (kc + 3 < KC) {
            #pragma unroll
            for (int ni = 0; ni < 4; ni++)
                br2[ni] = *(const short8*)(bp[ni] + (kc + 3) * 32);
        }
        short8 af[4];
        #pragma unroll
        for (int mi = 0; mi < 4; mi++) {
            int row = mi * 16 + lm;
            af[mi] = *(const short8*)(A_s + row * K + (((kc * 4 + q) ^ (lm & 7)) * 8));
        }
        #pragma unroll
        for (int mi = 0; mi < 4; mi++)
            #pragma unroll
            for (int ni = 0; ni < 4; ni++)
                acc[mi][ni] = __builtin_amdgcn_mfma_f32_16x16x32_bf16(
                    af[mi], bc[ni], acc[mi][ni], 0, 0, 0);
    }

    // C/D layout: col = lane&15, row = (lane>>4)*4 + reg  [m89]
    if (isKV) {
        bf16* C = Ckv + (size_t)z * CkvStr;
        __syncthreads();                        // A_s dead; reuse as transpose stage
        bf16* stg = A_s + (size_t)w * (16 * 72);
        #pragma unroll
        for (int p = 0; p < 4; p++) {           // p == mi
            #pragma unroll
            for (int ni = 0; ni < 4; ni++) {
                int colg = n0 + w * 64 + ni * 16 + lm;
                float bias = (colg < Nh) ? b1[colg] : b2[colg - Nh];
                #pragma unroll
                for (int rg = 0; rg < 4; rg++)
                    stg[(q * 4 + rg) * 72 + ni * 16 + lm] = (bf16)(acc[p][ni][rg] + bias);
            }
            #pragma unroll
            for (int it = 0; it < 2; it++) {
                int rl = it * 8 + (lane >> 3);
                int grow = mbase + p * 16 + rl;
                short8 vv = *(const short8*)(stg + rl * 72 + (lane & 7) * 8);
                if (grow < M)
                    *(short8*)(C + (size_t)grow * N + n0 + w * 64 + (lane & 7) * 8) = vv;
            }
        }
    } else {
        float* C = Cqs + (size_t)z * CqsStr;
        __syncthreads();                        // A_s dead; reuse as f32 store stage
        float* stgf = (float*)A_s + (size_t)w * (16 * 64);  // 4 waves x 4KB <= 16KB
        #pragma unroll
        for (int p = 0; p < 4; p++) {           // p == mi
            #pragma unroll
            for (int ni = 0; ni < 4; ni++) {
                int colg = n0 + w * 64 + ni * 16 + lm;
                float bias = (colg < Nh) ? b1[colg] : b2[colg - Nh];
                #pragma unroll
                for (int rg = 0; rg < 4; rg++)
                    stgf[(q * 4 + rg) * 64 + ni * 16 + lm] = acc[p][ni][rg] + bias;
            }
            #pragma unroll
            for (int it = 0; it < 4; it++) {
                int rl = it * 4 + q;
                int rr = mbase + p * 16 + rl;
                float4 vv = *(const float4*)(stgf + rl * 64 + lm * 4);
                if (rr < M)
                    *(float4*)(C + (size_t)rr * N + n0 + w * 64 + lm * 4) = vv;
            }
        }
    }
}

// ---------------- weight packs: LDS-tiled TRANSPOSE (round-11, ~-5us) ----------------
__global__ __launch_bounds__(256) void pack_all(
    const float* __restrict__ l1_Wk, const float* __restrict__ l1_Wv,
    const float* __restrict__ l1_Wq, const float* __restrict__ l1_Ws,
    const float* __restrict__ l2_Wk, const float* __restrict__ l2_Wv,
    const float* __restrict__ l2_Wq, const float* __restrict__ l2_Ws,
    const float* __restrict__ l3_Wk, const float* __restrict__ l3_Wv,
    const float* __restrict__ l3_Wq, const float* __restrict__ l3_Ws,
    bf16* __restrict__ Wkv1, bf16* __restrict__ Wqs1,
    bf16* __restrict__ Wkv2, bf16* __restrict__ Wqs2,
    bf16* __restrict__ Wkv3, bf16* __restrict__ Wqs3)
{
    int job = blockIdx.z, r = blockIdx.y;
    const float *W1, *W2; bf16* Wt; int K, Nh;
    switch (job) {
        case 0: W1 = l1_Wk; W2 = l1_Wv; Wt = Wkv1; K = 256; Nh = 256; break;
        case 1: W1 = l1_Wq; W2 = l1_Ws; Wt = Wqs1; K = 256; Nh = 256; break;
        case 2: W1 = l2_Wk; W2 = l2_Wv; Wt = Wkv2; K = 256; Nh = 128; break;
        case 3: W1 = l2_Wq; W2 = l2_Ws; Wt = Wqs2; K = 256; Nh = 128; break;
        case 4: W1 = l3_Wk; W2 = l3_Wv; Wt = Wkv3; K = 128; Nh = 256; break;
        default: W1 = l3_Wq; W2 = l3_Ws; Wt = Wqs3; K = 128; Nh = 256; break;
    }
    int nn0 = blockIdx.x * 64;
    if (nn0 >= 2 * Nh) return;                  // whole-block uniform exit

    __shared__ float tile[64][65];              // +1 pad: conflict-free transpose
    size_t wstride = (size_t)K * Nh;
    const float* Wsrc = ((nn0 < Nh) ? W1 : W2) + (size_t)r * wstride;
    int col0 = (nn0 < Nh) ? nn0 : nn0 - Nh;
    bf16* Wdst = Wt + (size_t)r * 2 * wstride;

    int tq = threadIdx.x >> 6;                  // 0..3
    int tl = threadIdx.x & 63;

    for (int k0 = 0; k0 < K; k0 += 64) {
        #pragma unroll
        for (int j = 0; j < 16; j++) {
            int kl = tq * 16 + j;
            tile[kl][tl] = Wsrc[(size_t)(k0 + kl) * Nh + col0 + tl];
        }
        __syncthreads();
        #pragma unroll
        for (int j = 0; j < 16; j++) {
            int nl = tq * 16 + j;
            Wdst[(size_t)(nn0 + nl) * K + k0 + tl] = (bf16)tile[tl][nl];
        }
        __syncthreads();
    }
}

// ---------------- fused attention + gated skip ----------------
// v-prefetch: both random-access rounds issued back-to-back (in-order vmcnt
// keeps k-consumes unaffected; v latency hides under softmax math).
// (attn1 measured ~50us via round-8/9 differencing — near its L3-served floor.)
template<int CPL, int HEADS>   // hc = CPL*64
__global__ __launch_bounds__(256) void attn_gate(
    const float* __restrict__ qs, size_t qsStr,
    const bf16* __restrict__ kv, size_t kvStr,
    const int* __restrict__ src,
    const float* __restrict__ Wb,
    float* __restrict__ yf, size_t yfStr,
    bf16* __restrict__ yb, size_t ybStr,
    int ndst, float scale)
{
    constexpr int hc = CPL * 64;
    constexpr int LPH = 64 / HEADS;
    const int z = blockIdx.y;
    int lane = threadIdx.x & 63;
    int d = blockIdx.x * 4 + (threadIdx.x >> 6);
    if (d >= ndst) return;
    qs += (size_t)z * qsStr;
    kv += (size_t)z * kvStr;
    src += (size_t)z * ndst * FAN;
    Wb += (size_t)z * 3 * hc;

    const float* qp = qs + (size_t)d * (2 * hc) + lane * CPL;
    float qv[CPL], xv[CPL];
    if constexpr (CPL == 2) {
        float2 a = *(const float2*)qp;
        float2 b = *(const float2*)(qp + hc);
        qv[0] = a.x; qv[1] = a.y; xv[0] = b.x; xv[1] = b.y;
    } else {
        float4 a = *(const float4*)qp;
        float4 b = *(const float4*)(qp + hc);
        qv[0] = a.x; qv[1] = a.y; qv[2] = a.z; qv[3] = a.w;
        xv[0] = b.x; xv[1] = b.y; xv[2] = b.z; xv[3] = b.w;
    }
    const int* sp = src + (size_t)d * FAN;
    int sidx[FAN];
    #pragma unroll
    for (int e = 0; e < FAN; e++) sidx[e] = sp[e];

    // partial dots (all k loads issued before the shuffle phase)
    float part[FAN];
    #pragma unroll
    for (int e = 0; e < FAN; e++) {
        const bf16* kp = kv + (size_t)sidx[e] * (2 * hc) + lane * CPL;
        if constexpr (CPL == 2) {
            float2 kf = cvt_bf2(*(const unsigned*)kp);
            part[e] = qv[0] * kf.x + qv[1] * kf.y;
        } else {
            uint2 u = *(const uint2*)kp;
            float2 k0 = cvt_bf2(u.x), k1 = cvt_bf2(u.y);
            part[e] = qv[0] * k0.x + qv[1] * k0.y + qv[2] * k1.x + qv[3] * k1.y;
        }
    }

    // prefetch v rows into regs (overlaps softmax below)
    uint2 vreg[FAN];
    #pragma unroll
    for (int e = 0; e < FAN; e++) {
        const bf16* vp = kv + (size_t)sidx[e] * (2 * hc) + hc + lane * CPL;
        if constexpr (CPL == 2) vreg[e].x = *(const unsigned*)vp;
        else                    vreg[e]   = *(const uint2*)vp;
    }

    float logit[FAN], mx = -1e30f;
    #pragma unroll
    for (int e = 0; e < FAN; e++) {
        float dt = part[e];
        #pragma unroll
        for (int off = LPH / 2; off > 0; off >>= 1) dt += __shfl_xor(dt, off, 64);
        dt *= scale;
        logit[e] = dt;
        mx = fmaxf(mx, dt);
    }
    float zsum = 0.f, p[FAN];
    #pragma unroll
    for (int e = 0; e < FAN; e++) { p[e] = __expf(logit[e] - mx); zsum += p[e]; }
    float inv = 1.f / zsum;

    float ov[CPL];
    #pragma unroll
    for (int j = 0; j < CPL; j++) ov[j] = 0.f;
    #pragma unroll
    for (int e = 0; e < FAN; e++) {
        if constexpr (CPL == 2) {
            float2 vf = cvt_bf2(vreg[e].x);
            ov[0] += p[e] * vf.x; ov[1] += p[e] * vf.y;
        } else {
            float2 v0 = cvt_bf2(vreg[e].x), v1 = cvt_bf2(vreg[e].y);
            ov[0] += p[e] * v0.x; ov[1] += p[e] * v0.y;
            ov[2] += p[e] * v1.x; ov[3] += p[e] * v1.y;
        }
    }
    #pragma unroll
    for (int j = 0; j < CPL; j++) ov[j] *= inv;

    // gated skip
    float s = 0.f;
    #pragma unroll
    for (int j = 0; j < CPL; j++) {
        int c = lane * CPL + j;
        s += ov[j] * Wb[c] + xv[j] * Wb[hc + c] + (ov[j] - xv[j]) * Wb[2 * hc + c];
    }
    #pragma unroll
    for (int off = 32; off > 0; off >>= 1) s += __shfl_xor(s, off, 64);
    float g = 1.f / (1.f + __expf(-s));

    float yv[CPL];
    #pragma unroll
    for (int j = 0; j < CPL; j++) yv[j] = g * xv[j] + (1.f - g) * ov[j];

    if (yf) {
        float* op = yf + (size_t)z * yfStr + (size_t)d * hc + lane * CPL;
        if constexpr (CPL == 2) *(float2*)op = make_float2(yv[0], yv[1]);
        else *(float4*)op = make_float4(yv[0], yv[1], yv[2], yv[3]);
    }
    if (yb) {
        bf16* op = yb + (size_t)z * ybStr + (size_t)d * hc + lane * CPL;
        bf16 tmp[CPL];
        #pragma unroll
        for (int j = 0; j < CPL; j++) tmp[j] = (bf16)yv[j];
        if constexpr (CPL == 2) *(short2v*)op = *(const short2v*)tmp;
        else *(short4v*)op = *(const short4v*)tmp;
    }
}

// ---------------- column stats: VECTORIZED bf16 loads (round-12) ----------------
// Old: one scalar 2B bf16 load per thread per row (156 rows/block) — Common
// mistake #2, ~2-2.5x slower. Now: thread t covers channels (t&31)*8..+8 of
// row base+(t>>5) via short8 — a wave reads 2 rows x 512B fully coalesced.
// 8 interleaved row-partials reduced via 16KB LDS tile at block end.
__global__ __launch_bounds__(256) void colstat_partial(
    const bf16* __restrict__ x, size_t xStr, int M,
    float* __restrict__ ps, float* __restrict__ pss)
{
    int z = blockIdx.y;
    const bf16* xp = x + (size_t)z * xStr;
    int cg = (threadIdx.x & 31) * 8;            // channel-group base
    int rsub = threadIdx.x >> 5;                // 0..7
    int b = blockIdx.x;                         // 0..63
    float s[8], ss[8];
    #pragma unroll
    for (int j = 0; j < 8; j++) { s[j] = 0.f; ss[j] = 0.f; }
    for (int r = b * 8 + rsub; r < M; r += 512) {
        short8 v = *(const short8*)(xp + (size_t)r * H + cg);
        #pragma unroll
        for (int j = 0; j < 8; j++) {
            union { unsigned u; float f; } cv;
            cv.u = ((unsigned)(unsigned short)v[j]) << 16;
            s[j] += cv.f; ss[j] += cv.f * cv.f;
        }
    }
    __shared__ float red[2][8][H];              // 16KB
    #pragma unroll
    for (int j = 0; j < 8; j++) {
        red[0][rsub][cg + j] = s[j];
        red[1][rsub][cg + j] = ss[j];
    }
    __syncthreads();
    int c = threadIdx.x;
    float a = 0.f, aa = 0.f;
    #pragma unroll
    for (int g = 0; g < 8; g++) { a += red[0][g][c]; aa += red[1][g][c]; }
    ps[((size_t)z * 64 + b) * H + c] = a;
    pss[((size_t)z * 64 + b) * H + c] = aa;
}

// tiny: reduce ps/pss (64 partials) -> per-column mu, istd (3 x H each)
__global__ __launch_bounds__(256) void colstats_final(
    const float* __restrict__ ps, const float* __restrict__ pss, int M,
    float* __restrict__ muv, float* __restrict__ istdv)
{
    int z = blockIdx.y;
    int c = threadIdx.x;
    float s = 0.f, ss = 0.f;
    #pragma unroll 8
    for (int b = 0; b < 64; b++) {
        s += ps[((size_t)z * 64 + b) * H + c];
        ss += pss[((size_t)z * 64 + b) * H + c];
    }
    float mu = s / M;
    muv[(size_t)z * H + c] = mu;
    istdv[(size_t)z * H + c] = rsqrtf(ss / M - mu * mu + 1e-5f);
}

// ---------------- semantic attention across the 3 relations ----------------
// shuffle-based score reduction: 7 barriers/block (was 27 with the LDS tree)
__global__ __launch_bounds__(256) void semantic_kernel(
    const float* __restrict__ emb,   // (3, N3, H)
    const float* __restrict__ Wo, const float* __restrict__ bo,
    const float* __restrict__ uo, const float* __restrict__ rl,
    float* __restrict__ outp)
{
    __shared__ float m_s[3][H];
    __shared__ float wsum[4];
    __shared__ float score_s[3];
    int n = blockIdx.x, c = threadIdx.x;
    for (int r = 0; r < 3; r++)
        m_s[r][c] = emb[((size_t)r * N3 + n) * H + c] * rl[r];
    __syncthreads();
    for (int r = 0; r < 3; r++) {
        float t = bo[c];
        #pragma unroll 4
        for (int k2 = 0; k2 < H; k2++) t += m_s[r][k2] * Wo[k2 * H + c];
        float v = tanhf(t) * uo[c];
        #pragma unroll
        for (int off = 32; off > 0; off >>= 1) v += __shfl_xor(v, off, 64);
        if ((c & 63) == 0) wsum[c >> 6] = v;
        __syncthreads();
        if (c == 0) score_s[r] = wsum[0] + wsum[1] + wsum[2] + wsum[3];
        __syncthreads();
    }
    float s0 = score_s[0], s1 = score_s[1], s2 = score_s[2];
    float mx = fmaxf(s0, fmaxf(s1, s2));
    float e0 = __expf(s0 - mx), e1 = __expf(s1 - mx), e2 = __expf(s2 - mx);
    float zi = 1.0f / (e0 + e1 + e2);
    outp[(size_t)n * H + c] = (m_s[0][c] * e0 + m_s[1][c] * e1 + m_s[2][c] * e2) * zi;
}

extern "C" void kernel_launch(void* const* d_in, const int* in_sizes, int n_in,
                              void* d_out, int out_size, void* d_ws, size_t ws_size,
                              hipStream_t stream) {
    const float* features = (const float*)d_in[0];
    const int*   n_ids    = (const int*)d_in[1];
    const int*   src1     = (const int*)d_in[2];
    const int*   src2     = (const int*)d_in[4];
    const int*   src3     = (const int*)d_in[6];
    const float* l1_Wq = (const float*)d_in[8];
    const float* l1_Wk = (const float*)d_in[9];
    const float* l1_Wv = (const float*)d_in[10];
    const float* l1_Ws = (const float*)d_in[11];
    const float* l1_bq = (const float*)d_in[12];
    const float* l1_bk = (const float*)d_in[13];
    const float* l1_bv = (const float*)d_in[14];
    const float* l1_bs = (const float*)d_in[15];
    const float* l1_Wb = (const float*)d_in[16];
    const float* l2_Wq = (const float*)d_in[17];
    const float* l2_Wk = (const float*)d_in[18];
    const float* l2_Wv = (const float*)d_in[19];
    const float* l2_Ws = (const float*)d_in[20];
    const float* l2_bq = (const float*)d_in[21];
    const float* l2_bk = (const float*)d_in[22];
    const float* l2_bv = (const float*)d_in[23];
    const float* l2_bs = (const float*)d_in[24];
    const float* l2_Wb = (const float*)d_in[25];
    const float* l3_Wq = (const float*)d_in[26];
    const float* l3_Wk = (const float*)d_in[27];
    const float* l3_Wv = (const float*)d_in[28];
    const float* l3_Ws = (const float*)d_in[29];
    const float* l3_bq = (const float*)d_in[30];
    const float* l3_bk = (const float*)d_in[31];
    const float* l3_bv = (const float*)d_in[32];
    const float* l3_bs = (const float*)d_in[33];
    const float* l3_Wb = (const float*)d_in[34];
    const float* w_omega = (const float*)d_in[35];
    const float* b_omega = (const float*)d_in[36];
    const float* u_omega = (const float*)d_in[37];
    const float* rl      = (const float*)d_in[38];

    // ---- workspace layout: per-relation buffers ----
    float* ws = (float*)d_ws;
    size_t o = 0;
    float* emb = ws + o; o += (size_t)3 * N3 * H;
    float* qs1 = ws + o; o += (size_t)3 * N1 * 512;
    float* qs2 = ws + o; o += (size_t)3 * N2 * 256;
    float* qs3 = ws + o; o += (size_t)3 * N3 * 512;
    float* ps  = ws + o; o += (size_t)3 * 64 * H;
    float* pss = ws + o; o += (size_t)3 * 64 * H;
    float* muv   = ws + o; o += (size_t)3 * H;
    float* istdv = ws + o; o += (size_t)3 * H;

    bf16* bws = (bf16*)(ws + o);
    size_t b = 0;
    bf16* kv1 = bws + b; b += (size_t)3 * N0 * 512;
    bf16* x1b = bws + b; b += (size_t)3 * N1 * 256;
    bf16* kv2 = bws + b; b += (size_t)3 * N1 * 256;
    bf16* x2b = bws + b; b += (size_t)3 * N2 * 128;
    bf16* kv3 = bws + b; b += (size_t)3 * N2 * 512;
    bf16* Wkv1 = bws + b; b += (size_t)3 * 512 * H;
    bf16* Wqs1 = bws + b; b += (size_t)3 * 512 * H;
    bf16* Wkv2 = bws + b; b += (size_t)3 * 256 * H;
    bf16* Wqs2 = bws + b; b += (size_t)3 * 256 * H;
    bf16* Wkv3 = bws + b; b += (size_t)3 * 512 * 128;
    bf16* Wqs3 = bws + b; b += (size_t)3 * 512 * 128;

    const float sc128 = 0.088388347648318447f;  // 1/sqrt(128)
    const float sc256 = 0.0625f;                // 1/sqrt(256)

    // ---- all weight packs, one dispatch (LDS-tiled transpose) ----
    pack_all<<<dim3(8, 3, 6), 256, 0, stream>>>(
        l1_Wk, l1_Wv, l1_Wq, l1_Ws, l2_Wk, l2_Wv, l2_Wq, l2_Ws,
        l3_Wk, l3_Wv, l3_Wq, l3_Ws, Wkv1, Wqs1, Wkv2, Wqs2, Wkv3, Wqs3);

    // ---- L1 (gather-fused, kv/qs interleaved grid): 64x512 tile, 512 thr ----
    {
        int nbKV = (N0 + 63) / 64, nbQS = (N1 + 63) / 64;
        gemm_l1_fused<<<dim3(nbKV + nbQS, 1, 3), 512, 0, stream>>>(
            features, n_ids, Wkv1, Wqs1, l1_bk, l1_bv, l1_bq, l1_bs,
            kv1, (size_t)N0 * 512, qs1, (size_t)N1 * 512);
    }
    attn_gate<4, 2><<<dim3((N1 + 3) / 4, 3), 256, 0, stream>>>(
        qs1, (size_t)N1 * 512, kv1, (size_t)N0 * 512, src1, l1_Wb,
        (float*)nullptr, 0, x1b, (size_t)N1 * 256, N1, sc128);
    colstat_partial<<<dim3(64, 3), 256, 0, stream>>>(x1b, (size_t)N1 * 256, N1, ps, pss);
    colstats_final<<<dim3(1, 3), 256, 0, stream>>>(ps, pss, N1, muv, istdv);

    // ---- L2 (norm+ELU folded into A-staging): din=256, hc=128, N=256, K=256 ----
    {
        int nbKV = (N1 + 63) / 64, nbQS = (N2 + 63) / 64;
        gemm_dual<256, true><<<dim3(nbKV + nbQS, 1, 3), 256, 0, stream>>>(
            x1b, (size_t)N1 * 256, muv, istdv,
            Wkv2, Wqs2, l2_bk, l2_bv, l2_bq, l2_bs, 128,
            kv2, (size_t)N1 * 256, N1, qs2, (size_t)N2 * 256, N2, nbKV);
    }
    attn_gate<2, 1><<<dim3((N2 + 3) / 4, 3), 256, 0, stream>>>(
        qs2, (size_t)N2 * 256, kv2, (size_t)N1 * 256, src2, l2_Wb,
        (float*)nullptr, 0, x2b, (size_t)N2 * 128, N2, sc128);

    // ---- L3: din=128, heads=1, ch=256, hc=256, N=512, K=128 ----
    {
        int nbKV = (N2 + 63) / 64, nbQS = (N3 + 63) / 64;
        gemm_dual<128, false><<<dim3(nbKV + nbQS, 2, 3), 256, 0, stream>>>(
            x2b, (size_t)N2 * 128, (const float*)nullptr, (const float*)nullptr,
            Wkv3, Wqs3, l3_bk, l3_bv, l3_bq, l3_bs, 256,
            kv3, (size_t)N2 * 512, N2, qs3, (size_t)N3 * 512, N3, nbKV);
    }
    attn_gate<4, 1><<<dim3((N3 + 3) / 4, 3), 256, 0, stream>>>(
        qs3, (size_t)N3 * 512, kv3, (size_t)N2 * 512, src3, l3_Wb,
        emb, (size_t)N3 * H, (bf16*)nullptr, 0, N3, sc256);

    semantic_kernel<<<N3, 256, 0, stream>>>(emb, w_omega, b_omega, u_omega, rl, (float*)d_out);
}

// Round 14
// 532.787 us; speedup vs baseline: 4.5898x; 1.0065x over previous
//
#include <hip/hip_runtime.h>
#include <hip/hip_bf16.h>
#include <math.h>

#define H 256
#define N0 50000
#define N1 10000
#define N2 4000
#define N3 1024
#define FAN 16

typedef __hip_bfloat16 bf16;
typedef __attribute__((ext_vector_type(8))) short short8;
typedef __attribute__((ext_vector_type(4))) short short4v;
typedef __attribute__((ext_vector_type(2))) short short2v;
typedef __attribute__((ext_vector_type(4))) float floatx4;

typedef const __attribute__((address_space(1))) void* gas_ptr;
typedef __attribute__((address_space(3))) void* las_ptr;

__device__ __forceinline__ void load_lds16(const void* g, void* l) {
    __builtin_amdgcn_global_load_lds((gas_ptr)g, (las_ptr)l, 16, 0, 0);
}

__device__ __forceinline__ float2 cvt_bf2(unsigned u) {
    union { unsigned q; float f; } lo, hi;
    lo.q = u << 16; hi.q = u & 0xffff0000u;
    return make_float2(lo.f, hi.f);
}

// ---------------- L1 gather-fused GEMM: 64x512 tile, 512 thr (8 waves) ----------------
// STATUS (round-11..13): at rate-law floor. FETCH 118MB = 3 x 39.35MB unique
// gathered rows per relation, fetched once per z; 374MB @ 2.45 TB/s = 153us vs
// 157 measured (5 consecutive byte-identical runs). DONE.
// RULE (round-8): never convert a column-reduction into same-address global
// atomics when rows >> 1000 — 10k serialized atomics/address = 1.9ms.
__global__ __launch_bounds__(512, 4) void gemm_l1_fused(
    const float* __restrict__ F, const int* __restrict__ n_ids,
    const bf16* __restrict__ BtKV, const bf16* __restrict__ BtQS,
    const float* __restrict__ bk, const float* __restrict__ bv,
    const float* __restrict__ bq, const float* __restrict__ bs,
    bf16* __restrict__ Ckv, size_t CkvStr,
    float* __restrict__ Cqs, size_t CqsStr)
{
    constexpr int K = 256, Nh = 256, N = 512, KC = K / 32;
    constexpr int NBKV = (N0 + 63) / 64, NBQS = (N1 + 63) / 64;
    __shared__ bf16 A_s[64 * K];

    const int z = blockIdx.z;
    int x = blockIdx.x, bxl;
    if (x < 2 * NBQS) bxl = (x & 1) ? (NBKV + (x >> 1)) : (x >> 1);
    else              bxl = x - NBQS;
    const bool isKV = bxl < NBKV;
    const int bx = isKV ? bxl : bxl - NBKV;
    const int M = isKV ? N0 : N1;
    const bf16* Bt = (isKV ? BtKV : BtQS) + (size_t)z * N * K;
    const float* b1 = (isKV ? bk : bq) + (size_t)z * Nh;
    const float* b2 = (isKV ? bv : bs) + (size_t)z * Nh;

    const int lane = threadIdx.x & 63;
    const int w = threadIdx.x >> 6;             // 0..7 (col group)
    const int lm = lane & 15;
    const int q = lane >> 4;
    const int mbase = bx * 64;

    // ---- gather-stage A (64 x 256): LDS chunk c of row r holds global chunk c^(r&7) ----
    {
        const int* idz = n_ids + (size_t)z * N0;
        #pragma unroll 4
        for (int j = 0; j < 8; j++) {
            int row = w * 8 + j;
            int grow = mbase + row; grow = grow < M ? grow : M - 1;
            int gidx = idz[grow];               // wave-uniform -> scalar load
            float4 v = *(const float4*)(F + (size_t)gidx * H + lane * 4);
            bf16 t4[4] = {(bf16)v.x, (bf16)v.y, (bf16)v.z, (bf16)v.w};
            int c16 = (lane >> 1) ^ (row & 7);  // 16B bf16 chunk, XOR swizzle
            *(short4v*)(A_s + (size_t)row * K + c16 * 8 + (lane & 1) * 4) =
                *(const short4v*)t4;
        }
    }

    const bf16* bp[4];
    #pragma unroll
    for (int ni = 0; ni < 4; ni++)
        bp[ni] = Bt + (size_t)(w * 64 + ni * 16 + lm) * K + q * 8;

    floatx4 acc[4][4];
    #pragma unroll
    for (int i = 0; i < 4; i++)
        #pragma unroll
        for (int j = 0; j < 4; j++)
            acc[i][j] = (floatx4){0.f, 0.f, 0.f, 0.f};

    // 3-deep B ring preload (L2-resident weights), issued before the barrier
    short8 br0[4], br1[4], br2[4];
    #pragma unroll
    for (int ni = 0; ni < 4; ni++) br0[ni] = *(const short8*)(bp[ni]);
    #pragma unroll
    for (int ni = 0; ni < 4; ni++) br1[ni] = *(const short8*)(bp[ni] + 32);
    #pragma unroll
    for (int ni = 0; ni < 4; ni++) br2[ni] = *(const short8*)(bp[ni] + 64);

    __syncthreads();

    #pragma unroll
    for (int kc = 0; kc < KC; kc++) {
        short8 bc[4];
        #pragma unroll
        for (int ni = 0; ni < 4; ni++) {
            bc[ni] = br0[ni]; br0[ni] = br1[ni]; br1[ni] = br2[ni];
        }
        if (kc + 3 < KC) {
            #pragma unroll
            for (int ni = 0; ni < 4; ni++)
                br2[ni] = *(const short8*)(bp[ni] + (kc + 3) * 32);
        }
        short8 af[4];
        #pragma unroll
        for (int mi = 0; mi < 4; mi++) {
            int row = mi * 16 + lm;
            af[mi] = *(const short8*)(A_s + row * K + (((kc * 4 + q) ^ (lm & 7)) * 8));
        }
        #pragma unroll
        for (int mi = 0; mi < 4; mi++)
            #pragma unroll
            for (int ni = 0; ni < 4; ni++)
                acc[mi][ni] = __builtin_amdgcn_mfma_f32_16x16x32_bf16(
                    af[mi], bc[ni], acc[mi][ni], 0, 0, 0);
    }

    // C/D layout: col = lane&15, row = (lane>>4)*4 + reg  [m89]
    if (isKV) {
        bf16* C = Ckv + (size_t)z * CkvStr;
        __syncthreads();                        // A_s dead; reuse as transpose stage
        bf16* stg = A_s + (size_t)w * (16 * 72);    // 8 waves x 2304B = 18KB < 32KB
        #pragma unroll
        for (int p = 0; p < 4; p++) {           // p == mi
            #pragma unroll
            for (int ni = 0; ni < 4; ni++) {
                int colg = w * 64 + ni * 16 + lm;
                float bias = (colg < Nh) ? b1[colg] : b2[colg - Nh];
                #pragma unroll
                for (int rg = 0; rg < 4; rg++)
                    stg[(q * 4 + rg) * 72 + ni * 16 + lm] = (bf16)(acc[p][ni][rg] + bias);
            }
            #pragma unroll
            for (int it = 0; it < 2; it++) {
                int rl = it * 8 + (lane >> 3);
                int grow = mbase + p * 16 + rl;
                short8 vv = *(const short8*)(stg + rl * 72 + (lane & 7) * 8);
                if (grow < M)
                    *(short8*)(C + (size_t)grow * N + w * 64 + (lane & 7) * 8) = vv;
            }
        }
    } else {
        float* C = Cqs + (size_t)z * CqsStr;
        __syncthreads();                        // A_s dead; reuse as f32 store stage
        float* stgf = (float*)A_s + (size_t)w * (16 * 64);  // 8 waves x 4KB = 32KB exact
        #pragma unroll
        for (int p = 0; p < 4; p++) {           // p == mi
            #pragma unroll
            for (int ni = 0; ni < 4; ni++) {
                int colg = w * 64 + ni * 16 + lm;
                float bias = (colg < Nh) ? b1[colg] : b2[colg - Nh];
                #pragma unroll
                for (int rg = 0; rg < 4; rg++)
                    stgf[(q * 4 + rg) * 64 + ni * 16 + lm] = acc[p][ni][rg] + bias;
            }
            #pragma unroll
            for (int it = 0; it < 4; it++) {
                int rl = it * 4 + q;
                int rr = mbase + p * 16 + rl;
                float4 vv = *(const float4*)(stgf + rl * 64 + lm * 4);
                if (rr < M)
                    *(float4*)(C + (size_t)rr * N + w * 64 + lm * 4) = vv;
            }
        }
    }
}

// ---------------- dual-output LDS-A MFMA GEMM (L2/L3) ----------------
// NORM mode (L2): (x-mu)*istd -> ELU applied during A-staging (reg-staged bf16,
// same XOR-swizzled LDS layout; K-loop/epilogue untouched).
// qs epilogue LDS-coalesced (round-10 full-line store rate fix).
template<int K, bool NORM>
__global__ __launch_bounds__(256, 4) void gemm_dual(
    const bf16* __restrict__ A, size_t Astr,
    const float* __restrict__ muv, const float* __restrict__ istdv,
    const bf16* __restrict__ BtKV, const bf16* __restrict__ BtQS,
    const float* __restrict__ bk, const float* __restrict__ bv,
    const float* __restrict__ bq, const float* __restrict__ bs, int Nh,
    bf16* __restrict__ Ckv, size_t CkvStr, int Mkv,
    float* __restrict__ Cqs, size_t CqsStr, int Mqs,
    int nbKV)
{
    constexpr int KC = K / 32;
    constexpr int CPR = K / 8;                  // 16B chunks per row
    constexpr int LOG_CPR = (K == 256) ? 5 : 4;
    constexpr int RPI = 64 / CPR;               // rows per staging issue
    constexpr int ISSUES = 16 / RPI;            // per wave (16 rows/wave)
    const int N = 2 * Nh;
    __shared__ bf16 A_s[64 * K];

    const int z = blockIdx.z;
    const bool isKV = (int)blockIdx.x < nbKV;
    const int bx = isKV ? blockIdx.x : blockIdx.x - nbKV;
    const int M = isKV ? Mkv : Mqs;
    const bf16* Bt = (isKV ? BtKV : BtQS) + (size_t)z * N * K;
    const float* b1 = (isKV ? bk : bq) + (size_t)z * Nh;
    const float* b2 = (isKV ? bv : bs) + (size_t)z * Nh;
    A += (size_t)z * Astr;

    const int lane = threadIdx.x & 63;
    const int w = threadIdx.x >> 6;             // 0..3 (col group)
    const int lm = lane & 15;
    const int q = lane >> 4;
    const int mbase = bx * 64;
    const int n0 = blockIdx.y * 256;

    // ---- stage A tile (64 x K): LDS chunk c of row r holds global chunk c^(r&7) ----
    {
        const int ch = lane & (CPR - 1);
        const int rsub = lane >> LOG_CPR;
        if constexpr (NORM) {
            const float* muz = muv + (size_t)z * K;
            const float* isz = istdv + (size_t)z * K;
            #pragma unroll
            for (int i = 0; i < ISSUES; i++) {
                int row = w * 16 + i * RPI + rsub;
                int grow = mbase + row; grow = grow < M ? grow : M - 1;
                int gch = ch ^ (row & 7);
                short8 raw = *(const short8*)(A + (size_t)grow * K + gch * 8);
                float4 m0 = *(const float4*)(muz + gch * 8);
                float4 m1 = *(const float4*)(muz + gch * 8 + 4);
                float4 i0 = *(const float4*)(isz + gch * 8);
                float4 i1 = *(const float4*)(isz + gch * 8 + 4);
                float mm[8] = {m0.x, m0.y, m0.z, m0.w, m1.x, m1.y, m1.z, m1.w};
                float ii[8] = {i0.x, i0.y, i0.z, i0.w, i1.x, i1.y, i1.z, i1.w};
                bf16 outb[8];
                #pragma unroll
                for (int j = 0; j < 8; j++) {
                    union { unsigned u; float f; } cv;
                    cv.u = ((unsigned)(unsigned short)raw[j]) << 16;
                    float t = (cv.f - mm[j]) * ii[j];
                    t = t > 0.f ? t : __expf(t) - 1.0f;
                    outb[j] = (bf16)t;
                }
                *(short8*)(A_s + (size_t)row * K + ch * 8) = *(const short8*)outb;
            }
        } else {
            #pragma unroll
            for (int i = 0; i < ISSUES; i++) {
                int row = w * 16 + i * RPI + rsub;
                int grow = mbase + row; grow = grow < M ? grow : M - 1;
                int gch = ch ^ (row & 7);
                load_lds16(A + (size_t)grow * K + gch * 8,
                           A_s + (size_t)(w * 16 + i * RPI) * K);
            }
        }
    }

    const bf16* bp[4];
    #pragma unroll
    for (int ni = 0; ni < 4; ni++)
        bp[ni] = Bt + (size_t)(n0 + w * 64 + ni * 16 + lm) * K + q * 8;

    floatx4 acc[4][4];
    #pragma unroll
    for (int i = 0; i < 4; i++)
        #pragma unroll
        for (int j = 0; j < 4; j++)
            acc[i][j] = (floatx4){0.f, 0.f, 0.f, 0.f};

    // 3-deep B ring preload, issued before the barrier (overlaps staging drain)
    short8 br0[4], br1[4], br2[4];
    #pragma unroll
    for (int ni = 0; ni < 4; ni++) br0[ni] = *(const short8*)(bp[ni]);
    #pragma unroll
    for (int ni = 0; ni < 4; ni++) br1[ni] = *(const short8*)(bp[ni] + 32);
    #pragma unroll
    for (int ni = 0; ni < 4; ni++) br2[ni] = *(const short8*)(bp[ni] + 64);

    __syncthreads();

    #pragma unroll
    for (int kc = 0; kc < KC; kc++) {
        short8 bc[4];
        #pragma unroll
        for (int ni = 0; ni < 4; ni++) {
            bc[ni] = br0[ni]; br0[ni] = br1[ni]; br1[ni] = br2[ni];
        }
        if (kc + 3 < KC) {
            #pragma unroll
            for (int ni = 0; ni < 4; ni++)
                br2[ni] = *(const short8*)(bp[ni] + (kc + 3) * 32);
        }
        short8 af[4];
        #pragma unroll
        for (int mi = 0; mi < 4; mi++) {
            int row = mi * 16 + lm;
            af[mi] = *(const short8*)(A_s + row * K + (((kc * 4 + q) ^ (lm & 7)) * 8));
        }
        #pragma unroll
        for (int mi = 0; mi < 4; mi++)
            #pragma unroll
            for (int ni = 0; ni < 4; ni++)
                acc[mi][ni] = __builtin_amdgcn_mfma_f32_16x16x32_bf16(
                    af[mi], bc[ni], acc[mi][ni], 0, 0, 0);
    }

    // C/D layout: col = lane&15, row = (lane>>4)*4 + reg  [m89]
    if (isKV) {
        bf16* C = Ckv + (size_t)z * CkvStr;
        __syncthreads();                        // A_s dead; reuse as transpose stage
        bf16* stg = A_s + (size_t)w * (16 * 72);
        #pragma unroll
        for (int p = 0; p < 4; p++) {           // p == mi
            #pragma unroll
            for (int ni = 0; ni < 4; ni++) {
                int colg = n0 + w * 64 + ni * 16 + lm;
                float bias = (colg < Nh) ? b1[colg] : b2[colg - Nh];
                #pragma unroll
                for (int rg = 0; rg < 4; rg++)
                    stg[(q * 4 + rg) * 72 + ni * 16 + lm] = (bf16)(acc[p][ni][rg] + bias);
            }
            #pragma unroll
            for (int it = 0; it < 2; it++) {
                int rl = it * 8 + (lane >> 3);
                int grow = mbase + p * 16 + rl;
                short8 vv = *(const short8*)(stg + rl * 72 + (lane & 7) * 8);
                if (grow < M)
                    *(short8*)(C + (size_t)grow * N + n0 + w * 64 + (lane & 7) * 8) = vv;
            }
        }
    } else {
        float* C = Cqs + (size_t)z * CqsStr;
        __syncthreads();                        // A_s dead; reuse as f32 store stage
        float* stgf = (float*)A_s + (size_t)w * (16 * 64);  // 4 waves x 4KB <= 16KB
        #pragma unroll
        for (int p = 0; p < 4; p++) {           // p == mi
            #pragma unroll
            for (int ni = 0; ni < 4; ni++) {
                int colg = n0 + w * 64 + ni * 16 + lm;
                float bias = (colg < Nh) ? b1[colg] : b2[colg - Nh];
                #pragma unroll
                for (int rg = 0; rg < 4; rg++)
                    stgf[(q * 4 + rg) * 64 + ni * 16 + lm] = acc[p][ni][rg] + bias;
            }
            #pragma unroll
            for (int it = 0; it < 4; it++) {
                int rl = it * 4 + q;
                int rr = mbase + p * 16 + rl;
                float4 vv = *(const float4*)(stgf + rl * 64 + lm * 4);
                if (rr < M)
                    *(float4*)(C + (size_t)rr * N + n0 + w * 64 + lm * 4) = vv;
            }
        }
    }
}

// ---------------- weight packs: LDS-tiled TRANSPOSE (round-11, ~-5us) ----------------
__global__ __launch_bounds__(256) void pack_all(
    const float* __restrict__ l1_Wk, const float* __restrict__ l1_Wv,
    const float* __restrict__ l1_Wq, const float* __restrict__ l1_Ws,
    const float* __restrict__ l2_Wk, const float* __restrict__ l2_Wv,
    const float* __restrict__ l2_Wq, const float* __restrict__ l2_Ws,
    const float* __restrict__ l3_Wk, const float* __restrict__ l3_Wv,
    const float* __restrict__ l3_Wq, const float* __restrict__ l3_Ws,
    bf16* __restrict__ Wkv1, bf16* __restrict__ Wqs1,
    bf16* __restrict__ Wkv2, bf16* __restrict__ Wqs2,
    bf16* __restrict__ Wkv3, bf16* __restrict__ Wqs3)
{
    int job = blockIdx.z, r = blockIdx.y;
    const float *W1, *W2; bf16* Wt; int K, Nh;
    switch (job) {
        case 0: W1 = l1_Wk; W2 = l1_Wv; Wt = Wkv1; K = 256; Nh = 256; break;
        case 1: W1 = l1_Wq; W2 = l1_Ws; Wt = Wqs1; K = 256; Nh = 256; break;
        case 2: W1 = l2_Wk; W2 = l2_Wv; Wt = Wkv2; K = 256; Nh = 128; break;
        case 3: W1 = l2_Wq; W2 = l2_Ws; Wt = Wqs2; K = 256; Nh = 128; break;
        case 4: W1 = l3_Wk; W2 = l3_Wv; Wt = Wkv3; K = 128; Nh = 256; break;
        default: W1 = l3_Wq; W2 = l3_Ws; Wt = Wqs3; K = 128; Nh = 256; break;
    }
    int nn0 = blockIdx.x * 64;
    if (nn0 >= 2 * Nh) return;                  // whole-block uniform exit

    __shared__ float tile[64][65];              // +1 pad: conflict-free transpose
    size_t wstride = (size_t)K * Nh;
    const float* Wsrc = ((nn0 < Nh) ? W1 : W2) + (size_t)r * wstride;
    int col0 = (nn0 < Nh) ? nn0 : nn0 - Nh;
    bf16* Wdst = Wt + (size_t)r * 2 * wstride;

    int tq = threadIdx.x >> 6;                  // 0..3
    int tl = threadIdx.x & 63;

    for (int k0 = 0; k0 < K; k0 += 64) {
        #pragma unroll
        for (int j = 0; j < 16; j++) {
            int kl = tq * 16 + j;
            tile[kl][tl] = Wsrc[(size_t)(k0 + kl) * Nh + col0 + tl];
        }
        __syncthreads();
        #pragma unroll
        for (int j = 0; j < 16; j++) {
            int nl = tq * 16 + j;
            Wdst[(size_t)(nn0 + nl) * K + k0 + tl] = (bf16)tile[tl][nl];
        }
        __syncthreads();
    }
}

// ---------------- fused attention + gated skip ----------------
// v-prefetch: both random-access rounds issued back-to-back (in-order vmcnt
// keeps k-consumes unaffected; v latency hides under softmax math).
template<int CPL, int HEADS>   // hc = CPL*64
__global__ __launch_bounds__(256) void attn_gate(
    const float* __restrict__ qs, size_t qsStr,
    const bf16* __restrict__ kv, size_t kvStr,
    const int* __restrict__ src,
    const float* __restrict__ Wb,
    float* __restrict__ yf, size_t yfStr,
    bf16* __restrict__ yb, size_t ybStr,
    int ndst, float scale)
{
    constexpr int hc = CPL * 64;
    constexpr int LPH = 64 / HEADS;
    const int z = blockIdx.y;
    int lane = threadIdx.x & 63;
    int d = blockIdx.x * 4 + (threadIdx.x >> 6);
    if (d >= ndst) return;
    qs += (size_t)z * qsStr;
    kv += (size_t)z * kvStr;
    src += (size_t)z * ndst * FAN;
    Wb += (size_t)z * 3 * hc;

    const float* qp = qs + (size_t)d * (2 * hc) + lane * CPL;
    float qv[CPL], xv[CPL];
    if constexpr (CPL == 2) {
        float2 a = *(const float2*)qp;
        float2 b = *(const float2*)(qp + hc);
        qv[0] = a.x; qv[1] = a.y; xv[0] = b.x; xv[1] = b.y;
    } else {
        float4 a = *(const float4*)qp;
        float4 b = *(const float4*)(qp + hc);
        qv[0] = a.x; qv[1] = a.y; qv[2] = a.z; qv[3] = a.w;
        xv[0] = b.x; xv[1] = b.y; xv[2] = b.z; xv[3] = b.w;
    }
    const int* sp = src + (size_t)d * FAN;
    int sidx[FAN];
    #pragma unroll
    for (int e = 0; e < FAN; e++) sidx[e] = sp[e];

    // partial dots (all k loads issued before the shuffle phase)
    float part[FAN];
    #pragma unroll
    for (int e = 0; e < FAN; e++) {
        const bf16* kp = kv + (size_t)sidx[e] * (2 * hc) + lane * CPL;
        if constexpr (CPL == 2) {
            float2 kf = cvt_bf2(*(const unsigned*)kp);
            part[e] = qv[0] * kf.x + qv[1] * kf.y;
        } else {
            uint2 u = *(const uint2*)kp;
            float2 k0 = cvt_bf2(u.x), k1 = cvt_bf2(u.y);
            part[e] = qv[0] * k0.x + qv[1] * k0.y + qv[2] * k1.x + qv[3] * k1.y;
        }
    }

    // prefetch v rows into regs (overlaps softmax below)
    uint2 vreg[FAN];
    #pragma unroll
    for (int e = 0; e < FAN; e++) {
        const bf16* vp = kv + (size_t)sidx[e] * (2 * hc) + hc + lane * CPL;
        if constexpr (CPL == 2) vreg[e].x = *(const unsigned*)vp;
        else                    vreg[e]   = *(const uint2*)vp;
    }

    float logit[FAN], mx = -1e30f;
    #pragma unroll
    for (int e = 0; e < FAN; e++) {
        float dt = part[e];
        #pragma unroll
        for (int off = LPH / 2; off > 0; off >>= 1) dt += __shfl_xor(dt, off, 64);
        dt *= scale;
        logit[e] = dt;
        mx = fmaxf(mx, dt);
    }
    float zsum = 0.f, p[FAN];
    #pragma unroll
    for (int e = 0; e < FAN; e++) { p[e] = __expf(logit[e] - mx); zsum += p[e]; }
    float inv = 1.f / zsum;

    float ov[CPL];
    #pragma unroll
    for (int j = 0; j < CPL; j++) ov[j] = 0.f;
    #pragma unroll
    for (int e = 0; e < FAN; e++) {
        if constexpr (CPL == 2) {
            float2 vf = cvt_bf2(vreg[e].x);
            ov[0] += p[e] * vf.x; ov[1] += p[e] * vf.y;
        } else {
            float2 v0 = cvt_bf2(vreg[e].x), v1 = cvt_bf2(vreg[e].y);
            ov[0] += p[e] * v0.x; ov[1] += p[e] * v0.y;
            ov[2] += p[e] * v1.x; ov[3] += p[e] * v1.y;
        }
    }
    #pragma unroll
    for (int j = 0; j < CPL; j++) ov[j] *= inv;

    // gated skip
    float s = 0.f;
    #pragma unroll
    for (int j = 0; j < CPL; j++) {
        int c = lane * CPL + j;
        s += ov[j] * Wb[c] + xv[j] * Wb[hc + c] + (ov[j] - xv[j]) * Wb[2 * hc + c];
    }
    #pragma unroll
    for (int off = 32; off > 0; off >>= 1) s += __shfl_xor(s, off, 64);
    float g = 1.f / (1.f + __expf(-s));

    float yv[CPL];
    #pragma unroll
    for (int j = 0; j < CPL; j++) yv[j] = g * xv[j] + (1.f - g) * ov[j];

    if (yf) {
        float* op = yf + (size_t)z * yfStr + (size_t)d * hc + lane * CPL;
        if constexpr (CPL == 2) *(float2*)op = make_float2(yv[0], yv[1]);
        else *(float4*)op = make_float4(yv[0], yv[1], yv[2], yv[3]);
    }
    if (yb) {
        bf16* op = yb + (size_t)z * ybStr + (size_t)d * hc + lane * CPL;
        bf16 tmp[CPL];
        #pragma unroll
        for (int j = 0; j < CPL; j++) tmp[j] = (bf16)yv[j];
        if constexpr (CPL == 2) *(short2v*)op = *(const short2v*)tmp;
        else *(short4v*)op = *(const short4v*)tmp;
    }
}

// ---------------- column stats: VECTORIZED bf16 loads (round-12, ~-10us) ----------------
__global__ __launch_bounds__(256) void colstat_partial(
    const bf16* __restrict__ x, size_t xStr, int M,
    float* __restrict__ ps, float* __restrict__ pss)
{
    int z = blockIdx.y;
    const bf16* xp = x + (size_t)z * xStr;
    int cg = (threadIdx.x & 31) * 8;            // channel-group base
    int rsub = threadIdx.x >> 5;                // 0..7
    int b = blockIdx.x;                         // 0..63
    float s[8], ss[8];
    #pragma unroll
    for (int j = 0; j < 8; j++) { s[j] = 0.f; ss[j] = 0.f; }
    for (int r = b * 8 + rsub; r < M; r += 512) {
        short8 v = *(const short8*)(xp + (size_t)r * H + cg);
        #pragma unroll
        for (int j = 0; j < 8; j++) {
            union { unsigned u; float f; } cv;
            cv.u = ((unsigned)(unsigned short)v[j]) << 16;
            s[j] += cv.f; ss[j] += cv.f * cv.f;
        }
    }
    __shared__ float red[2][8][H];              // 16KB
    #pragma unroll
    for (int j = 0; j < 8; j++) {
        red[0][rsub][cg + j] = s[j];
        red[1][rsub][cg + j] = ss[j];
    }
    __syncthreads();
    int c = threadIdx.x;
    float a = 0.f, aa = 0.f;
    #pragma unroll
    for (int g = 0; g < 8; g++) { a += red[0][g][c]; aa += red[1][g][c]; }
    ps[((size_t)z * 64 + b) * H + c] = a;
    pss[((size_t)z * 64 + b) * H + c] = aa;
}

// tiny: reduce ps/pss (64 partials) -> per-column mu, istd (3 x H each)
__global__ __launch_bounds__(256) void colstats_final(
    const float* __restrict__ ps, const float* __restrict__ pss, int M,
    float* __restrict__ muv, float* __restrict__ istdv)
{
    int z = blockIdx.y;
    int c = threadIdx.x;
    float s = 0.f, ss = 0.f;
    #pragma unroll 8
    for (int b = 0; b < 64; b++) {
        s += ps[((size_t)z * 64 + b) * H + c];
        ss += pss[((size_t)z * 64 + b) * H + c];
    }
    float mu = s / M;
    muv[(size_t)z * H + c] = mu;
    istdv[(size_t)z * H + c] = rsqrtf(ss / M - mu * mu + 1e-5f);
}

// ---------------- semantic attention across the 3 relations ----------------
// Round-14: 8 nodes/block (grid 128). The old 1-node/block version re-read the
// whole Wo 3x per block: 1024 x 768KB = 786MB of L2 traffic for a 2.4-GFLOP
// matvec (~25us). Now each Wo value loaded per k2 is reused across 8 nodes
// (traffic /8 = 98MB) and m_s reads are float4 (4x fewer LDS instrs).
// Per-node accumulation order (k2 ascending, single chain) is unchanged ->
// bitwise-identical scores; reduction structure unchanged.
__global__ __launch_bounds__(256) void semantic_kernel(
    const float* __restrict__ emb,   // (3, N3, H)
    const float* __restrict__ Wo, const float* __restrict__ bo,
    const float* __restrict__ uo, const float* __restrict__ rl,
    float* __restrict__ outp)
{
    __shared__ float m_s[3][8][H];   // 24KB
    __shared__ float wsum[8][4];
    __shared__ float score_s[3][8];
    int n0 = blockIdx.x * 8, c = threadIdx.x;
    for (int r = 0; r < 3; r++) {
        float rv = rl[r];
        #pragma unroll
        for (int nn = 0; nn < 8; nn++)
            m_s[r][nn][c] = emb[((size_t)r * N3 + n0 + nn) * H + c] * rv;
    }
    __syncthreads();
    float boc = bo[c], uoc = uo[c];
    for (int r = 0; r < 3; r++) {
        float t[8];
        #pragma unroll
        for (int nn = 0; nn < 8; nn++) t[nn] = boc;
        for (int k2 = 0; k2 < H; k2 += 4) {
            float w0 = Wo[(size_t)(k2 + 0) * H + c];
            float w1 = Wo[(size_t)(k2 + 1) * H + c];
            float w2 = Wo[(size_t)(k2 + 2) * H + c];
            float w3 = Wo[(size_t)(k2 + 3) * H + c];
            #pragma unroll
            for (int nn = 0; nn < 8; nn++) {
                float4 mv = *(const float4*)&m_s[r][nn][k2];
                t[nn] += mv.x * w0;
                t[nn] += mv.y * w1;
                t[nn] += mv.z * w2;
                t[nn] += mv.w * w3;
            }
        }
        #pragma unroll
        for (int nn = 0; nn < 8; nn++) {
            float v = tanhf(t[nn]) * uoc;
            #pragma unroll
            for (int off = 32; off > 0; off >>= 1) v += __shfl_xor(v, off, 64);
            if ((c & 63) == 0) wsum[nn][c >> 6] = v;
        }
        __syncthreads();
        if (c < 8) score_s[r][c] = wsum[c][0] + wsum[c][1] + wsum[c][2] + wsum[c][3];
        __syncthreads();
    }
    #pragma unroll
    for (int nn = 0; nn < 8; nn++) {
        float s0 = score_s[0][nn], s1 = score_s[1][nn], s2 = score_s[2][nn];
        float mx = fmaxf(s0, fmaxf(s1, s2));
        float e0 = __expf(s0 - mx), e1 = __expf(s1 - mx), e2 = __expf(s2 - mx);
        float zi = 1.0f / (e0 + e1 + e2);
        outp[(size_t)(n0 + nn) * H + c] =
            (m_s[0][nn][c] * e0 + m_s[1][nn][c] * e1 + m_s[2][nn][c] * e2) * zi;
    }
}

extern "C" void kernel_launch(void* const* d_in, const int* in_sizes, int n_in,
                              void* d_out, int out_size, void* d_ws, size_t ws_size,
                              hipStream_t stream) {
    const float* features = (const float*)d_in[0];
    const int*   n_ids    = (const int*)d_in[1];
    const int*   src1     = (const int*)d_in[2];
    const int*   src2     = (const int*)d_in[4];
    const int*   src3     = (const int*)d_in[6];
    const float* l1_Wq = (const float*)d_in[8];
    const float* l1_Wk = (const float*)d_in[9];
    const float* l1_Wv = (const float*)d_in[10];
    const float* l1_Ws = (const float*)d_in[11];
    const float* l1_bq = (const float*)d_in[12];
    const float* l1_bk = (const float*)d_in[13];
    const float* l1_bv = (const float*)d_in[14];
    const float* l1_bs = (const float*)d_in[15];
    const float* l1_Wb = (const float*)d_in[16];
    const float* l2_Wq = (const float*)d_in[17];
    const float* l2_Wk = (const float*)d_in[18];
    const float* l2_Wv = (const float*)d_in[19];
    const float* l2_Ws = (const float*)d_in[20];
    const float* l2_bq = (const float*)d_in[21];
    const float* l2_bk = (const float*)d_in[22];
    const float* l2_bv = (const float*)d_in[23];
    const float* l2_bs = (const float*)d_in[24];
    const float* l2_Wb = (const float*)d_in[25];
    const float* l3_Wq = (const float*)d_in[26];
    const float* l3_Wk = (const float*)d_in[27];
    const float* l3_Wv = (const float*)d_in[28];
    const float* l3_Ws = (const float*)d_in[29];
    const float* l3_bq = (const float*)d_in[30];
    const float* l3_bk = (const float*)d_in[31];
    const float* l3_bv = (const float*)d_in[32];
    const float* l3_bs = (const float*)d_in[33];
    const float* l3_Wb = (const float*)d_in[34];
    const float* w_omega = (const float*)d_in[35];
    const float* b_omega = (const float*)d_in[36];
    const float* u_omega = (const float*)d_in[37];
    const float* rl      = (const float*)d_in[38];

    // ---- workspace layout: per-relation buffers ----
    float* ws = (float*)d_ws;
    size_t o = 0;
    float* emb = ws + o; o += (size_t)3 * N3 * H;
    float* qs1 = ws + o; o += (size_t)3 * N1 * 512;
    float* qs2 = ws + o; o += (size_t)3 * N2 * 256;
    float* qs3 = ws + o; o += (size_t)3 * N3 * 512;
    float* ps  = ws + o; o += (size_t)3 * 64 * H;
    float* pss = ws + o; o += (size_t)3 * 64 * H;
    float* muv   = ws + o; o += (size_t)3 * H;
    float* istdv = ws + o; o += (size_t)3 * H;

    bf16* bws = (bf16*)(ws + o);
    size_t b = 0;
    bf16* kv1 = bws + b; b += (size_t)3 * N0 * 512;
    bf16* x1b = bws + b; b += (size_t)3 * N1 * 256;
    bf16* kv2 = bws + b; b += (size_t)3 * N1 * 256;
    bf16* x2b = bws + b; b += (size_t)3 * N2 * 128;
    bf16* kv3 = bws + b; b += (size_t)3 * N2 * 512;
    bf16* Wkv1 = bws + b; b += (size_t)3 * 512 * H;
    bf16* Wqs1 = bws + b; b += (size_t)3 * 512 * H;
    bf16* Wkv2 = bws + b; b += (size_t)3 * 256 * H;
    bf16* Wqs2 = bws + b; b += (size_t)3 * 256 * H;
    bf16* Wkv3 = bws + b; b += (size_t)3 * 512 * 128;
    bf16* Wqs3 = bws + b; b += (size_t)3 * 512 * 128;

    const float sc128 = 0.088388347648318447f;  // 1/sqrt(128)
    const float sc256 = 0.0625f;                // 1/sqrt(256)

    // ---- all weight packs, one dispatch (LDS-tiled transpose) ----
    pack_all<<<dim3(8, 3, 6), 256, 0, stream>>>(
        l1_Wk, l1_Wv, l1_Wq, l1_Ws, l2_Wk, l2_Wv, l2_Wq, l2_Ws,
        l3_Wk, l3_Wv, l3_Wq, l3_Ws, Wkv1, Wqs1, Wkv2, Wqs2, Wkv3, Wqs3);

    // ---- L1 (gather-fused, kv/qs interleaved grid): 64x512 tile, 512 thr ----
    {
        int nbKV = (N0 + 63) / 64, nbQS = (N1 + 63) / 64;
        gemm_l1_fused<<<dim3(nbKV + nbQS, 1, 3), 512, 0, stream>>>(
            features, n_ids, Wkv1, Wqs1, l1_bk, l1_bv, l1_bq, l1_bs,
            kv1, (size_t)N0 * 512, qs1, (size_t)N1 * 512);
    }
    attn_gate<4, 2><<<dim3((N1 + 3) / 4, 3), 256, 0, stream>>>(
        qs1, (size_t)N1 * 512, kv1, (size_t)N0 * 512, src1, l1_Wb,
        (float*)nullptr, 0, x1b, (size_t)N1 * 256, N1, sc128);
    colstat_partial<<<dim3(64, 3), 256, 0, stream>>>(x1b, (size_t)N1 * 256, N1, ps, pss);
    colstats_final<<<dim3(1, 3), 256, 0, stream>>>(ps, pss, N1, muv, istdv);

    // ---- L2 (norm+ELU folded into A-staging): din=256, hc=128, N=256, K=256 ----
    {
        int nbKV = (N1 + 63) / 64, nbQS = (N2 + 63) / 64;
        gemm_dual<256, true><<<dim3(nbKV + nbQS, 1, 3), 256, 0, stream>>>(
            x1b, (size_t)N1 * 256, muv, istdv,
            Wkv2, Wqs2, l2_bk, l2_bv, l2_bq, l2_bs, 128,
            kv2, (size_t)N1 * 256, N1, qs2, (size_t)N2 * 256, N2, nbKV);
    }
    attn_gate<2, 1><<<dim3((N2 + 3) / 4, 3), 256, 0, stream>>>(
        qs2, (size_t)N2 * 256, kv2, (size_t)N1 * 256, src2, l2_Wb,
        (float*)nullptr, 0, x2b, (size_t)N2 * 128, N2, sc128);

    // ---- L3: din=128, heads=1, ch=256, hc=256, N=512, K=128 ----
    {
        int nbKV = (N2 + 63) / 64, nbQS = (N3 + 63) / 64;
        gemm_dual<128, false><<<dim3(nbKV + nbQS, 2, 3), 256, 0, stream>>>(
            x2b, (size_t)N2 * 128, (const float*)nullptr, (const float*)nullptr,
            Wkv3, Wqs3, l3_bk, l3_bv, l3_bq, l3_bs, 256,
            kv3, (size_t)N2 * 512, N2, qs3, (size_t)N3 * 512, N3, nbKV);
    }
    attn_gate<4, 1><<<dim3((N3 + 3) / 4, 3), 256, 0, stream>>>(
        qs3, (size_t)N3 * 512, kv3, (size_t)N2 * 512, src3, l3_Wb,
        emb, (size_t)N3 * H, (bf16*)nullptr, 0, N3, sc256);

    semantic_kernel<<<N3 / 8, 256, 0, stream>>>(emb, w_omega, b_omega, u_omega, rl, (float*)d_out);
}